// Round 8
// baseline (18662.776 us; speedup 1.0000x reference)
//
#include <hip/hip_runtime.h>
#include <hip/hip_cooperative_groups.h>
#include <math.h>

#define NB 128
#define NS 256
#define ND 512
#define NBS (NB*NS)   // 32768
#define KE 544        // 512 x | 10 back | 20 cnn | 1 bias | 1 pad
#define NC 2560       // 2048 cell gates + 512 leap hidden

typedef unsigned short u16;
typedef __attribute__((ext_vector_type(8))) short s8v;   // 8 bf16 (4 VGPRs)
typedef __attribute__((ext_vector_type(4))) float f4v;   // 4 f32 acc

static constexpr size_t PSA  = (size_t)NBS * KE;
static constexpr size_t PSWE = (size_t)NC  * KE;
static constexpr size_t PSWS = (size_t)NC  * ND;
static constexpr size_t PSH  = (size_t)NB  * ND;

// ---------------- device-global scratch ----------------
__device__ double g_A[(size_t)NBS * KE];
__device__ u16    g_Ab[3 * PSA];
__device__ float  g_Pre[(size_t)NBS * NC];
__device__ double g_Aproj[(size_t)NBS * 40];
__device__ double g_gum[NS * NB * 2];
__device__ double g_hx[NB * ND];
__device__ u16    g_hxb[3 * NB * ND];
__device__ double g_c[NB * ND];
__device__ double g_gbuf[NB * NC];
__device__ double g_final[NB * ND];
__device__ float  g_Wext[PSWE];
__device__ u16    g_Wextb[3 * PSWE];
__device__ float  g_Wstep[PSWS];
__device__ u16    g_Wstepb[3 * PSWS];
__device__ int    g_ok, g_bad, g_badstep;

__device__ __forceinline__ double sigd(double x) { return 1.0 / (1.0 + exp(-x)); }
__device__ __forceinline__ u16 f2bf(float f) {
    unsigned u = __float_as_uint(f);
    return (u16)((u + 0x7FFFu + ((u >> 16) & 1u)) >> 16);   // RNE
}
__device__ __forceinline__ float bf2f(u16 b) { return __uint_as_float(((unsigned)b) << 16); }
__device__ __forceinline__ void decomp3(float f, u16& b0, u16& b1, u16& b2) {
    b0 = f2bf(f); float r1 = f - bf2f(b0);
    b1 = f2bf(r1); float r2 = r1 - bf2f(b1);
    b2 = f2bf(r2);
}

#define MFMA_BF16 __builtin_amdgcn_mfma_f32_16x16x32_bf16
#define STEP6(AP,AC,A0,A1,A2,B0,B1,B2) \
    AP = MFMA_BF16(A0, B0, AP, 0, 0, 0); \
    AC = MFMA_BF16(A0, B1, AC, 0, 0, 0); \
    AC = MFMA_BF16(A1, B0, AC, 0, 0, 0); \
    AC = MFMA_BF16(A0, B2, AC, 0, 0, 0); \
    AC = MFMA_BF16(A1, B1, AC, 0, 0, 0); \
    AC = MFMA_BF16(A2, B0, AC, 0, 0, 0);

// ---------------- bf16 MFMA layout probe ----------------
__global__ void probe_bf16() {
    int l = threadIdx.x, lr = l & 15, lk = l >> 4;
    s8v a, b;
#pragma unroll
    for (int e = 0; e < 8; ++e) {
        int k = 8 * lk + e;
        a[e] = (short)f2bf((float)(((3 * lr + 7 * k) % 13) + 1));
        b[e] = (short)f2bf((float)(((5 * k + 11 * lr) % 17) + 1));
    }
    f4v d = {0.f, 0.f, 0.f, 0.f};
    d = MFMA_BF16(a, b, d, 0, 0, 0);
    bool okl = true;
#pragma unroll
    for (int r = 0; r < 4; ++r) {
        int row = 4 * lk + r, col = lr;
        int e = 0;
        for (int k = 0; k < 32; ++k)
            e += (((3 * row + 7 * k) % 13) + 1) * (((5 * k + 11 * col) % 17) + 1);
        if (d[r] != (float)e) okl = false;
    }
    unsigned long long vote = __ballot(okl);
    if (l == 0) { g_ok = (vote == 0xFFFFFFFFFFFFFFFFull) ? 1 : 0; g_bad = 0; g_badstep = 0; }
}

// ---------------- init ----------------
__global__ void init_state() {
    int i = blockIdx.x * 256 + threadIdx.x;
    if (i < NB * ND) {
        g_hx[i] = 0.0; g_c[i] = 0.0;
        g_hxb[i] = 0; g_hxb[PSH + i] = 0; g_hxb[2 * PSH + i] = 0;
    }
}

// ---------------- weight repack + bf16x3 ----------------
__global__ __launch_bounds__(256) void build_w(const float* __restrict__ cWih,
                                               const float* __restrict__ cWhh,
                                               const float* __restrict__ W1,
                                               const float* __restrict__ b1) {
    int n = blockIdx.x;
    for (int c = threadIdx.x; c < KE; c += 256) {
        float we;
        if (n < 2048) we = (c < 512) ? cWih[(size_t)n * 512 + c] : 0.f;
        else {
            int n2 = n - 2048;
            if      (c < 512)  we = W1[(size_t)n2 * 1054 + 512 + c];
            else if (c < 522)  we = W1[(size_t)n2 * 1054 + 1024 + (c - 512)];
            else if (c < 542)  we = W1[(size_t)n2 * 1054 + 1034 + (c - 522)];
            else if (c == 542) we = b1[n2];
            else               we = 0.f;
        }
        size_t ix = (size_t)n * KE + c;
        g_Wext[ix] = we;
        u16 b0, b1_, b2; decomp3(we, b0, b1_, b2);
        g_Wextb[ix] = b0; g_Wextb[PSWE + ix] = b1_; g_Wextb[2 * PSWE + ix] = b2;
        if (c < 512) {
            float ws = (n < 2048) ? cWhh[(size_t)n * 512 + c]
                                  : W1[(size_t)(n - 2048) * 1054 + c];
            size_t ix2 = (size_t)n * ND + c;
            g_Wstep[ix2] = ws;
            decomp3(ws, b0, b1_, b2);
            g_Wstepb[ix2] = b0; g_Wstepb[PSWS + ix2] = b1_; g_Wstepb[2 * PSWS + ix2] = b2;
        }
    }
}

// ---------------- gumbel: JAX partitionable threefry2x32, key (0,42) ----------------
__device__ __forceinline__ unsigned rotl32(unsigned x, int r) { return (x << r) | (x >> (32 - r)); }

__global__ void gumbel_init() {
    unsigned p = blockIdx.x * 256 + threadIdx.x;
    if (p >= 65536u) return;
    unsigned k0 = 0u, k1 = 42u;
    unsigned ks2 = k0 ^ k1 ^ 0x1BD11BDAu;
    unsigned x0 = 0u, x1 = p;
    x0 += k0; x1 += k1;
#define RND(r) { x0 += x1; x1 = rotl32(x1, (r)); x1 ^= x0; }
    RND(13) RND(15) RND(26) RND(6)
    x0 += k1;  x1 += ks2 + 1u;
    RND(17) RND(29) RND(16) RND(24)
    x0 += ks2; x1 += k0 + 2u;
    RND(13) RND(15) RND(26) RND(6)
    x0 += k0;  x1 += k1 + 3u;
    RND(17) RND(29) RND(16) RND(24)
    x0 += k1;  x1 += ks2 + 4u;
    RND(13) RND(15) RND(26) RND(6)
    x0 += ks2; x1 += k0 + 5u;
#undef RND
    unsigned bits = x0 ^ x1;
    float u = __uint_as_float((bits >> 9) | 0x3f800000u) - 1.0f;
    g_gum[p] = log(-log((double)u + 1e-20) + 1e-20);
}

// ---------------- embedding gather+sum ----------------
__global__ __launch_bounds__(128) void embed_sum(const int* __restrict__ seqs,
                                                 const float* __restrict__ emb) {
    int bs = blockIdx.x;
    int tid = threadIdx.x;
    __shared__ int idxs[16];
    if (tid < 16) idxs[tid] = seqs[(size_t)bs * 16 + tid];
    __syncthreads();
    double a0 = 0, a1 = 0, a2 = 0, a3 = 0;
    for (int v = 0; v < 16; ++v) {
        const float4* row = (const float4*)(emb + (size_t)idxs[v] * ND);
        float4 e = row[tid];
        a0 += (double)e.x; a1 += (double)e.y; a2 += (double)e.z; a3 += (double)e.w;
    }
    double* o = g_A + (size_t)bs * KE + tid * 4;
    o[0] = a0; o[1] = a1; o[2] = a2; o[3] = a3;
    if (tid == 0) { g_A[(size_t)bs * KE + 542] = 1.0; g_A[(size_t)bs * KE + 543] = 0.0; }
}

// ---------------- decompose g_A -> bf16x3 ----------------
__global__ void decomp_A() {
    for (size_t i = (size_t)blockIdx.x * 256 + threadIdx.x; i < PSA; i += (size_t)gridDim.x * 256) {
        float f = (float)g_A[i];
        u16 b0, b1, b2; decomp3(f, b0, b1, b2);
        g_Ab[i] = b0; g_Ab[PSA + i] = b1; g_Ab[2 * PSA + i] = b2;
    }
}

// ---------------- f64 vector GEMM (Aproj only) ----------------
__global__ __launch_bounds__(256) void gemm_f64(
    const double* __restrict__ A, int lda,
    const float* __restrict__ W, int ldw,
    double* __restrict__ C, int ldc,
    int M, int N, int K) {
    __shared__ double As[16][66];
    __shared__ double Ws[16][66];
    int m0 = blockIdx.x * 64, n0 = blockIdx.y * 64;
    int tid = threadIdx.x, tx = tid & 15, ty = tid >> 4;
    double acc[4][4] = {};
    for (int k0 = 0; k0 < K; k0 += 16) {
        for (int i = tid; i < 1024; i += 256) {
            int r = i >> 4, c = i & 15;
            As[c][r] = (m0 + r < M && k0 + c < K) ? A[(size_t)(m0 + r) * lda + k0 + c] : 0.0;
            Ws[c][r] = (n0 + r < N && k0 + c < K) ? (double)W[(size_t)(n0 + r) * ldw + k0 + c] : 0.0;
        }
        __syncthreads();
#pragma unroll
        for (int kk = 0; kk < 16; ++kk) {
            double a0 = As[kk][ty*4], a1 = As[kk][ty*4+1], a2 = As[kk][ty*4+2], a3 = As[kk][ty*4+3];
            double w0 = Ws[kk][tx*4], w1 = Ws[kk][tx*4+1], w2 = Ws[kk][tx*4+2], w3 = Ws[kk][tx*4+3];
            acc[0][0] += a0*w0; acc[0][1] += a0*w1; acc[0][2] += a0*w2; acc[0][3] += a0*w3;
            acc[1][0] += a1*w0; acc[1][1] += a1*w1; acc[1][2] += a1*w2; acc[1][3] += a1*w3;
            acc[2][0] += a2*w0; acc[2][1] += a2*w1; acc[2][2] += a2*w2; acc[2][3] += a2*w3;
            acc[3][0] += a3*w0; acc[3][1] += a3*w1; acc[3][2] += a3*w2; acc[3][3] += a3*w3;
        }
        __syncthreads();
    }
#pragma unroll
    for (int i = 0; i < 4; ++i)
#pragma unroll
        for (int j = 0; j < 4; ++j) {
            int m = m0 + ty*4 + i, n = n0 + tx*4 + j;
            if (m < M && n < N) C[(size_t)m * ldc + n] = acc[i][j];
        }
}

// ---------------- reverse LSTM ----------------
__global__ __launch_bounds__(64) void rev_lstm(const float* __restrict__ Whh) {
    int b = blockIdx.x;
    int tid = threadIdx.x;
    __shared__ double h[10], cc[10], g[40], wsh[400];
    for (int i = tid; i < 400; i += 64) wsh[i] = (double)Whh[i];
    if (tid < 10) { h[tid] = 0.0; cc[tid] = 0.0; }
    __syncthreads();
    for (int s = NS - 1; s >= 0; --s) {
        if (tid < 40) {
            double acc = g_Aproj[((size_t)b * NS + s) * 40 + tid];
#pragma unroll
            for (int k = 0; k < 10; ++k) acc += h[k] * wsh[tid * 10 + k];
            g[tid] = acc;
        }
        __syncthreads();
        if (tid < 10) {
            double gi = g[tid], gf = g[10 + tid], gg = g[20 + tid], go = g[30 + tid];
            double cn = sigd(gf) * cc[tid] + sigd(gi) * tanh(gg);
            cc[tid] = cn;
            double hn = sigd(go) * tanh(cn);
            h[tid] = hn;
            g_A[((size_t)b * NS + s) * KE + 512 + tid] = hn;
        }
        __syncthreads();
    }
}

// ---------------- conv1d + relu ----------------
__global__ __launch_bounds__(256) void conv_relu(const float* __restrict__ w) {
    int b = blockIdx.x, s0 = blockIdx.y * 8;
    int tid = threadIdx.x, grp = tid >> 5, lane = tid & 31;
    __shared__ double xs[10][ND];
    for (int i = tid; i < 10 * ND; i += 256) {
        int r = i >> 9, d = i & (ND - 1);
        int s = s0 - 1 + r;
        xs[r][d] = (s >= 0 && s < NS) ? g_A[((size_t)b * NS + s) * KE + d] : 0.0;
    }
    __syncthreads();
    int s = s0 + grp;
    for (int o = 0; o < 20; ++o) {
        const float* wo = w + (size_t)o * 1536;
        double acc = 0.0;
        for (int d = lane; d < ND; d += 32) {
            acc += xs[grp][d]     * (double)wo[d*3]
                 + xs[grp + 1][d] * (double)wo[d*3 + 1]
                 + xs[grp + 2][d] * (double)wo[d*3 + 2];
        }
        for (int m = 16; m > 0; m >>= 1) acc += __shfl_xor(acc, m, 32);
        if (lane == 0)
            g_A[((size_t)b * NS + s) * KE + 522 + o] = acc > 0.0 ? acc : 0.0;
    }
}

// ---------------- big GEMM: g_Pre = g_A @ g_Wext^T (bf16x3 MFMA | f64 vector) ----------------
__global__ __launch_bounds__(256) void big_gemm() {
    __shared__ __align__(16) unsigned char shm[36864];
    int tid = threadIdx.x;
    int n0 = blockIdx.x * 64, m0 = blockIdx.y * 64;
    if (g_ok) {
        u16* usA = (u16*)shm;
        u16* usB = usA + 9216;
        int lane = tid & 63, wave = tid >> 6;
        int wm = (wave & 1) * 32, wn = (wave >> 1) * 32;
        int lr = lane & 15, lk = lane >> 4;
        f4v z = {0.f,0.f,0.f,0.f};
        f4v aP00=z,aP01=z,aP10=z,aP11=z, aC00=z,aC01=z,aC10=z,aC11=z;
        for (int k0 = 0; k0 < KE; k0 += 32) {
            for (int i = tid; i < 1536; i += 256) {
                if (i < 768) {
                    int p = i >> 8, rem = i & 255, r = rem >> 2, sg = rem & 3;
                    *(uint4*)(void*)(usA + p*3072 + r*48 + sg*8) =
                        *(const uint4*)(const void*)(g_Ab + (size_t)p*PSA + (size_t)(m0+r)*KE + k0 + sg*8);
                } else {
                    int j = i - 768;
                    int p = j >> 8, rem = j & 255, r = rem >> 2, sg = rem & 3;
                    *(uint4*)(void*)(usB + p*3072 + r*48 + sg*8) =
                        *(const uint4*)(const void*)(g_Wextb + (size_t)p*PSWE + (size_t)(n0+r)*KE + k0 + sg*8);
                }
            }
            __syncthreads();
            const u16* pa = usA + (wm + lr) * 48 + 8 * lk;
            const u16* pb = usB + (wn + lr) * 48 + 8 * lk;
            s8v a0_0 = *(const s8v*)(const void*)(pa);
            s8v a0_1 = *(const s8v*)(const void*)(pa + 768);
            s8v a1_0 = *(const s8v*)(const void*)(pa + 3072);
            s8v a1_1 = *(const s8v*)(const void*)(pa + 3840);
            s8v a2_0 = *(const s8v*)(const void*)(pa + 6144);
            s8v a2_1 = *(const s8v*)(const void*)(pa + 6912);
            s8v b0_0 = *(const s8v*)(const void*)(pb);
            s8v b0_1 = *(const s8v*)(const void*)(pb + 768);
            s8v b1_0 = *(const s8v*)(const void*)(pb + 3072);
            s8v b1_1 = *(const s8v*)(const void*)(pb + 3840);
            s8v b2_0 = *(const s8v*)(const void*)(pb + 6144);
            s8v b2_1 = *(const s8v*)(const void*)(pb + 6912);
            STEP6(aP00, aC00, a0_0, a1_0, a2_0, b0_0, b1_0, b2_0)
            STEP6(aP01, aC01, a0_0, a1_0, a2_0, b0_1, b1_1, b2_1)
            STEP6(aP10, aC10, a0_1, a1_1, a2_1, b0_0, b1_0, b2_0)
            STEP6(aP11, aC11, a0_1, a1_1, a2_1, b0_1, b1_1, b2_1)
            __syncthreads();
        }
        int rb = m0 + wm + 4 * lk, cb0 = n0 + wn + lr, cb1 = cb0 + 16;
#pragma unroll
        for (int r = 0; r < 4; ++r) {
            g_Pre[(size_t)(rb + r)      * NC + cb0] = aP00[r] + aC00[r];
            g_Pre[(size_t)(rb + r)      * NC + cb1] = aP01[r] + aC01[r];
            g_Pre[(size_t)(rb + 16 + r) * NC + cb0] = aP10[r] + aC10[r];
            g_Pre[(size_t)(rb + 16 + r) * NC + cb1] = aP11[r] + aC11[r];
        }
    } else {
        double* Asd = (double*)shm;
        double* Wsd = Asd + 64 * 33;
        int tx = tid & 15, ty = tid >> 4;
        double acc[4][4] = {};
        for (int k0 = 0; k0 < KE; k0 += 32) {
            for (int i = tid; i < 2048; i += 256) {
                int r = i >> 5, c = i & 31;
                Asd[r * 33 + c] = g_A[(size_t)(m0 + r) * KE + k0 + c];
                Wsd[r * 33 + c] = (double)g_Wext[(size_t)(n0 + r) * KE + k0 + c];
            }
            __syncthreads();
            for (int kk = 0; kk < 32; ++kk) {
                double a0 = Asd[(ty*4)*33+kk], a1 = Asd[(ty*4+1)*33+kk], a2 = Asd[(ty*4+2)*33+kk], a3 = Asd[(ty*4+3)*33+kk];
                double w0 = Wsd[(tx*4)*33+kk], w1 = Wsd[(tx*4+1)*33+kk], w2 = Wsd[(tx*4+2)*33+kk], w3 = Wsd[(tx*4+3)*33+kk];
                acc[0][0] += a0*w0; acc[0][1] += a0*w1; acc[0][2] += a0*w2; acc[0][3] += a0*w3;
                acc[1][0] += a1*w0; acc[1][1] += a1*w1; acc[1][2] += a1*w2; acc[1][3] += a1*w3;
                acc[2][0] += a2*w0; acc[2][1] += a2*w1; acc[2][2] += a2*w2; acc[2][3] += a2*w3;
                acc[3][0] += a3*w0; acc[3][1] += a3*w1; acc[3][2] += a3*w2; acc[3][3] += a3*w3;
            }
            __syncthreads();
        }
#pragma unroll
        for (int i = 0; i < 4; ++i)
#pragma unroll
            for (int j = 0; j < 4; ++j)
                g_Pre[(size_t)(m0 + ty*4 + i) * NC + (n0 + tx*4 + j)] = (float)acc[i][j];
    }
}

// ---------------- sample-verify g_Pre ----------------
__global__ void verify_pre() {
    int s = blockIdx.x * 256 + threadIdx.x;
    unsigned m = ((unsigned)s * 2654435761u) & 32767u;
    unsigned n = ((unsigned)s * 40503u + 7u) % 2560u;
    double dot = 0.0;
    const double* ar = g_A + (size_t)m * KE;
    const float*  wr = g_Wext + (size_t)n * KE;
    for (int c = 0; c < KE; ++c) dot += ar[c] * (double)wr[c];
    double got = (double)g_Pre[(size_t)m * NC + n];
    if (fabs(got - dot) > 1e-4 * (1.0 + fabs(dot))) atomicOr(&g_bad, 1);
}

// ---------------- full vector recompute of g_Pre (only if ok && bad) ----------------
__global__ __launch_bounds__(256) void big_fix() {
    if (!(g_ok && g_bad)) return;
    __shared__ double As[64][33];
    __shared__ double Ws[64][33];
    int tid = threadIdx.x, tx = tid & 15, ty = tid >> 4;
    for (int tile = blockIdx.x; tile < (NC/64) * (NBS/64); tile += gridDim.x) {
        int n0 = (tile % (NC/64)) * 64, m0 = (tile / (NC/64)) * 64;
        double acc[4][4] = {};
        for (int k0 = 0; k0 < KE; k0 += 32) {
            for (int i = tid; i < 2048; i += 256) {
                int r = i >> 5, c = i & 31;
                As[r][c] = g_A[(size_t)(m0 + r) * KE + k0 + c];
                Ws[r][c] = (double)g_Wext[(size_t)(n0 + r) * KE + k0 + c];
            }
            __syncthreads();
            for (int kk = 0; kk < 32; ++kk) {
                double a0 = As[ty*4][kk], a1 = As[ty*4+1][kk], a2 = As[ty*4+2][kk], a3 = As[ty*4+3][kk];
                double w0 = Ws[tx*4][kk], w1 = Ws[tx*4+1][kk], w2 = Ws[tx*4+2][kk], w3 = Ws[tx*4+3][kk];
                acc[0][0] += a0*w0; acc[0][1] += a0*w1; acc[0][2] += a0*w2; acc[0][3] += a0*w3;
                acc[1][0] += a1*w0; acc[1][1] += a1*w1; acc[1][2] += a1*w2; acc[1][3] += a1*w3;
                acc[2][0] += a2*w0; acc[2][1] += a2*w1; acc[2][2] += a2*w2; acc[2][3] += a2*w3;
                acc[3][0] += a3*w0; acc[3][1] += a3*w1; acc[3][2] += a3*w2; acc[3][3] += a3*w3;
            }
            __syncthreads();
        }
#pragma unroll
        for (int i = 0; i < 4; ++i)
#pragma unroll
            for (int j = 0; j < 4; ++j)
                g_Pre[(size_t)(m0 + ty*4 + i) * NC + (n0 + tx*4 + j)] = (float)acc[i][j];
        __syncthreads();
    }
}

// ---------------- synthetic hx for step probe ----------------
__global__ void synth_hx() {
    int i = blockIdx.x * 256 + threadIdx.x;
    if (i >= NB * ND) return;
    unsigned h = (unsigned)i * 2654435761u;
    float v = (float)((h >> 8) & 0xFFFFu) / 65536.0f - 0.5f;
    g_hx[i] = (double)v;
    u16 b0, b1, b2; decomp3(v, b0, b1, b2);
    g_hxb[i] = b0; g_hxb[PSH + i] = b1; g_hxb[2 * PSH + i] = b2;
}

// ---------------- shared phase-A bodies ----------------
// MFMA path: direct-global fragment loads (hxb/Wstepb are L2-resident), no LDS, no barriers.
__device__ __forceinline__ void phaseA_mfma(int t, int m0, int n0, int tid) {
    int lane = tid & 63, wave = tid >> 6;
    int wm = (wave & 1) * 16, wn = (wave >> 1) * 32;
    int lr = lane & 15, lk = lane >> 4;
    size_t ha  = (size_t)(m0 + wm + lr) * ND;
    size_t wb0 = (size_t)(n0 + wn + lr) * ND;
    size_t wb1 = (size_t)(n0 + wn + 16 + lr) * ND;
    f4v z = {0.f,0.f,0.f,0.f};
    f4v aP0=z, aP1=z, aC0=z, aC1=z;
    for (int k0 = 0; k0 < ND; k0 += 32) {
        int kk = k0 + 8 * lk;
        s8v a0  = *(const s8v*)(const void*)(g_hxb + ha + kk);
        s8v a1  = *(const s8v*)(const void*)(g_hxb + PSH + ha + kk);
        s8v a2  = *(const s8v*)(const void*)(g_hxb + 2*PSH + ha + kk);
        s8v b00 = *(const s8v*)(const void*)(g_Wstepb + wb0 + kk);
        s8v b01 = *(const s8v*)(const void*)(g_Wstepb + wb1 + kk);
        s8v b10 = *(const s8v*)(const void*)(g_Wstepb + PSWS + wb0 + kk);
        s8v b11 = *(const s8v*)(const void*)(g_Wstepb + PSWS + wb1 + kk);
        s8v b20 = *(const s8v*)(const void*)(g_Wstepb + 2*PSWS + wb0 + kk);
        s8v b21 = *(const s8v*)(const void*)(g_Wstepb + 2*PSWS + wb1 + kk);
        STEP6(aP0, aC0, a0, a1, a2, b00, b10, b20)
        STEP6(aP1, aC1, a0, a1, a2, b01, b11, b21)
    }
    int rb = m0 + wm + 4 * lk, cb0 = n0 + wn + lr, cb1 = cb0 + 16;
#pragma unroll
    for (int r = 0; r < 4; ++r) {
        g_gbuf[(size_t)(rb + r) * NC + cb0] = (double)aP0[r] + (double)aC0[r]
            + (double)g_Pre[((size_t)(rb + r) * NS + t) * NC + cb0];
        g_gbuf[(size_t)(rb + r) * NC + cb1] = (double)aP1[r] + (double)aC1[r]
            + (double)g_Pre[((size_t)(rb + r) * NS + t) * NC + cb1];
    }
}

// f64 vector fallback (r7-verified structure); shd: >= 3168 doubles
__device__ __forceinline__ void phaseA_vec(int t, int m0, int n0, int tid, double* shd) {
    double* Asd = shd;            // [32][33]
    double* Wsd = shd + 1056;     // [64][33]
    int tx = tid & 15, ty = tid >> 4;
    double acc[2][4] = {};
    for (int k0 = 0; k0 < ND; k0 += 32) {
        for (int i = tid; i < 1024; i += 256) {
            int r = i >> 5, c = i & 31;
            Asd[r * 33 + c] = g_hx[(size_t)(m0 + r) * ND + k0 + c];
        }
        for (int i = tid; i < 2048; i += 256) {
            int r = i >> 5, c = i & 31;
            Wsd[r * 33 + c] = (double)g_Wstep[(size_t)(n0 + r) * ND + k0 + c];
        }
        __syncthreads();
        for (int kk = 0; kk < 32; ++kk) {
            double a0 = Asd[(ty*2)*33+kk], a1 = Asd[(ty*2+1)*33+kk];
            double w0 = Wsd[(tx*4)*33+kk], w1 = Wsd[(tx*4+1)*33+kk], w2 = Wsd[(tx*4+2)*33+kk], w3 = Wsd[(tx*4+3)*33+kk];
            acc[0][0] += a0*w0; acc[0][1] += a0*w1; acc[0][2] += a0*w2; acc[0][3] += a0*w3;
            acc[1][0] += a1*w0; acc[1][1] += a1*w1; acc[1][2] += a1*w2; acc[1][3] += a1*w3;
        }
        __syncthreads();
    }
#pragma unroll
    for (int i = 0; i < 2; ++i)
#pragma unroll
        for (int j = 0; j < 4; ++j) {
            int m = m0 + ty*2 + i, n = n0 + tx*4 + j;
            g_gbuf[(size_t)m * NC + n] = acc[i][j] + (double)g_Pre[((size_t)m * NS + t) * NC + n];
        }
}

// phase B: per-row softmax/skip/cell update (r7 step_update math); shd >= 514 doubles
__device__ __forceinline__ void phaseB(int b, int t, int mylen, int tid, double* shd,
                                       const float* __restrict__ W2, const float* __restrict__ b2) {
    const double* gb = g_gbuf + (size_t)b * NC;
    double* red = shd;            // [256][2]
    double* skipsh = shd + 512;   // [2]
    double p0 = 0.0, p1 = 0.0;
    for (int j = tid; j < ND; j += 256) {
        double h = gb[2048 + j];
        h = h > 0.0 ? h : 0.0;
        p0 += h * (double)W2[j];
        p1 += h * (double)W2[ND + j];
    }
    red[tid*2] = p0; red[tid*2+1] = p1;
    __syncthreads();
    for (int s = 128; s > 0; s >>= 1) {
        if (tid < s) { red[tid*2] += red[(tid+s)*2]; red[tid*2+1] += red[(tid+s)*2+1]; }
        __syncthreads();
    }
    if (tid == 0) {
        double l0 = red[0] + (double)b2[0], l1 = red[1] + (double)b2[1];
        double mx = fmax(l0, l1);
        double sh0 = l0 - mx, sh1 = l1 - mx;
        double lsum = log(exp(sh0) + exp(sh1));
        double y0 = (sh0 - lsum) - g_gum[(size_t)t * (NB * 2) + b * 2 + 0];
        double y1 = (sh1 - lsum) - g_gum[(size_t)t * (NB * 2) + b * 2 + 1];
        double xx0 = y0 / 1e-5, xx1 = y1 / 1e-5;
        double mm = fmax(xx0, xx1);
        double e0 = exp(xx0 - mm), e1 = exp(xx1 - mm);
        double inv = 1.0 / (e0 + e1);
        skipsh[0] = e0 * inv; skipsh[1] = e1 * inv;
    }
    __syncthreads();
    double s0 = skipsh[0], s1 = skipsh[1];
    bool isFinal = (t == mylen - 1);
    for (int j = tid; j < ND; j += 256) {
        double gi = gb[j], gf = gb[ND + j], gg = gb[2*ND + j], go = gb[3*ND + j];
        size_t ix = (size_t)b * ND + j;
        double cn = sigd(gf) * g_c[ix] + sigd(gi) * tanh(gg);
        double shx = sigd(go) * tanh(cn);
        double hn = g_hx[ix] * s1 + shx * s0;
        g_c[ix] = cn;
        g_hx[ix] = hn;
        u16 b0, b1, b2x; decomp3((float)hn, b0, b1, b2x);
        g_hxb[ix] = b0; g_hxb[PSH + ix] = b1; g_hxb[2 * PSH + ix] = b2x;
        if (isFinal) g_final[ix] = hn;
    }
}

// ---------------- standalone step kernels (probe + host fallback) ----------------
__global__ __launch_bounds__(256) void step_gemm(int t, int probe) {
    __shared__ double shd[3168];
    int m0 = blockIdx.x * 32, n0 = blockIdx.y * 64;
    int use_mfma = g_ok && (probe || !g_badstep);
    if (use_mfma) phaseA_mfma(t, m0, n0, threadIdx.x);
    else          phaseA_vec(t, m0, n0, threadIdx.x, shd);
}

__global__ __launch_bounds__(256) void step_update(
    const float* __restrict__ W2, const float* __restrict__ b2,
    const int* __restrict__ lengths, int t) {
    __shared__ double shd[516];
    int b = blockIdx.x;
    phaseB(b, t, lengths[b], threadIdx.x, shd, W2, b2);
}

// ---------------- verify step-GEMM on synthetic state (t=0) ----------------
__global__ void verify_step() {
    int s = blockIdx.x * 256 + threadIdx.x;
    unsigned m = ((unsigned)s * 2654435761u) & 127u;
    unsigned n = ((unsigned)s * 40503u + 7u) % 2560u;
    double dot = 0.0;
    const double* hr = g_hx + (size_t)m * ND;
    const float*  wr = g_Wstep + (size_t)n * ND;
    for (int c = 0; c < ND; ++c) dot += hr[c] * (double)wr[c];
    dot += (double)g_Pre[((size_t)m * NS + 0) * NC + n];
    double got = g_gbuf[(size_t)m * NC + n];
    if (fabs(got - dot) > 1e-4 * (1.0 + fabs(dot))) atomicOr(&g_badstep, 1);
}

// ---------------- persistent cooperative time loop ----------------
__global__ __launch_bounds__(256) void loop_fused(const float* __restrict__ W2,
                                                  const float* __restrict__ b2,
                                                  const int* __restrict__ lengths) {
    cooperative_groups::grid_group grid = cooperative_groups::this_grid();
    __shared__ double shd[3168];
    int bid = blockIdx.x, tid = threadIdx.x;
    int m0 = (bid & 3) * 32, n0 = (bid >> 2) * 64;
    int mylen = (bid < NB) ? lengths[bid] : -1;
    int path = g_ok && !g_badstep;
    for (int t = 0; t < NS; ++t) {
        if (path) phaseA_mfma(t, m0, n0, tid);
        else      phaseA_vec(t, m0, n0, tid, shd);
        grid.sync();
        if (bid < NB) phaseB(bid, t, mylen, tid, shd, W2, b2);
        grid.sync();
    }
}

// ---------------- final projection ----------------
__global__ __launch_bounds__(256) void final_out(const float* __restrict__ Wo,
                                                 const float* __restrict__ bo,
                                                 float* __restrict__ out) {
    int tid = threadIdx.x;
    int b = tid >> 1, k = tid & 1;
    double acc = 0.0;
    const double* f = g_final + (size_t)b * ND;
    const float* w = Wo + (size_t)k * ND;
    for (int d = 0; d < ND; ++d) acc += f[d] * (double)w[d];
    out[b * 2 + k] = (float)(acc + (double)bo[k]);
}

// ---------------- host launcher ----------------
extern "C" void kernel_launch(void* const* d_in, const int* in_sizes, int n_in,
                              void* d_out, int out_size, void* d_ws, size_t ws_size,
                              hipStream_t stream) {
    (void)in_sizes; (void)n_in; (void)d_ws; (void)ws_size; (void)out_size;
    const int*   seqs    = (const int*)d_in[0];
    const int*   lengths = (const int*)d_in[2];
    const float* emb     = (const float*)d_in[5];
    const float* revWih  = (const float*)d_in[6];
    const float* revWhh  = (const float*)d_in[7];
    const float* convw   = (const float*)d_in[8];
    const float* W1      = (const float*)d_in[9];
    const float* b1      = (const float*)d_in[10];
    const float* W2      = (const float*)d_in[11];
    const float* b2      = (const float*)d_in[12];
    const float* cWih    = (const float*)d_in[13];
    const float* cWhh    = (const float*)d_in[14];
    const float* Wo      = (const float*)d_in[15];
    const float* bo      = (const float*)d_in[16];
    float* out = (float*)d_out;

    double *A_p = nullptr, *Ap_p = nullptr;
    hipGetSymbolAddress((void**)&A_p,  HIP_SYMBOL(g_A));
    hipGetSymbolAddress((void**)&Ap_p, HIP_SYMBOL(g_Aproj));

    probe_bf16<<<1, 64, 0, stream>>>();
    build_w<<<NC, 256, 0, stream>>>(cWih, cWhh, W1, b1);
    gumbel_init<<<256, 256, 0, stream>>>();
    embed_sum<<<NBS, 128, 0, stream>>>(seqs, emb);

    gemm_f64<<<dim3(NBS / 64, 1), 256, 0, stream>>>(A_p, KE, revWih, ND, Ap_p, 40,
                                                    NBS, 40, ND);
    rev_lstm<<<NB, 64, 0, stream>>>(revWhh);
    conv_relu<<<dim3(NB, NS / 8), 256, 0, stream>>>(convw);
    decomp_A<<<4096, 256, 0, stream>>>();

    big_gemm<<<dim3(NC / 64, NBS / 64), 256, 0, stream>>>();
    verify_pre<<<32, 256, 0, stream>>>();
    big_fix<<<2048, 256, 0, stream>>>();

    // step-GEMM probe on synthetic state, then zero real state
    synth_hx<<<256, 256, 0, stream>>>();
    step_gemm<<<dim3(4, 40), 256, 0, stream>>>(0, 1);
    verify_step<<<8, 256, 0, stream>>>();
    init_state<<<256, 256, 0, stream>>>();

    // persistent cooperative time loop; deterministic host fallback if refused
    void* args[] = { (void*)&W2, (void*)&b2, (void*)&lengths };
    hipError_t ce = hipLaunchCooperativeKernel((const void*)loop_fused,
                                               dim3(160), dim3(256), args, 0, stream);
    if (ce != hipSuccess) {
        (void)hipGetLastError();   // clear sticky error
        for (int t = 0; t < NS; ++t) {
            step_gemm<<<dim3(4, 40), 256, 0, stream>>>(t, 0);
            step_update<<<NB, 256, 0, stream>>>(W2, b2, lengths, t);
        }
    }
    final_out<<<1, 256, 0, stream>>>(Wo, bo, out);
}

// Round 9
// 16844.400 us; speedup vs baseline: 1.1080x; 1.1080x over previous
//
#include <hip/hip_runtime.h>
#include <hip/hip_cooperative_groups.h>
#include <math.h>

#define NB 128
#define NS 256
#define ND 512
#define NBS (NB*NS)   // 32768
#define KE 544        // 512 x | 10 back | 20 cnn | 1 bias | 1 pad
#define NC 2560       // 2048 cell gates + 512 leap hidden

typedef unsigned short u16;
typedef __attribute__((ext_vector_type(8))) short s8v;   // 8 bf16
typedef __attribute__((ext_vector_type(4))) float f4v;   // 4 f32 acc

static constexpr size_t PSA  = (size_t)NBS * KE;
static constexpr size_t PSWE = (size_t)NC  * KE;
static constexpr size_t PSWS = (size_t)NC  * ND;
static constexpr size_t PSH  = (size_t)NB  * ND;

// ---------------- device-global scratch ----------------
__device__ double g_A[(size_t)NBS * KE];
__device__ u16    g_Ab[3 * PSA];
__device__ float  g_Pre[(size_t)NBS * NC];    // layout [t][b][n]
__device__ double g_Aproj[(size_t)NBS * 40];
__device__ double g_gum[NS * NB * 2];
__device__ double g_hx[NB * ND];
__device__ u16    g_hxb[3 * NB * ND];
__device__ double g_c[NB * ND];
__device__ float  g_gbufF[NB * NC];
__device__ double g_final[NB * ND];
__device__ float  g_Wext[PSWE];
__device__ u16    g_Wextb[3 * PSWE];
__device__ float  g_Wstep[PSWS];
__device__ u16    g_Wstepb[3 * PSWS];
__device__ int    g_ok, g_bad, g_badstep, g_badfused;

__device__ __forceinline__ double sigd(double x) { return 1.0 / (1.0 + exp(-x)); }
__device__ __forceinline__ u16 f2bf(float f) {
    unsigned u = __float_as_uint(f);
    return (u16)((u + 0x7FFFu + ((u >> 16) & 1u)) >> 16);   // RNE
}
__device__ __forceinline__ float bf2f(u16 b) { return __uint_as_float(((unsigned)b) << 16); }
__device__ __forceinline__ void decomp3(float f, u16& b0, u16& b1, u16& b2) {
    b0 = f2bf(f); float r1 = f - bf2f(b0);
    b1 = f2bf(r1); float r2 = r1 - bf2f(b1);
    b2 = f2bf(r2);
}
__device__ __forceinline__ size_t pre_ix(int m /*b*NS+s*/, int n) {
    return ((size_t)(m & 255) * NB + (m >> 8)) * NC + n;    // -> [s][b][n]
}

#define MFMA_BF16 __builtin_amdgcn_mfma_f32_16x16x32_bf16
#define STEP6(AP,AC,A0,A1,A2,B0,B1,B2) \
    AP = MFMA_BF16(A0, B0, AP, 0, 0, 0); \
    AC = MFMA_BF16(A0, B1, AC, 0, 0, 0); \
    AC = MFMA_BF16(A1, B0, AC, 0, 0, 0); \
    AC = MFMA_BF16(A0, B2, AC, 0, 0, 0); \
    AC = MFMA_BF16(A1, B1, AC, 0, 0, 0); \
    AC = MFMA_BF16(A2, B0, AC, 0, 0, 0);

// ---------------- bf16 MFMA layout probe ----------------
__global__ void probe_bf16() {
    int l = threadIdx.x, lr = l & 15, lk = l >> 4;
    s8v a, b;
#pragma unroll
    for (int e = 0; e < 8; ++e) {
        int k = 8 * lk + e;
        a[e] = (short)f2bf((float)(((3 * lr + 7 * k) % 13) + 1));
        b[e] = (short)f2bf((float)(((5 * k + 11 * lr) % 17) + 1));
    }
    f4v d = {0.f, 0.f, 0.f, 0.f};
    d = MFMA_BF16(a, b, d, 0, 0, 0);
    bool okl = true;
#pragma unroll
    for (int r = 0; r < 4; ++r) {
        int row = 4 * lk + r, col = lr;
        int e = 0;
        for (int k = 0; k < 32; ++k)
            e += (((3 * row + 7 * k) % 13) + 1) * (((5 * k + 11 * col) % 17) + 1);
        if (d[r] != (float)e) okl = false;
    }
    unsigned long long vote = __ballot(okl);
    if (l == 0) {
        g_ok = (vote == 0xFFFFFFFFFFFFFFFFull) ? 1 : 0;
        g_bad = 0; g_badstep = 0; g_badfused = 0;
    }
}

// ---------------- init ----------------
__global__ void init_state() {
    int i = blockIdx.x * 256 + threadIdx.x;
    if (i < NB * ND) {
        g_hx[i] = 0.0; g_c[i] = 0.0;
        g_hxb[i] = 0; g_hxb[PSH + i] = 0; g_hxb[2 * PSH + i] = 0;
    }
}

// ---------------- weight repack + bf16x3 ----------------
__global__ __launch_bounds__(256) void build_w(const float* __restrict__ cWih,
                                               const float* __restrict__ cWhh,
                                               const float* __restrict__ W1,
                                               const float* __restrict__ b1) {
    int n = blockIdx.x;
    for (int c = threadIdx.x; c < KE; c += 256) {
        float we;
        if (n < 2048) we = (c < 512) ? cWih[(size_t)n * 512 + c] : 0.f;
        else {
            int n2 = n - 2048;
            if      (c < 512)  we = W1[(size_t)n2 * 1054 + 512 + c];
            else if (c < 522)  we = W1[(size_t)n2 * 1054 + 1024 + (c - 512)];
            else if (c < 542)  we = W1[(size_t)n2 * 1054 + 1034 + (c - 522)];
            else if (c == 542) we = b1[n2];
            else               we = 0.f;
        }
        size_t ix = (size_t)n * KE + c;
        g_Wext[ix] = we;
        u16 b0, b1_, b2; decomp3(we, b0, b1_, b2);
        g_Wextb[ix] = b0; g_Wextb[PSWE + ix] = b1_; g_Wextb[2 * PSWE + ix] = b2;
        if (c < 512) {
            float ws = (n < 2048) ? cWhh[(size_t)n * 512 + c]
                                  : W1[(size_t)(n - 2048) * 1054 + c];
            size_t ix2 = (size_t)n * ND + c;
            g_Wstep[ix2] = ws;
            decomp3(ws, b0, b1_, b2);
            g_Wstepb[ix2] = b0; g_Wstepb[PSWS + ix2] = b1_; g_Wstepb[2 * PSWS + ix2] = b2;
        }
    }
}

// ---------------- gumbel: JAX partitionable threefry2x32, key (0,42) ----------------
__device__ __forceinline__ unsigned rotl32(unsigned x, int r) { return (x << r) | (x >> (32 - r)); }

__global__ void gumbel_init() {
    unsigned p = blockIdx.x * 256 + threadIdx.x;
    if (p >= 65536u) return;
    unsigned k0 = 0u, k1 = 42u;
    unsigned ks2 = k0 ^ k1 ^ 0x1BD11BDAu;
    unsigned x0 = 0u, x1 = p;
    x0 += k0; x1 += k1;
#define RND(r) { x0 += x1; x1 = rotl32(x1, (r)); x1 ^= x0; }
    RND(13) RND(15) RND(26) RND(6)
    x0 += k1;  x1 += ks2 + 1u;
    RND(17) RND(29) RND(16) RND(24)
    x0 += ks2; x1 += k0 + 2u;
    RND(13) RND(15) RND(26) RND(6)
    x0 += k0;  x1 += k1 + 3u;
    RND(17) RND(29) RND(16) RND(24)
    x0 += k1;  x1 += ks2 + 4u;
    RND(13) RND(15) RND(26) RND(6)
    x0 += ks2; x1 += k0 + 5u;
#undef RND
    unsigned bits = x0 ^ x1;
    float u = __uint_as_float((bits >> 9) | 0x3f800000u) - 1.0f;
    g_gum[p] = log(-log((double)u + 1e-20) + 1e-20);
}

// ---------------- embedding gather+sum ----------------
__global__ __launch_bounds__(128) void embed_sum(const int* __restrict__ seqs,
                                                 const float* __restrict__ emb) {
    int bs = blockIdx.x;
    int tid = threadIdx.x;
    __shared__ int idxs[16];
    if (tid < 16) idxs[tid] = seqs[(size_t)bs * 16 + tid];
    __syncthreads();
    double a0 = 0, a1 = 0, a2 = 0, a3 = 0;
    for (int v = 0; v < 16; ++v) {
        const float4* row = (const float4*)(emb + (size_t)idxs[v] * ND);
        float4 e = row[tid];
        a0 += (double)e.x; a1 += (double)e.y; a2 += (double)e.z; a3 += (double)e.w;
    }
    double* o = g_A + (size_t)bs * KE + tid * 4;
    o[0] = a0; o[1] = a1; o[2] = a2; o[3] = a3;
    if (tid == 0) { g_A[(size_t)bs * KE + 542] = 1.0; g_A[(size_t)bs * KE + 543] = 0.0; }
}

// ---------------- decompose g_A -> bf16x3 ----------------
__global__ void decomp_A() {
    for (size_t i = (size_t)blockIdx.x * 256 + threadIdx.x; i < PSA; i += (size_t)gridDim.x * 256) {
        float f = (float)g_A[i];
        u16 b0, b1, b2; decomp3(f, b0, b1, b2);
        g_Ab[i] = b0; g_Ab[PSA + i] = b1; g_Ab[2 * PSA + i] = b2;
    }
}

// ---------------- f64 vector GEMM (Aproj only) ----------------
__global__ __launch_bounds__(256) void gemm_f64(
    const double* __restrict__ A, int lda,
    const float* __restrict__ W, int ldw,
    double* __restrict__ C, int ldc,
    int M, int N, int K) {
    __shared__ double As[16][66];
    __shared__ double Ws[16][66];
    int m0 = blockIdx.x * 64, n0 = blockIdx.y * 64;
    int tid = threadIdx.x, tx = tid & 15, ty = tid >> 4;
    double acc[4][4] = {};
    for (int k0 = 0; k0 < K; k0 += 16) {
        for (int i = tid; i < 1024; i += 256) {
            int r = i >> 4, c = i & 15;
            As[c][r] = (m0 + r < M && k0 + c < K) ? A[(size_t)(m0 + r) * lda + k0 + c] : 0.0;
            Ws[c][r] = (n0 + r < N && k0 + c < K) ? (double)W[(size_t)(n0 + r) * ldw + k0 + c] : 0.0;
        }
        __syncthreads();
#pragma unroll
        for (int kk = 0; kk < 16; ++kk) {
            double a0 = As[kk][ty*4], a1 = As[kk][ty*4+1], a2 = As[kk][ty*4+2], a3 = As[kk][ty*4+3];
            double w0 = Ws[kk][tx*4], w1 = Ws[kk][tx*4+1], w2 = Ws[kk][tx*4+2], w3 = Ws[kk][tx*4+3];
            acc[0][0] += a0*w0; acc[0][1] += a0*w1; acc[0][2] += a0*w2; acc[0][3] += a0*w3;
            acc[1][0] += a1*w0; acc[1][1] += a1*w1; acc[1][2] += a1*w2; acc[1][3] += a1*w3;
            acc[2][0] += a2*w0; acc[2][1] += a2*w1; acc[2][2] += a2*w2; acc[2][3] += a2*w3;
            acc[3][0] += a3*w0; acc[3][1] += a3*w1; acc[3][2] += a3*w2; acc[3][3] += a3*w3;
        }
        __syncthreads();
    }
#pragma unroll
    for (int i = 0; i < 4; ++i)
#pragma unroll
        for (int j = 0; j < 4; ++j) {
            int m = m0 + ty*4 + i, n = n0 + tx*4 + j;
            if (m < M && n < N) C[(size_t)m * ldc + n] = acc[i][j];
        }
}

// ---------------- reverse LSTM ----------------
__global__ __launch_bounds__(64) void rev_lstm(const float* __restrict__ Whh) {
    int b = blockIdx.x;
    int tid = threadIdx.x;
    __shared__ double h[10], cc[10], g[40], wsh[400];
    for (int i = tid; i < 400; i += 64) wsh[i] = (double)Whh[i];
    if (tid < 10) { h[tid] = 0.0; cc[tid] = 0.0; }
    __syncthreads();
    for (int s = NS - 1; s >= 0; --s) {
        if (tid < 40) {
            double acc = g_Aproj[((size_t)b * NS + s) * 40 + tid];
#pragma unroll
            for (int k = 0; k < 10; ++k) acc += h[k] * wsh[tid * 10 + k];
            g[tid] = acc;
        }
        __syncthreads();
        if (tid < 10) {
            double gi = g[tid], gf = g[10 + tid], gg = g[20 + tid], go = g[30 + tid];
            double cn = sigd(gf) * cc[tid] + sigd(gi) * tanh(gg);
            cc[tid] = cn;
            double hn = sigd(go) * tanh(cn);
            h[tid] = hn;
            g_A[((size_t)b * NS + s) * KE + 512 + tid] = hn;
        }
        __syncthreads();
    }
}

// ---------------- conv1d + relu ----------------
__global__ __launch_bounds__(256) void conv_relu(const float* __restrict__ w) {
    int b = blockIdx.x, s0 = blockIdx.y * 8;
    int tid = threadIdx.x, grp = tid >> 5, lane = tid & 31;
    __shared__ double xs[10][ND];
    for (int i = tid; i < 10 * ND; i += 256) {
        int r = i >> 9, d = i & (ND - 1);
        int s = s0 - 1 + r;
        xs[r][d] = (s >= 0 && s < NS) ? g_A[((size_t)b * NS + s) * KE + d] : 0.0;
    }
    __syncthreads();
    int s = s0 + grp;
    for (int o = 0; o < 20; ++o) {
        const float* wo = w + (size_t)o * 1536;
        double acc = 0.0;
        for (int d = lane; d < ND; d += 32) {
            acc += xs[grp][d]     * (double)wo[d*3]
                 + xs[grp + 1][d] * (double)wo[d*3 + 1]
                 + xs[grp + 2][d] * (double)wo[d*3 + 2];
        }
        for (int m = 16; m > 0; m >>= 1) acc += __shfl_xor(acc, m, 32);
        if (lane == 0)
            g_A[((size_t)b * NS + s) * KE + 522 + o] = acc > 0.0 ? acc : 0.0;
    }
}

// ---------------- big GEMM: g_Pre[t][b][n] = g_A @ g_Wext^T ----------------
__global__ __launch_bounds__(256) void big_gemm() {
    __shared__ __align__(16) unsigned char shm[36864];
    int tid = threadIdx.x;
    int n0 = blockIdx.x * 64, m0 = blockIdx.y * 64;
    if (g_ok) {
        u16* usA = (u16*)shm;
        u16* usB = usA + 9216;
        int lane = tid & 63, wave = tid >> 6;
        int wm = (wave & 1) * 32, wn = (wave >> 1) * 32;
        int lr = lane & 15, lk = lane >> 4;
        f4v z = {0.f,0.f,0.f,0.f};
        f4v aP00=z,aP01=z,aP10=z,aP11=z, aC00=z,aC01=z,aC10=z,aC11=z;
        for (int k0 = 0; k0 < KE; k0 += 32) {
            for (int i = tid; i < 1536; i += 256) {
                if (i < 768) {
                    int p = i >> 8, rem = i & 255, r = rem >> 2, sg = rem & 3;
                    *(uint4*)(void*)(usA + p*3072 + r*48 + sg*8) =
                        *(const uint4*)(const void*)(g_Ab + (size_t)p*PSA + (size_t)(m0+r)*KE + k0 + sg*8);
                } else {
                    int j = i - 768;
                    int p = j >> 8, rem = j & 255, r = rem >> 2, sg = rem & 3;
                    *(uint4*)(void*)(usB + p*3072 + r*48 + sg*8) =
                        *(const uint4*)(const void*)(g_Wextb + (size_t)p*PSWE + (size_t)(n0+r)*KE + k0 + sg*8);
                }
            }
            __syncthreads();
            const u16* pa = usA + (wm + lr) * 48 + 8 * lk;
            const u16* pb = usB + (wn + lr) * 48 + 8 * lk;
            s8v a0_0 = *(const s8v*)(const void*)(pa);
            s8v a0_1 = *(const s8v*)(const void*)(pa + 768);
            s8v a1_0 = *(const s8v*)(const void*)(pa + 3072);
            s8v a1_1 = *(const s8v*)(const void*)(pa + 3840);
            s8v a2_0 = *(const s8v*)(const void*)(pa + 6144);
            s8v a2_1 = *(const s8v*)(const void*)(pa + 6912);
            s8v b0_0 = *(const s8v*)(const void*)(pb);
            s8v b0_1 = *(const s8v*)(const void*)(pb + 768);
            s8v b1_0 = *(const s8v*)(const void*)(pb + 3072);
            s8v b1_1 = *(const s8v*)(const void*)(pb + 3840);
            s8v b2_0 = *(const s8v*)(const void*)(pb + 6144);
            s8v b2_1 = *(const s8v*)(const void*)(pb + 6912);
            STEP6(aP00, aC00, a0_0, a1_0, a2_0, b0_0, b1_0, b2_0)
            STEP6(aP01, aC01, a0_0, a1_0, a2_0, b0_1, b1_1, b2_1)
            STEP6(aP10, aC10, a0_1, a1_1, a2_1, b0_0, b1_0, b2_0)
            STEP6(aP11, aC11, a0_1, a1_1, a2_1, b0_1, b1_1, b2_1)
            __syncthreads();
        }
        int rb = m0 + wm + 4 * lk, cb0 = n0 + wn + lr, cb1 = cb0 + 16;
#pragma unroll
        for (int r = 0; r < 4; ++r) {
            g_Pre[pre_ix(rb + r, cb0)]      = aP00[r] + aC00[r];
            g_Pre[pre_ix(rb + r, cb1)]      = aP01[r] + aC01[r];
            g_Pre[pre_ix(rb + 16 + r, cb0)] = aP10[r] + aC10[r];
            g_Pre[pre_ix(rb + 16 + r, cb1)] = aP11[r] + aC11[r];
        }
    } else {
        double* Asd = (double*)shm;
        double* Wsd = Asd + 64 * 33;
        int tx = tid & 15, ty = tid >> 4;
        double acc[4][4] = {};
        for (int k0 = 0; k0 < KE; k0 += 32) {
            for (int i = tid; i < 2048; i += 256) {
                int r = i >> 5, c = i & 31;
                Asd[r * 33 + c] = g_A[(size_t)(m0 + r) * KE + k0 + c];
                Wsd[r * 33 + c] = (double)g_Wext[(size_t)(n0 + r) * KE + k0 + c];
            }
            __syncthreads();
            for (int kk = 0; kk < 32; ++kk) {
                double a0 = Asd[(ty*4)*33+kk], a1 = Asd[(ty*4+1)*33+kk], a2 = Asd[(ty*4+2)*33+kk], a3 = Asd[(ty*4+3)*33+kk];
                double w0 = Wsd[(tx*4)*33+kk], w1 = Wsd[(tx*4+1)*33+kk], w2 = Wsd[(tx*4+2)*33+kk], w3 = Wsd[(tx*4+3)*33+kk];
                acc[0][0] += a0*w0; acc[0][1] += a0*w1; acc[0][2] += a0*w2; acc[0][3] += a0*w3;
                acc[1][0] += a1*w0; acc[1][1] += a1*w1; acc[1][2] += a1*w2; acc[1][3] += a1*w3;
                acc[2][0] += a2*w0; acc[2][1] += a2*w1; acc[2][2] += a2*w2; acc[2][3] += a2*w3;
                acc[3][0] += a3*w0; acc[3][1] += a3*w1; acc[3][2] += a3*w2; acc[3][3] += a3*w3;
            }
            __syncthreads();
        }
#pragma unroll
        for (int i = 0; i < 4; ++i)
#pragma unroll
            for (int j = 0; j < 4; ++j)
                g_Pre[pre_ix(m0 + ty*4 + i, n0 + tx*4 + j)] = (float)acc[i][j];
    }
}

// ---------------- sample-verify g_Pre ----------------
__global__ void verify_pre() {
    int s = blockIdx.x * 256 + threadIdx.x;
    unsigned m = ((unsigned)s * 2654435761u) & 32767u;
    unsigned n = ((unsigned)s * 40503u + 7u) % 2560u;
    double dot = 0.0;
    const double* ar = g_A + (size_t)m * KE;
    const float*  wr = g_Wext + (size_t)n * KE;
    for (int c = 0; c < KE; ++c) dot += ar[c] * (double)wr[c];
    double got = (double)g_Pre[pre_ix((int)m, (int)n)];
    if (fabs(got - dot) > 1e-4 * (1.0 + fabs(dot))) atomicOr(&g_bad, 1);
}

// ---------------- full vector recompute of g_Pre (only if ok && bad) ----------------
__global__ __launch_bounds__(256) void big_fix() {
    if (!(g_ok && g_bad)) return;
    __shared__ double As[64][33];
    __shared__ double Ws[64][33];
    int tid = threadIdx.x, tx = tid & 15, ty = tid >> 4;
    for (int tile = blockIdx.x; tile < (NC/64) * (NBS/64); tile += gridDim.x) {
        int n0 = (tile % (NC/64)) * 64, m0 = (tile / (NC/64)) * 64;
        double acc[4][4] = {};
        for (int k0 = 0; k0 < KE; k0 += 32) {
            for (int i = tid; i < 2048; i += 256) {
                int r = i >> 5, c = i & 31;
                As[r][c] = g_A[(size_t)(m0 + r) * KE + k0 + c];
                Ws[r][c] = (double)g_Wext[(size_t)(n0 + r) * KE + k0 + c];
            }
            __syncthreads();
            for (int kk = 0; kk < 32; ++kk) {
                double a0 = As[ty*4][kk], a1 = As[ty*4+1][kk], a2 = As[ty*4+2][kk], a3 = As[ty*4+3][kk];
                double w0 = Ws[tx*4][kk], w1 = Ws[tx*4+1][kk], w2 = Ws[tx*4+2][kk], w3 = Ws[tx*4+3][kk];
                acc[0][0] += a0*w0; acc[0][1] += a0*w1; acc[0][2] += a0*w2; acc[0][3] += a0*w3;
                acc[1][0] += a1*w0; acc[1][1] += a1*w1; acc[1][2] += a1*w2; acc[1][3] += a1*w3;
                acc[2][0] += a2*w0; acc[2][1] += a2*w1; acc[2][2] += a2*w2; acc[2][3] += a2*w3;
                acc[3][0] += a3*w0; acc[3][1] += a3*w1; acc[3][2] += a3*w2; acc[3][3] += a3*w3;
            }
            __syncthreads();
        }
#pragma unroll
        for (int i = 0; i < 4; ++i)
#pragma unroll
            for (int j = 0; j < 4; ++j)
                g_Pre[pre_ix(m0 + ty*4 + i, n0 + tx*4 + j)] = (float)acc[i][j];
        __syncthreads();
    }
}

// ---------------- synthetic hx for step probes ----------------
__global__ void synth_hx() {
    int i = blockIdx.x * 256 + threadIdx.x;
    if (i >= NB * ND) return;
    unsigned h = (unsigned)i * 2654435761u;
    float v = (float)((h >> 8) & 0xFFFFu) / 65536.0f - 0.5f;
    g_hx[i] = (double)v;
    u16 b0, b1, b2; decomp3(v, b0, b1, b2);
    g_hxb[i] = b0; g_hxb[PSH + i] = b1; g_hxb[2 * PSH + i] = b2;
}

// ---------------- standalone step GEMM (probe + host-fallback path) ----------------
__global__ __launch_bounds__(256) void step_gemm(int t, int probe) {
    __shared__ double shd[3168];
    int tid = threadIdx.x;
    int m0 = blockIdx.x * 32, n0 = blockIdx.y * 64;
    int use_mfma = g_ok && (probe || !g_badstep);
    if (use_mfma) {
        int lane = tid & 63, wave = tid >> 6;
        int wm = (wave & 1) * 16, wn = (wave >> 1) * 32;
        int lr = lane & 15, lk = lane >> 4;
        size_t ha  = (size_t)(m0 + wm + lr) * ND;
        size_t wb0 = (size_t)(n0 + wn + lr) * ND;
        size_t wb1 = (size_t)(n0 + wn + 16 + lr) * ND;
        f4v z = {0.f,0.f,0.f,0.f};
        f4v aP0=z, aP1=z, aC0=z, aC1=z;
        for (int k0 = 0; k0 < ND; k0 += 32) {
            int kk = k0 + 8 * lk;
            s8v a0  = *(const s8v*)(const void*)(g_hxb + ha + kk);
            s8v a1  = *(const s8v*)(const void*)(g_hxb + PSH + ha + kk);
            s8v a2  = *(const s8v*)(const void*)(g_hxb + 2*PSH + ha + kk);
            s8v b00 = *(const s8v*)(const void*)(g_Wstepb + wb0 + kk);
            s8v b01 = *(const s8v*)(const void*)(g_Wstepb + wb1 + kk);
            s8v b10 = *(const s8v*)(const void*)(g_Wstepb + PSWS + wb0 + kk);
            s8v b11 = *(const s8v*)(const void*)(g_Wstepb + PSWS + wb1 + kk);
            s8v b20 = *(const s8v*)(const void*)(g_Wstepb + 2*PSWS + wb0 + kk);
            s8v b21 = *(const s8v*)(const void*)(g_Wstepb + 2*PSWS + wb1 + kk);
            STEP6(aP0, aC0, a0, a1, a2, b00, b10, b20)
            STEP6(aP1, aC1, a0, a1, a2, b01, b11, b21)
        }
        int rb = m0 + wm + 4 * lk, cb0 = n0 + wn + lr, cb1 = cb0 + 16;
#pragma unroll
        for (int r = 0; r < 4; ++r) {
            g_gbufF[(size_t)(rb + r) * NC + cb0] = aP0[r] + aC0[r]
                + g_Pre[((size_t)t * NB + rb + r) * NC + cb0];
            g_gbufF[(size_t)(rb + r) * NC + cb1] = aP1[r] + aC1[r]
                + g_Pre[((size_t)t * NB + rb + r) * NC + cb1];
        }
    } else {
        double* Asd = shd;
        double* Wsd = shd + 1056;
        int tx = tid & 15, ty = tid >> 4;
        double acc[2][4] = {};
        for (int k0 = 0; k0 < ND; k0 += 32) {
            for (int i = tid; i < 1024; i += 256) {
                int r = i >> 5, c = i & 31;
                Asd[r * 33 + c] = g_hx[(size_t)(m0 + r) * ND + k0 + c];
            }
            for (int i = tid; i < 2048; i += 256) {
                int r = i >> 5, c = i & 31;
                Wsd[r * 33 + c] = (double)g_Wstep[(size_t)(n0 + r) * ND + k0 + c];
            }
            __syncthreads();
            for (int kk = 0; kk < 32; ++kk) {
                double a0 = Asd[(ty*2)*33+kk], a1 = Asd[(ty*2+1)*33+kk];
                double w0 = Wsd[(tx*4)*33+kk], w1 = Wsd[(tx*4+1)*33+kk], w2 = Wsd[(tx*4+2)*33+kk], w3 = Wsd[(tx*4+3)*33+kk];
                acc[0][0] += a0*w0; acc[0][1] += a0*w1; acc[0][2] += a0*w2; acc[0][3] += a0*w3;
                acc[1][0] += a1*w0; acc[1][1] += a1*w1; acc[1][2] += a1*w2; acc[1][3] += a1*w3;
            }
            __syncthreads();
        }
#pragma unroll
        for (int i = 0; i < 2; ++i)
#pragma unroll
            for (int j = 0; j < 4; ++j) {
                int m = m0 + ty*2 + i, n = n0 + tx*4 + j;
                g_gbufF[(size_t)m * NC + n] = (float)(acc[i][j]
                    + (double)g_Pre[((size_t)t * NB + m) * NC + n]);
            }
    }
}

// ---------------- verifiers of gbufF vs f64 dot (t=0, synthetic hx) ----------------
__device__ __forceinline__ void verify_gbuf_core(int* flag) {
    int s = blockIdx.x * 256 + threadIdx.x;
    unsigned m = ((unsigned)s * 2654435761u) & 127u;
    unsigned n = ((unsigned)s * 40503u + 7u) % 2560u;
    double dot = 0.0;
    const double* hr = g_hx + (size_t)m * ND;
    const float*  wr = g_Wstep + (size_t)n * ND;
    for (int c = 0; c < ND; ++c) dot += hr[c] * (double)wr[c];
    dot += (double)g_Pre[(size_t)m * NC + n];
    double got = (double)g_gbufF[(size_t)m * NC + n];
    if (fabs(got - dot) > 1e-4 * (1.0 + fabs(dot))) atomicOr(flag, 1);
}
__global__ void verify_step()  { verify_gbuf_core(&g_badstep); }
__global__ void verify_fused() { verify_gbuf_core(&g_badfused); }

// ---------------- phase B core (shared math) ----------------
#define PHASEB_BODY(GB, B, T, MYLEN, S0, S1, WR_STATE)                              \
    {                                                                               \
        bool isFinal = ((T) == (MYLEN) - 1);                                        \
        _Pragma("unroll")                                                           \
        for (int e = 0; e < 2; ++e) { /* compile-time bound */ }                    \
    }

// ---------------- standalone per-step update (host fallback) ----------------
__global__ __launch_bounds__(256) void step_update(
    const float* __restrict__ W2, const float* __restrict__ b2,
    const int* __restrict__ lengths, int t) {
    __shared__ double red[8];
    __shared__ double skipsh[2];
    int b = blockIdx.x, tid = threadIdx.x, lane = tid & 63, wave = tid >> 6;
    const float* gb = g_gbufF + (size_t)b * NC;
    double p0 = 0.0, p1 = 0.0;
    for (int j = tid; j < ND; j += 256) {
        double h = (double)gb[2048 + j];
        h = h > 0.0 ? h : 0.0;
        p0 += h * (double)W2[j];
        p1 += h * (double)W2[ND + j];
    }
    for (int off = 32; off > 0; off >>= 1) {
        p0 += __shfl_down(p0, off, 64);
        p1 += __shfl_down(p1, off, 64);
    }
    if (lane == 0) { red[wave*2] = p0; red[wave*2+1] = p1; }
    __syncthreads();
    if (tid == 0) {
        double l0 = red[0]+red[2]+red[4]+red[6] + (double)b2[0];
        double l1 = red[1]+red[3]+red[5]+red[7] + (double)b2[1];
        double mx = fmax(l0, l1);
        double sh0 = l0 - mx, sh1 = l1 - mx;
        double lsum = log(exp(sh0) + exp(sh1));
        double y0 = (sh0 - lsum) - g_gum[(size_t)t * (NB * 2) + b * 2 + 0];
        double y1 = (sh1 - lsum) - g_gum[(size_t)t * (NB * 2) + b * 2 + 1];
        double xx0 = y0 / 1e-5, xx1 = y1 / 1e-5;
        double mm = fmax(xx0, xx1);
        double e0 = exp(xx0 - mm), e1 = exp(xx1 - mm);
        double inv = 1.0 / (e0 + e1);
        skipsh[0] = e0 * inv; skipsh[1] = e1 * inv;
    }
    __syncthreads();
    double s0 = skipsh[0], s1 = skipsh[1];
    bool isFinal = (t == lengths[b] - 1);
#pragma unroll
    for (int e = 0; e < 2; ++e) {
        int j = tid + 256 * e;
        size_t ix = (size_t)b * ND + j;
        double gi = (double)gb[j], gf = (double)gb[ND + j];
        double gg = (double)gb[2*ND + j], go = (double)gb[3*ND + j];
        double cn = sigd(gf) * g_c[ix] + sigd(gi) * tanh(gg);
        double shx = sigd(go) * tanh(cn);
        double hn = g_hx[ix] * s1 + shx * s0;
        g_c[ix] = cn; g_hx[ix] = hn;
        u16 w0, w1, w2x; decomp3((float)hn, w0, w1, w2x);
        g_hxb[ix] = w0; g_hxb[PSH + ix] = w1; g_hxb[2 * PSH + ix] = w2x;
        if (isFinal) g_final[ix] = hn;
    }
}

// ---------------- persistent weights-stationary cooperative loop ----------------
// grid = 160 blocks; block i owns cols [16i,16i+16) of Wstep (LDS-resident),
// computes gbufF[all 128 rows][its cols] per step; block b<128 owns row b's
// state (hx,c in REGISTERS) for phase B.
__global__ __launch_bounds__(256) void loop_fused(const float* __restrict__ W2,
                                                  const float* __restrict__ b2,
                                                  const int* __restrict__ lengths,
                                                  int steps, int probe) {
    cooperative_groups::grid_group grid = cooperative_groups::this_grid();
    __shared__ __align__(16) unsigned char shm[53376];
    int bid = blockIdx.x, tid = threadIdx.x;
    int nc0 = bid * 16;
    int lane = tid & 63, wave = tid >> 6;
    int lr = lane & 15, lk = lane >> 4;
    int path = g_ok && !g_badfused;
    double c0 = 0.0, c1 = 0.0, h0 = 0.0, h1 = 0.0;   // register state (row = bid)
    if (!probe && bid < NB) {
        size_t ix0 = (size_t)bid * ND + tid, ix1 = ix0 + 256;
        c0 = g_c[ix0]; c1 = g_c[ix1];                 // zeros from init_state
        h0 = g_hx[ix0]; h1 = g_hx[ix1];
    }
    int mylen = (bid < NB) ? lengths[bid] : -1;
    u16*    Wl     = (u16*)shm;                       // [3][16kk][64lane][8]
    double* red    = (double*)(shm + 49152);          // [8]
    double* skipsh = (double*)(shm + 49152 + 64);     // [2]
    if (path) {
        for (int i = tid; i < 3072; i += 256) {
            int p = i >> 10, rem = i & 1023, kk = rem >> 6, l = rem & 63;
            int col = l & 15, k8 = l >> 4;
            *(uint4*)(void*)(Wl + (size_t)p*8192 + kk*512 + l*8) =
                *(const uint4*)(const void*)(g_Wstepb + (size_t)p*PSWS
                      + (size_t)(nc0 + col)*ND + kk*32 + k8*8);
        }
    } else {
        float* Wf = (float*)shm;                      // [16 cols][512]
        for (int i = tid; i < 16*512; i += 256)
            Wf[i] = g_Wstep[(size_t)(nc0 + (i >> 9))*ND + (i & 511)];
    }
    __syncthreads();
    for (int t = 0; t < steps; ++t) {
        // ---- phase A: gbufF[all rows][nc0..nc0+15] ----
        if (path) {
            f4v z = {0.f,0.f,0.f,0.f};
            f4v aP0=z,aC0=z,aP1=z,aC1=z;
            size_t ha0 = (size_t)(32*wave + lr) * ND;
            size_t ha1 = ha0 + (size_t)16 * ND;
            for (int kk = 0; kk < 16; ++kk) {
                int kb = kk*32 + 8*lk;
                s8v A00 = *(const s8v*)(const void*)(g_hxb + ha0 + kb);
                s8v A01 = *(const s8v*)(const void*)(g_hxb + PSH + ha0 + kb);
                s8v A02 = *(const s8v*)(const void*)(g_hxb + 2*PSH + ha0 + kb);
                s8v A10 = *(const s8v*)(const void*)(g_hxb + ha1 + kb);
                s8v A11 = *(const s8v*)(const void*)(g_hxb + PSH + ha1 + kb);
                s8v A12 = *(const s8v*)(const void*)(g_hxb + 2*PSH + ha1 + kb);
                const u16* wp = Wl + kk*512 + lane*8;
                s8v B0 = *(const s8v*)(const void*)(wp);
                s8v B1 = *(const s8v*)(const void*)(wp + 8192);
                s8v B2 = *(const s8v*)(const void*)(wp + 16384);
                STEP6(aP0,aC0, A00,A01,A02, B0,B1,B2)
                STEP6(aP1,aC1, A10,A11,A12, B0,B1,B2)
            }
            int r0 = 32*wave + 4*lk;
#pragma unroll
            for (int r = 0; r < 4; ++r) {
                g_gbufF[(size_t)(r0 + r) * NC + nc0 + lr] = aP0[r] + aC0[r]
                    + g_Pre[((size_t)t * NB + r0 + r) * NC + nc0 + lr];
                g_gbufF[(size_t)(r0 + 16 + r) * NC + nc0 + lr] = aP1[r] + aC1[r]
                    + g_Pre[((size_t)t * NB + r0 + 16 + r) * NC + nc0 + lr];
            }
        } else {
            const float* Wf = (const float*)shm;
            int col = tid & 15, rbase = (tid >> 4) * 8;
            for (int rr = 0; rr < 8; ++rr) {
                int row = rbase + rr;
                const double* hr = g_hx + (size_t)row * ND;
                double dot = 0.0;
                for (int k = 0; k < ND; ++k) dot += hr[k] * (double)Wf[col*ND + k];
                g_gbufF[(size_t)row * NC + nc0 + col] = (float)(dot
                    + (double)g_Pre[((size_t)t * NB + row) * NC + nc0 + col]);
            }
        }
        grid.sync();
        // ---- phase B: row bid update on register state ----
        if (!probe && bid < NB) {
            const float* gb = g_gbufF + (size_t)bid * NC;
            double p0 = 0.0, p1 = 0.0;
            for (int j = tid; j < ND; j += 256) {
                double h = (double)gb[2048 + j];
                h = h > 0.0 ? h : 0.0;
                p0 += h * (double)W2[j];
                p1 += h * (double)W2[ND + j];
            }
            for (int off = 32; off > 0; off >>= 1) {
                p0 += __shfl_down(p0, off, 64);
                p1 += __shfl_down(p1, off, 64);
            }
            if (lane == 0) { red[wave*2] = p0; red[wave*2+1] = p1; }
            __syncthreads();
            if (tid == 0) {
                double l0 = red[0]+red[2]+red[4]+red[6] + (double)b2[0];
                double l1 = red[1]+red[3]+red[5]+red[7] + (double)b2[1];
                double mx = fmax(l0, l1);
                double sh0 = l0 - mx, sh1 = l1 - mx;
                double lsum = log(exp(sh0) + exp(sh1));
                double y0 = (sh0 - lsum) - g_gum[(size_t)t * (NB * 2) + bid * 2 + 0];
                double y1 = (sh1 - lsum) - g_gum[(size_t)t * (NB * 2) + bid * 2 + 1];
                double xx0 = y0 / 1e-5, xx1 = y1 / 1e-5;
                double mm = fmax(xx0, xx1);
                double e0 = exp(xx0 - mm), e1 = exp(xx1 - mm);
                double inv = 1.0 / (e0 + e1);
                skipsh[0] = e0 * inv; skipsh[1] = e1 * inv;
            }
            __syncthreads();
            double s0 = skipsh[0], s1 = skipsh[1];
            bool isFinal = (t == mylen - 1);
#define CELLUPD(J, CREG, HREG)                                                     \
            {                                                                      \
                int j = (J);                                                       \
                size_t ix = (size_t)bid * ND + j;                                  \
                double gi = (double)gb[j], gf = (double)gb[ND + j];                \
                double gg = (double)gb[2*ND + j], go = (double)gb[3*ND + j];       \
                double cn = sigd(gf) * CREG + sigd(gi) * tanh(gg);                 \
                double shx = sigd(go) * tanh(cn);                                  \
                double hn = HREG * s1 + shx * s0;                                  \
                CREG = cn; HREG = hn;                                              \
                g_hx[ix] = hn;                                                     \
                u16 w0, w1, w2x; decomp3((float)hn, w0, w1, w2x);                  \
                g_hxb[ix] = w0; g_hxb[PSH + ix] = w1; g_hxb[2 * PSH + ix] = w2x;   \
                if (isFinal) g_final[ix] = hn;                                     \
            }
            CELLUPD(tid,       c0, h0)
            CELLUPD(tid + 256, c1, h1)
#undef CELLUPD
        }
        grid.sync();
    }
}

// ---------------- final projection ----------------
__global__ __launch_bounds__(256) void final_out(const float* __restrict__ Wo,
                                                 const float* __restrict__ bo,
                                                 float* __restrict__ out) {
    int tid = threadIdx.x;
    int b = tid >> 1, k = tid & 1;
    double acc = 0.0;
    const double* f = g_final + (size_t)b * ND;
    const float* w = Wo + (size_t)k * ND;
    for (int d = 0; d < ND; ++d) acc += f[d] * (double)w[d];
    out[b * 2 + k] = (float)(acc + (double)bo[k]);
}

// ---------------- host launcher ----------------
extern "C" void kernel_launch(void* const* d_in, const int* in_sizes, int n_in,
                              void* d_out, int out_size, void* d_ws, size_t ws_size,
                              hipStream_t stream) {
    (void)in_sizes; (void)n_in; (void)d_ws; (void)ws_size; (void)out_size;
    const int*   seqs    = (const int*)d_in[0];
    const int*   lengths = (const int*)d_in[2];
    const float* emb     = (const float*)d_in[5];
    const float* revWih  = (const float*)d_in[6];
    const float* revWhh  = (const float*)d_in[7];
    const float* convw   = (const float*)d_in[8];
    const float* W1      = (const float*)d_in[9];
    const float* b1      = (const float*)d_in[10];
    const float* W2      = (const float*)d_in[11];
    const float* b2      = (const float*)d_in[12];
    const float* cWih    = (const float*)d_in[13];
    const float* cWhh    = (const float*)d_in[14];
    const float* Wo      = (const float*)d_in[15];
    const float* bo      = (const float*)d_in[16];
    float* out = (float*)d_out;

    double *A_p = nullptr, *Ap_p = nullptr;
    hipGetSymbolAddress((void**)&A_p,  HIP_SYMBOL(g_A));
    hipGetSymbolAddress((void**)&Ap_p, HIP_SYMBOL(g_Aproj));

    probe_bf16<<<1, 64, 0, stream>>>();
    build_w<<<NC, 256, 0, stream>>>(cWih, cWhh, W1, b1);
    gumbel_init<<<256, 256, 0, stream>>>();
    embed_sum<<<NBS, 128, 0, stream>>>(seqs, emb);

    gemm_f64<<<dim3(NBS / 64, 1), 256, 0, stream>>>(A_p, KE, revWih, ND, Ap_p, 40,
                                                    NBS, 40, ND);
    rev_lstm<<<NB, 64, 0, stream>>>(revWhh);
    conv_relu<<<dim3(NB, NS / 8), 256, 0, stream>>>(convw);
    decomp_A<<<4096, 256, 0, stream>>>();

    big_gemm<<<dim3(NC / 64, NBS / 64), 256, 0, stream>>>();
    verify_pre<<<32, 256, 0, stream>>>();
    big_fix<<<2048, 256, 0, stream>>>();

    // probes on synthetic state
    synth_hx<<<256, 256, 0, stream>>>();
    step_gemm<<<dim3(4, 40), 256, 0, stream>>>(0, 1);
    verify_step<<<8, 256, 0, stream>>>();
    {   // fused phase-A probe (1 step, no state writes)
        int steps1 = 1, probe1 = 1;
        void* pargs[] = { (void*)&W2, (void*)&b2, (void*)&lengths,
                          (void*)&steps1, (void*)&probe1 };
        hipError_t pe = hipLaunchCooperativeKernel((const void*)loop_fused,
                                                   dim3(160), dim3(256), pargs, 0, stream);
        if (pe == hipSuccess) verify_fused<<<8, 256, 0, stream>>>();
        else (void)hipGetLastError();
    }
    init_state<<<256, 256, 0, stream>>>();

    int stepsN = NS, probe0 = 0;
    void* args[] = { (void*)&W2, (void*)&b2, (void*)&lengths,
                     (void*)&stepsN, (void*)&probe0 };
    hipError_t ce = hipLaunchCooperativeKernel((const void*)loop_fused,
                                               dim3(160), dim3(256), args, 0, stream);
    if (ce != hipSuccess) {
        (void)hipGetLastError();
        for (int t = 0; t < NS; ++t) {
            step_gemm<<<dim3(4, 40), 256, 0, stream>>>(t, 0);
            step_update<<<NB, 256, 0, stream>>>(W2, b2, lengths, t);
        }
    }
    final_out<<<1, 256, 0, stream>>>(Wo, bo, out);
}

// Round 10
// 12765.375 us; speedup vs baseline: 1.4620x; 1.3195x over previous
//
#include <hip/hip_runtime.h>
#include <math.h>

#define NB 128
#define NS 256
#define ND 512
#define NBS (NB*NS)   // 32768
#define KE 544        // 512 x | 10 back | 20 cnn | 1 bias | 1 pad
#define NC 2560       // 2048 cell gates + 512 leap hidden

typedef unsigned short u16;
typedef __attribute__((ext_vector_type(8))) short s8v;   // 8 bf16
typedef __attribute__((ext_vector_type(4))) float f4v;   // 4 f32 acc

static constexpr size_t PSA  = (size_t)NBS * KE;
static constexpr size_t PSWE = (size_t)NC  * KE;
static constexpr size_t PSWS = (size_t)NC  * ND;
static constexpr size_t PSH  = (size_t)NB  * ND;

// ---------------- device-global scratch ----------------
__device__ double g_A[(size_t)NBS * KE];
__device__ u16    g_Ab[3 * PSA];
__device__ float  g_Pre[(size_t)NBS * NC];    // layout [t][b][n]
__device__ double g_Aproj[(size_t)NBS * 40];
__device__ double g_gum[NS * NB * 2];
__device__ double g_hx[NB * ND];
__device__ u16    g_hxb[3 * NB * ND];
__device__ double g_c[NB * ND];
__device__ float  g_gbufF[NB * NC];
__device__ double g_final[NB * ND];
__device__ float  g_Wext[PSWE];
__device__ u16    g_Wextb[3 * PSWE];
__device__ float  g_Wstep[PSWS];
__device__ u16    g_Wstepb[3 * PSWS];
__device__ int    g_ok, g_bad, g_badstep, g_badfused;
__device__ int    g_barCnt;

__device__ __forceinline__ double sigd(double x) { return 1.0 / (1.0 + exp(-x)); }
__device__ __forceinline__ u16 f2bf(float f) {
    unsigned u = __float_as_uint(f);
    return (u16)((u + 0x7FFFu + ((u >> 16) & 1u)) >> 16);   // RNE
}
__device__ __forceinline__ float bf2f(u16 b) { return __uint_as_float(((unsigned)b) << 16); }
__device__ __forceinline__ void decomp3(float f, u16& b0, u16& b1, u16& b2) {
    b0 = f2bf(f); float r1 = f - bf2f(b0);
    b1 = f2bf(r1); float r2 = r1 - bf2f(b1);
    b2 = f2bf(r2);
}
__device__ __forceinline__ size_t pre_ix(int m /*b*NS+s*/, int n) {
    return ((size_t)(m & 255) * NB + (m >> 8)) * NC + n;    // -> [s][b][n]
}
__device__ __forceinline__ void put_Ab(size_t ix, float f) {
    u16 b0, b1, b2; decomp3(f, b0, b1, b2);
    g_Ab[ix] = b0; g_Ab[PSA + ix] = b1; g_Ab[2 * PSA + ix] = b2;
}

// custom grid barrier: monotonic counter, agent-scope fences only
__device__ __forceinline__ void gbar(int target) {
    __syncthreads();
    if (threadIdx.x == 0) {
        __builtin_amdgcn_fence(__ATOMIC_RELEASE, "agent");
        atomicAdd(&g_barCnt, 1);
        while (__hip_atomic_load(&g_barCnt, __ATOMIC_RELAXED, __HIP_MEMORY_SCOPE_AGENT) < target)
            __builtin_amdgcn_s_sleep(2);
        __builtin_amdgcn_fence(__ATOMIC_ACQUIRE, "agent");
    }
    __syncthreads();
}

#define MFMA_BF16 __builtin_amdgcn_mfma_f32_16x16x32_bf16
#define STEP6(AP,AC,A0,A1,A2,B0,B1,B2) \
    AP = MFMA_BF16(A0, B0, AP, 0, 0, 0); \
    AC = MFMA_BF16(A0, B1, AC, 0, 0, 0); \
    AC = MFMA_BF16(A1, B0, AC, 0, 0, 0); \
    AC = MFMA_BF16(A0, B2, AC, 0, 0, 0); \
    AC = MFMA_BF16(A1, B1, AC, 0, 0, 0); \
    AC = MFMA_BF16(A2, B0, AC, 0, 0, 0);

// ---------------- bf16 MFMA layout probe ----------------
__global__ void probe_bf16() {
    int l = threadIdx.x, lr = l & 15, lk = l >> 4;
    s8v a, b;
#pragma unroll
    for (int e = 0; e < 8; ++e) {
        int k = 8 * lk + e;
        a[e] = (short)f2bf((float)(((3 * lr + 7 * k) % 13) + 1));
        b[e] = (short)f2bf((float)(((5 * k + 11 * lr) % 17) + 1));
    }
    f4v d = {0.f, 0.f, 0.f, 0.f};
    d = MFMA_BF16(a, b, d, 0, 0, 0);
    bool okl = true;
#pragma unroll
    for (int r = 0; r < 4; ++r) {
        int row = 4 * lk + r, col = lr;
        int e = 0;
        for (int k = 0; k < 32; ++k)
            e += (((3 * row + 7 * k) % 13) + 1) * (((5 * k + 11 * col) % 17) + 1);
        if (d[r] != (float)e) okl = false;
    }
    unsigned long long vote = __ballot(okl);
    if (l == 0) {
        g_ok = (vote == 0xFFFFFFFFFFFFFFFFull) ? 1 : 0;
        g_bad = 0; g_badstep = 0; g_badfused = 0; g_barCnt = 0;
    }
}

// ---------------- init ----------------
__global__ void init_state() {
    int i = blockIdx.x * 256 + threadIdx.x;
    if (i == 0) g_barCnt = 0;
    if (i < NB * ND) {
        g_hx[i] = 0.0; g_c[i] = 0.0;
        g_hxb[i] = 0; g_hxb[PSH + i] = 0; g_hxb[2 * PSH + i] = 0;
    }
}

// ---------------- weight repack + bf16x3 ----------------
__global__ __launch_bounds__(256) void build_w(const float* __restrict__ cWih,
                                               const float* __restrict__ cWhh,
                                               const float* __restrict__ W1,
                                               const float* __restrict__ b1) {
    int n = blockIdx.x;
    for (int c = threadIdx.x; c < KE; c += 256) {
        float we;
        if (n < 2048) we = (c < 512) ? cWih[(size_t)n * 512 + c] : 0.f;
        else {
            int n2 = n - 2048;
            if      (c < 512)  we = W1[(size_t)n2 * 1054 + 512 + c];
            else if (c < 522)  we = W1[(size_t)n2 * 1054 + 1024 + (c - 512)];
            else if (c < 542)  we = W1[(size_t)n2 * 1054 + 1034 + (c - 522)];
            else if (c == 542) we = b1[n2];
            else               we = 0.f;
        }
        size_t ix = (size_t)n * KE + c;
        g_Wext[ix] = we;
        u16 b0, b1_, b2; decomp3(we, b0, b1_, b2);
        g_Wextb[ix] = b0; g_Wextb[PSWE + ix] = b1_; g_Wextb[2 * PSWE + ix] = b2;
        if (c < 512) {
            float ws = (n < 2048) ? cWhh[(size_t)n * 512 + c]
                                  : W1[(size_t)(n - 2048) * 1054 + c];
            size_t ix2 = (size_t)n * ND + c;
            g_Wstep[ix2] = ws;
            decomp3(ws, b0, b1_, b2);
            g_Wstepb[ix2] = b0; g_Wstepb[PSWS + ix2] = b1_; g_Wstepb[2 * PSWS + ix2] = b2;
        }
    }
}

// ---------------- gumbel: JAX partitionable threefry2x32, key (0,42) ----------------
__device__ __forceinline__ unsigned rotl32(unsigned x, int r) { return (x << r) | (x >> (32 - r)); }

__global__ void gumbel_init() {
    unsigned p = blockIdx.x * 256 + threadIdx.x;
    if (p >= 65536u) return;
    unsigned k0 = 0u, k1 = 42u;
    unsigned ks2 = k0 ^ k1 ^ 0x1BD11BDAu;
    unsigned x0 = 0u, x1 = p;
    x0 += k0; x1 += k1;
#define RND(r) { x0 += x1; x1 = rotl32(x1, (r)); x1 ^= x0; }
    RND(13) RND(15) RND(26) RND(6)
    x0 += k1;  x1 += ks2 + 1u;
    RND(17) RND(29) RND(16) RND(24)
    x0 += ks2; x1 += k0 + 2u;
    RND(13) RND(15) RND(26) RND(6)
    x0 += k0;  x1 += k1 + 3u;
    RND(17) RND(29) RND(16) RND(24)
    x0 += k1;  x1 += ks2 + 4u;
    RND(13) RND(15) RND(26) RND(6)
    x0 += ks2; x1 += k0 + 5u;
#undef RND
    unsigned bits = x0 ^ x1;
    float u = __uint_as_float((bits >> 9) | 0x3f800000u) - 1.0f;
    g_gum[p] = log(-log((double)u + 1e-20) + 1e-20);
}

// ---------------- embedding gather+sum (writes f64 + bf16x3 planes) ----------------
__global__ __launch_bounds__(128) void embed_sum(const int* __restrict__ seqs,
                                                 const float* __restrict__ emb) {
    int bs = blockIdx.x;
    int tid = threadIdx.x;
    __shared__ int idxs[16];
    if (tid < 16) idxs[tid] = seqs[(size_t)bs * 16 + tid];
    __syncthreads();
    double a0 = 0, a1 = 0, a2 = 0, a3 = 0;
    for (int v = 0; v < 16; ++v) {
        const float4* row = (const float4*)(emb + (size_t)idxs[v] * ND);
        float4 e = row[tid];
        a0 += (double)e.x; a1 += (double)e.y; a2 += (double)e.z; a3 += (double)e.w;
    }
    size_t base = (size_t)bs * KE + tid * 4;
    double* o = g_A + base;
    o[0] = a0; o[1] = a1; o[2] = a2; o[3] = a3;
    put_Ab(base + 0, (float)a0); put_Ab(base + 1, (float)a1);
    put_Ab(base + 2, (float)a2); put_Ab(base + 3, (float)a3);
    if (tid == 0) {
        g_A[(size_t)bs * KE + 542] = 1.0; g_A[(size_t)bs * KE + 543] = 0.0;
        put_Ab((size_t)bs * KE + 542, 1.0f); put_Ab((size_t)bs * KE + 543, 0.0f);
    }
}

// ---------------- f64 vector GEMM (Aproj only) ----------------
__global__ __launch_bounds__(256) void gemm_f64(
    const double* __restrict__ A, int lda,
    const float* __restrict__ W, int ldw,
    double* __restrict__ C, int ldc,
    int M, int N, int K) {
    __shared__ double As[16][66];
    __shared__ double Ws[16][66];
    int m0 = blockIdx.x * 64, n0 = blockIdx.y * 64;
    int tid = threadIdx.x, tx = tid & 15, ty = tid >> 4;
    double acc[4][4] = {};
    for (int k0 = 0; k0 < K; k0 += 16) {
        for (int i = tid; i < 1024; i += 256) {
            int r = i >> 4, c = i & 15;
            As[c][r] = (m0 + r < M && k0 + c < K) ? A[(size_t)(m0 + r) * lda + k0 + c] : 0.0;
            Ws[c][r] = (n0 + r < N && k0 + c < K) ? (double)W[(size_t)(n0 + r) * ldw + k0 + c] : 0.0;
        }
        __syncthreads();
#pragma unroll
        for (int kk = 0; kk < 16; ++kk) {
            double a0 = As[kk][ty*4], a1 = As[kk][ty*4+1], a2 = As[kk][ty*4+2], a3 = As[kk][ty*4+3];
            double w0 = Ws[kk][tx*4], w1 = Ws[kk][tx*4+1], w2 = Ws[kk][tx*4+2], w3 = Ws[kk][tx*4+3];
            acc[0][0] += a0*w0; acc[0][1] += a0*w1; acc[0][2] += a0*w2; acc[0][3] += a0*w3;
            acc[1][0] += a1*w0; acc[1][1] += a1*w1; acc[1][2] += a1*w2; acc[1][3] += a1*w3;
            acc[2][0] += a2*w0; acc[2][1] += a2*w1; acc[2][2] += a2*w2; acc[2][3] += a2*w3;
            acc[3][0] += a3*w0; acc[3][1] += a3*w1; acc[3][2] += a3*w2; acc[3][3] += a3*w3;
        }
        __syncthreads();
    }
#pragma unroll
    for (int i = 0; i < 4; ++i)
#pragma unroll
        for (int j = 0; j < 4; ++j) {
            int m = m0 + ty*4 + i, n = n0 + tx*4 + j;
            if (m < M && n < N) C[(size_t)m * ldc + n] = acc[i][j];
        }
}

// ---------------- reverse LSTM (writes f64 + planes) ----------------
__global__ __launch_bounds__(64) void rev_lstm(const float* __restrict__ Whh) {
    int b = blockIdx.x;
    int tid = threadIdx.x;
    __shared__ double h[10], cc[10], g[40], wsh[400];
    for (int i = tid; i < 400; i += 64) wsh[i] = (double)Whh[i];
    if (tid < 10) { h[tid] = 0.0; cc[tid] = 0.0; }
    __syncthreads();
    for (int s = NS - 1; s >= 0; --s) {
        if (tid < 40) {
            double acc = g_Aproj[((size_t)b * NS + s) * 40 + tid];
#pragma unroll
            for (int k = 0; k < 10; ++k) acc += h[k] * wsh[tid * 10 + k];
            g[tid] = acc;
        }
        __syncthreads();
        if (tid < 10) {
            double gi = g[tid], gf = g[10 + tid], gg = g[20 + tid], go = g[30 + tid];
            double cn = sigd(gf) * cc[tid] + sigd(gi) * tanh(gg);
            cc[tid] = cn;
            double hn = sigd(go) * tanh(cn);
            h[tid] = hn;
            size_t ix = ((size_t)b * NS + s) * KE + 512 + tid;
            g_A[ix] = hn;
            put_Ab(ix, (float)hn);
        }
        __syncthreads();
    }
}

// ---------------- conv1d + relu (writes f64 + planes) ----------------
__global__ __launch_bounds__(256) void conv_relu(const float* __restrict__ w) {
    int b = blockIdx.x, s0 = blockIdx.y * 8;
    int tid = threadIdx.x, grp = tid >> 5, lane = tid & 31;
    __shared__ double xs[10][ND];
    for (int i = tid; i < 10 * ND; i += 256) {
        int r = i >> 9, d = i & (ND - 1);
        int s = s0 - 1 + r;
        xs[r][d] = (s >= 0 && s < NS) ? g_A[((size_t)b * NS + s) * KE + d] : 0.0;
    }
    __syncthreads();
    int s = s0 + grp;
    for (int o = 0; o < 20; ++o) {
        const float* wo = w + (size_t)o * 1536;
        double acc = 0.0;
        for (int d = lane; d < ND; d += 32) {
            acc += xs[grp][d]     * (double)wo[d*3]
                 + xs[grp + 1][d] * (double)wo[d*3 + 1]
                 + xs[grp + 2][d] * (double)wo[d*3 + 2];
        }
        for (int m = 16; m > 0; m >>= 1) acc += __shfl_xor(acc, m, 32);
        if (lane == 0) {
            double v = acc > 0.0 ? acc : 0.0;
            size_t ix = ((size_t)b * NS + s) * KE + 522 + o;
            g_A[ix] = v;
            put_Ab(ix, (float)v);
        }
    }
}

// ---------------- big GEMM: g_Pre[t][b][n] = g_A @ g_Wext^T ----------------
__global__ __launch_bounds__(256) void big_gemm() {
    __shared__ __align__(16) unsigned char shm[36864];
    int tid = threadIdx.x;
    int n0 = blockIdx.x * 64, m0 = blockIdx.y * 64;
    if (g_ok) {
        u16* usA = (u16*)shm;
        u16* usB = usA + 9216;
        int lane = tid & 63, wave = tid >> 6;
        int wm = (wave & 1) * 32, wn = (wave >> 1) * 32;
        int lr = lane & 15, lk = lane >> 4;
        f4v z = {0.f,0.f,0.f,0.f};
        f4v aP00=z,aP01=z,aP10=z,aP11=z, aC00=z,aC01=z,aC10=z,aC11=z;
        for (int k0 = 0; k0 < KE; k0 += 32) {
            for (int i = tid; i < 1536; i += 256) {
                if (i < 768) {
                    int p = i >> 8, rem = i & 255, r = rem >> 2, sg = rem & 3;
                    *(uint4*)(void*)(usA + p*3072 + r*48 + sg*8) =
                        *(const uint4*)(const void*)(g_Ab + (size_t)p*PSA + (size_t)(m0+r)*KE + k0 + sg*8);
                } else {
                    int j = i - 768;
                    int p = j >> 8, rem = j & 255, r = rem >> 2, sg = rem & 3;
                    *(uint4*)(void*)(usB + p*3072 + r*48 + sg*8) =
                        *(const uint4*)(const void*)(g_Wextb + (size_t)p*PSWE + (size_t)(n0+r)*KE + k0 + sg*8);
                }
            }
            __syncthreads();
            const u16* pa = usA + (wm + lr) * 48 + 8 * lk;
            const u16* pb = usB + (wn + lr) * 48 + 8 * lk;
            s8v a0_0 = *(const s8v*)(const void*)(pa);
            s8v a0_1 = *(const s8v*)(const void*)(pa + 768);
            s8v a1_0 = *(const s8v*)(const void*)(pa + 3072);
            s8v a1_1 = *(const s8v*)(const void*)(pa + 3840);
            s8v a2_0 = *(const s8v*)(const void*)(pa + 6144);
            s8v a2_1 = *(const s8v*)(const void*)(pa + 6912);
            s8v b0_0 = *(const s8v*)(const void*)(pb);
            s8v b0_1 = *(const s8v*)(const void*)(pb + 768);
            s8v b1_0 = *(const s8v*)(const void*)(pb + 3072);
            s8v b1_1 = *(const s8v*)(const void*)(pb + 3840);
            s8v b2_0 = *(const s8v*)(const void*)(pb + 6144);
            s8v b2_1 = *(const s8v*)(const void*)(pb + 6912);
            STEP6(aP00, aC00, a0_0, a1_0, a2_0, b0_0, b1_0, b2_0)
            STEP6(aP01, aC01, a0_0, a1_0, a2_0, b0_1, b1_1, b2_1)
            STEP6(aP10, aC10, a0_1, a1_1, a2_1, b0_0, b1_0, b2_0)
            STEP6(aP11, aC11, a0_1, a1_1, a2_1, b0_1, b1_1, b2_1)
            __syncthreads();
        }
        int rb = m0 + wm + 4 * lk, cb0 = n0 + wn + lr, cb1 = cb0 + 16;
#pragma unroll
        for (int r = 0; r < 4; ++r) {
            g_Pre[pre_ix(rb + r, cb0)]      = aP00[r] + aC00[r];
            g_Pre[pre_ix(rb + r, cb1)]      = aP01[r] + aC01[r];
            g_Pre[pre_ix(rb + 16 + r, cb0)] = aP10[r] + aC10[r];
            g_Pre[pre_ix(rb + 16 + r, cb1)] = aP11[r] + aC11[r];
        }
    } else {
        double* Asd = (double*)shm;
        double* Wsd = Asd + 64 * 33;
        int tx = tid & 15, ty = tid >> 4;
        double acc[4][4] = {};
        for (int k0 = 0; k0 < KE; k0 += 32) {
            for (int i = tid; i < 2048; i += 256) {
                int r = i >> 5, c = i & 31;
                Asd[r * 33 + c] = g_A[(size_t)(m0 + r) * KE + k0 + c];
                Wsd[r * 33 + c] = (double)g_Wext[(size_t)(n0 + r) * KE + k0 + c];
            }
            __syncthreads();
            for (int kk = 0; kk < 32; ++kk) {
                double a0 = Asd[(ty*4)*33+kk], a1 = Asd[(ty*4+1)*33+kk], a2 = Asd[(ty*4+2)*33+kk], a3 = Asd[(ty*4+3)*33+kk];
                double w0 = Wsd[(tx*4)*33+kk], w1 = Wsd[(tx*4+1)*33+kk], w2 = Wsd[(tx*4+2)*33+kk], w3 = Wsd[(tx*4+3)*33+kk];
                acc[0][0] += a0*w0; acc[0][1] += a0*w1; acc[0][2] += a0*w2; acc[0][3] += a0*w3;
                acc[1][0] += a1*w0; acc[1][1] += a1*w1; acc[1][2] += a1*w2; acc[1][3] += a1*w3;
                acc[2][0] += a2*w0; acc[2][1] += a2*w1; acc[2][2] += a2*w2; acc[2][3] += a2*w3;
                acc[3][0] += a3*w0; acc[3][1] += a3*w1; acc[3][2] += a3*w2; acc[3][3] += a3*w3;
            }
            __syncthreads();
        }
#pragma unroll
        for (int i = 0; i < 4; ++i)
#pragma unroll
            for (int j = 0; j < 4; ++j)
                g_Pre[pre_ix(m0 + ty*4 + i, n0 + tx*4 + j)] = (float)acc[i][j];
    }
}

// ---------------- sample-verify g_Pre ----------------
__global__ void verify_pre() {
    int s = blockIdx.x * 256 + threadIdx.x;
    unsigned m = ((unsigned)s * 2654435761u) & 32767u;
    unsigned n = ((unsigned)s * 40503u + 7u) % 2560u;
    double dot = 0.0;
    const double* ar = g_A + (size_t)m * KE;
    const float*  wr = g_Wext + (size_t)n * KE;
    for (int c = 0; c < KE; ++c) dot += ar[c] * (double)wr[c];
    double got = (double)g_Pre[pre_ix((int)m, (int)n)];
    if (fabs(got - dot) > 1e-4 * (1.0 + fabs(dot))) atomicOr(&g_bad, 1);
}

// ---------------- full vector recompute of g_Pre (only if ok && bad) ----------------
__global__ __launch_bounds__(256) void big_fix() {
    if (!(g_ok && g_bad)) return;
    __shared__ double As[64][33];
    __shared__ double Ws[64][33];
    int tid = threadIdx.x, tx = tid & 15, ty = tid >> 4;
    for (int tile = blockIdx.x; tile < (NC/64) * (NBS/64); tile += gridDim.x) {
        int n0 = (tile % (NC/64)) * 64, m0 = (tile / (NC/64)) * 64;
        double acc[4][4] = {};
        for (int k0 = 0; k0 < KE; k0 += 32) {
            for (int i = tid; i < 2048; i += 256) {
                int r = i >> 5, c = i & 31;
                As[r][c] = g_A[(size_t)(m0 + r) * KE + k0 + c];
                Ws[r][c] = (double)g_Wext[(size_t)(n0 + r) * KE + k0 + c];
            }
            __syncthreads();
            for (int kk = 0; kk < 32; ++kk) {
                double a0 = As[ty*4][kk], a1 = As[ty*4+1][kk], a2 = As[ty*4+2][kk], a3 = As[ty*4+3][kk];
                double w0 = Ws[tx*4][kk], w1 = Ws[tx*4+1][kk], w2 = Ws[tx*4+2][kk], w3 = Ws[tx*4+3][kk];
                acc[0][0] += a0*w0; acc[0][1] += a0*w1; acc[0][2] += a0*w2; acc[0][3] += a0*w3;
                acc[1][0] += a1*w0; acc[1][1] += a1*w1; acc[1][2] += a1*w2; acc[1][3] += a1*w3;
                acc[2][0] += a2*w0; acc[2][1] += a2*w1; acc[2][2] += a2*w2; acc[2][3] += a2*w3;
                acc[3][0] += a3*w0; acc[3][1] += a3*w1; acc[3][2] += a3*w2; acc[3][3] += a3*w3;
            }
            __syncthreads();
        }
#pragma unroll
        for (int i = 0; i < 4; ++i)
#pragma unroll
            for (int j = 0; j < 4; ++j)
                g_Pre[pre_ix(m0 + ty*4 + i, n0 + tx*4 + j)] = (float)acc[i][j];
        __syncthreads();
    }
}

// ---------------- synthetic hx for step probes ----------------
__global__ void synth_hx() {
    int i = blockIdx.x * 256 + threadIdx.x;
    if (i >= NB * ND) return;
    unsigned h = (unsigned)i * 2654435761u;
    float v = (float)((h >> 8) & 0xFFFFu) / 65536.0f - 0.5f;
    g_hx[i] = (double)v;
    u16 b0, b1, b2; decomp3(v, b0, b1, b2);
    g_hxb[i] = b0; g_hxb[PSH + i] = b1; g_hxb[2 * PSH + i] = b2;
}

// ---------------- standalone step GEMM (probe + host-fallback path) ----------------
__global__ __launch_bounds__(256) void step_gemm(int t, int probe) {
    __shared__ double shd[3168];
    int tid = threadIdx.x;
    int m0 = blockIdx.x * 32, n0 = blockIdx.y * 64;
    int use_mfma = g_ok && (probe || !g_badstep);
    if (use_mfma) {
        int lane = tid & 63, wave = tid >> 6;
        int wm = (wave & 1) * 16, wn = (wave >> 1) * 32;
        int lr = lane & 15, lk = lane >> 4;
        size_t ha  = (size_t)(m0 + wm + lr) * ND;
        size_t wb0 = (size_t)(n0 + wn + lr) * ND;
        size_t wb1 = (size_t)(n0 + wn + 16 + lr) * ND;
        f4v z = {0.f,0.f,0.f,0.f};
        f4v aP0=z, aP1=z, aC0=z, aC1=z;
        for (int k0 = 0; k0 < ND; k0 += 32) {
            int kk = k0 + 8 * lk;
            s8v a0  = *(const s8v*)(const void*)(g_hxb + ha + kk);
            s8v a1  = *(const s8v*)(const void*)(g_hxb + PSH + ha + kk);
            s8v a2  = *(const s8v*)(const void*)(g_hxb + 2*PSH + ha + kk);
            s8v b00 = *(const s8v*)(const void*)(g_Wstepb + wb0 + kk);
            s8v b01 = *(const s8v*)(const void*)(g_Wstepb + wb1 + kk);
            s8v b10 = *(const s8v*)(const void*)(g_Wstepb + PSWS + wb0 + kk);
            s8v b11 = *(const s8v*)(const void*)(g_Wstepb + PSWS + wb1 + kk);
            s8v b20 = *(const s8v*)(const void*)(g_Wstepb + 2*PSWS + wb0 + kk);
            s8v b21 = *(const s8v*)(const void*)(g_Wstepb + 2*PSWS + wb1 + kk);
            STEP6(aP0, aC0, a0, a1, a2, b00, b10, b20)
            STEP6(aP1, aC1, a0, a1, a2, b01, b11, b21)
        }
        int rb = m0 + wm + 4 * lk, cb0 = n0 + wn + lr, cb1 = cb0 + 16;
#pragma unroll
        for (int r = 0; r < 4; ++r) {
            g_gbufF[(size_t)(rb + r) * NC + cb0] = aP0[r] + aC0[r]
                + g_Pre[((size_t)t * NB + rb + r) * NC + cb0];
            g_gbufF[(size_t)(rb + r) * NC + cb1] = aP1[r] + aC1[r]
                + g_Pre[((size_t)t * NB + rb + r) * NC + cb1];
        }
    } else {
        double* Asd = shd;
        double* Wsd = shd + 1056;
        int tx = tid & 15, ty = tid >> 4;
        double acc[2][4] = {};
        for (int k0 = 0; k0 < ND; k0 += 32) {
            for (int i = tid; i < 1024; i += 256) {
                int r = i >> 5, c = i & 31;
                Asd[r * 33 + c] = g_hx[(size_t)(m0 + r) * ND + k0 + c];
            }
            for (int i = tid; i < 2048; i += 256) {
                int r = i >> 5, c = i & 31;
                Wsd[r * 33 + c] = (double)g_Wstep[(size_t)(n0 + r) * ND + k0 + c];
            }
            __syncthreads();
            for (int kk = 0; kk < 32; ++kk) {
                double a0 = Asd[(ty*2)*33+kk], a1 = Asd[(ty*2+1)*33+kk];
                double w0 = Wsd[(tx*4)*33+kk], w1 = Wsd[(tx*4+1)*33+kk], w2 = Wsd[(tx*4+2)*33+kk], w3 = Wsd[(tx*4+3)*33+kk];
                acc[0][0] += a0*w0; acc[0][1] += a0*w1; acc[0][2] += a0*w2; acc[0][3] += a0*w3;
                acc[1][0] += a1*w0; acc[1][1] += a1*w1; acc[1][2] += a1*w2; acc[1][3] += a1*w3;
            }
            __syncthreads();
        }
#pragma unroll
        for (int i = 0; i < 2; ++i)
#pragma unroll
            for (int j = 0; j < 4; ++j) {
                int m = m0 + ty*2 + i, n = n0 + tx*4 + j;
                g_gbufF[(size_t)m * NC + n] = (float)(acc[i][j]
                    + (double)g_Pre[((size_t)t * NB + m) * NC + n]);
            }
    }
}

// ---------------- verifiers of gbufF vs f64 dot (t=0, synthetic hx) ----------------
__device__ __forceinline__ void verify_gbuf_core(int* flag) {
    int s = blockIdx.x * 256 + threadIdx.x;
    unsigned m = ((unsigned)s * 2654435761u) & 127u;
    unsigned n = ((unsigned)s * 40503u + 7u) % 2560u;
    double dot = 0.0;
    const double* hr = g_hx + (size_t)m * ND;
    const float*  wr = g_Wstep + (size_t)n * ND;
    for (int c = 0; c < ND; ++c) dot += hr[c] * (double)wr[c];
    dot += (double)g_Pre[(size_t)m * NC + n];
    double got = (double)g_gbufF[(size_t)m * NC + n];
    if (fabs(got - dot) > 1e-4 * (1.0 + fabs(dot))) atomicOr(flag, 1);
}
__global__ void verify_step()  { verify_gbuf_core(&g_badstep); }
__global__ void verify_fused() { verify_gbuf_core(&g_badfused); }

// ---------------- standalone per-step update (host fallback) ----------------
__global__ __launch_bounds__(256) void step_update(
    const float* __restrict__ W2, const float* __restrict__ b2,
    const int* __restrict__ lengths, int t) {
    __shared__ double red[8];
    __shared__ double skipsh[2];
    int b = blockIdx.x, tid = threadIdx.x, lane = tid & 63, wave = tid >> 6;
    const float* gb = g_gbufF + (size_t)b * NC;
    double p0 = 0.0, p1 = 0.0;
    for (int j = tid; j < ND; j += 256) {
        double h = (double)gb[2048 + j];
        h = h > 0.0 ? h : 0.0;
        p0 += h * (double)W2[j];
        p1 += h * (double)W2[ND + j];
    }
    for (int off = 32; off > 0; off >>= 1) {
        p0 += __shfl_down(p0, off, 64);
        p1 += __shfl_down(p1, off, 64);
    }
    if (lane == 0) { red[wave*2] = p0; red[wave*2+1] = p1; }
    __syncthreads();
    if (tid == 0) {
        double l0 = red[0]+red[2]+red[4]+red[6] + (double)b2[0];
        double l1 = red[1]+red[3]+red[5]+red[7] + (double)b2[1];
        double mx = fmax(l0, l1);
        double sh0 = l0 - mx, sh1 = l1 - mx;
        double lsum = log(exp(sh0) + exp(sh1));
        double y0 = (sh0 - lsum) - g_gum[(size_t)t * (NB * 2) + b * 2 + 0];
        double y1 = (sh1 - lsum) - g_gum[(size_t)t * (NB * 2) + b * 2 + 1];
        double xx0 = y0 / 1e-5, xx1 = y1 / 1e-5;
        double mm = fmax(xx0, xx1);
        double e0 = exp(xx0 - mm), e1 = exp(xx1 - mm);
        double inv = 1.0 / (e0 + e1);
        skipsh[0] = e0 * inv; skipsh[1] = e1 * inv;
    }
    __syncthreads();
    double s0 = skipsh[0], s1 = skipsh[1];
    bool isFinal = (t == lengths[b] - 1);
#pragma unroll
    for (int e = 0; e < 2; ++e) {
        int j = tid + 256 * e;
        size_t ix = (size_t)b * ND + j;
        double gi = (double)gb[j], gf = (double)gb[ND + j];
        double gg = (double)gb[2*ND + j], go = (double)gb[3*ND + j];
        double cn = sigd(gf) * g_c[ix] + sigd(gi) * tanh(gg);
        double shx = sigd(go) * tanh(cn);
        double hn = g_hx[ix] * s1 + shx * s0;
        g_c[ix] = cn; g_hx[ix] = hn;
        u16 w0, w1, w2x; decomp3((float)hn, w0, w1, w2x);
        g_hxb[ix] = w0; g_hxb[PSH + ix] = w1; g_hxb[2 * PSH + ix] = w2x;
        if (isFinal) g_final[ix] = hn;
    }
}

// ---------------- persistent weights-stationary cooperative loop ----------------
__global__ __launch_bounds__(256, 1) void loop_fused(const float* __restrict__ W2,
                                                     const float* __restrict__ b2,
                                                     const int* __restrict__ lengths,
                                                     int steps, int probe) {
    __shared__ __align__(16) unsigned char shm[57472];
    int bid = blockIdx.x, tid = threadIdx.x;
    int nblk = gridDim.x;
    int nc0 = bid * 16;
    int lane = tid & 63, wave = tid >> 6;
    int lr = lane & 15, lk = lane >> 4;
    int path = g_ok && !g_badfused;
    double c0 = 0.0, c1 = 0.0, h0 = 0.0, h1 = 0.0;   // register state (row = bid)
    if (!probe && bid < NB) {
        size_t ix0 = (size_t)bid * ND + tid, ix1 = ix0 + 256;
        c0 = g_c[ix0]; c1 = g_c[ix1];
        h0 = g_hx[ix0]; h1 = g_hx[ix1];
    }
    int mylen = (bid < NB) ? lengths[bid] : -1;
    u16*    Wl     = (u16*)shm;                       // 49152 B
    float*  W2l    = (float*)(shm + 49152);           // 4096 B
    double* red    = (double*)(shm + 53248);          // 64 B
    double* skipsh = (double*)(shm + 53312);          // 16 B
    if (path) {
        for (int i = tid; i < 3072; i += 256) {
            int p = i >> 10, rem = i & 1023, kk = rem >> 6, l = rem & 63;
            int col = l & 15, k8 = l >> 4;
            *(uint4*)(void*)(Wl + (size_t)p*8192 + kk*512 + l*8) =
                *(const uint4*)(const void*)(g_Wstepb + (size_t)p*PSWS
                      + (size_t)(nc0 + col)*ND + kk*32 + k8*8);
        }
    } else {
        float* Wf = (float*)shm;                      // [16 cols][512]
        for (int i = tid; i < 16*512; i += 256)
            Wf[i] = g_Wstep[(size_t)(nc0 + (i >> 9))*ND + (i & 511)];
    }
    for (int i = tid; i < 1024; i += 256) W2l[i] = W2[i];
    __syncthreads();
    // initial Pre prefetch (t=0)
    int r0 = 32*wave + 4*lk;
    float preA[4], preB[4];
    if (path) {
#pragma unroll
        for (int r = 0; r < 4; ++r) {
            preA[r] = g_Pre[((size_t)0 * NB + r0 + r) * NC + nc0 + lr];
            preB[r] = g_Pre[((size_t)0 * NB + r0 + 16 + r) * NC + nc0 + lr];
        }
    }
    int nbar = 0;
    for (int t = 0; t < steps; ++t) {
        // ---- phase A ----
        if (path) {
            f4v z = {0.f,0.f,0.f,0.f};
            f4v aP0=z,aC0=z,aP1=z,aC1=z;
            size_t ha0 = (size_t)(32*wave + lr) * ND;
            size_t ha1 = ha0 + (size_t)16 * ND;
#pragma unroll 2
            for (int kk = 0; kk < 16; ++kk) {
                int kb = kk*32 + 8*lk;
                s8v A00 = *(const s8v*)(const void*)(g_hxb + ha0 + kb);
                s8v A01 = *(const s8v*)(const void*)(g_hxb + PSH + ha0 + kb);
                s8v A02 = *(const s8v*)(const void*)(g_hxb + 2*PSH + ha0 + kb);
                s8v A10 = *(const s8v*)(const void*)(g_hxb + ha1 + kb);
                s8v A11 = *(const s8v*)(const void*)(g_hxb + PSH + ha1 + kb);
                s8v A12 = *(const s8v*)(const void*)(g_hxb + 2*PSH + ha1 + kb);
                const u16* wp = Wl + kk*512 + lane*8;
                s8v B0 = *(const s8v*)(const void*)(wp);
                s8v B1 = *(const s8v*)(const void*)(wp + 8192);
                s8v B2 = *(const s8v*)(const void*)(wp + 16384);
                STEP6(aP0,aC0, A00,A01,A02, B0,B1,B2)
                STEP6(aP1,aC1, A10,A11,A12, B0,B1,B2)
            }
#pragma unroll
            for (int r = 0; r < 4; ++r) {
                g_gbufF[(size_t)(r0 + r) * NC + nc0 + lr] = aP0[r] + aC0[r] + preA[r];
                g_gbufF[(size_t)(r0 + 16 + r) * NC + nc0 + lr] = aP1[r] + aC1[r] + preB[r];
            }
            // prefetch next step's Pre slice (in flight across both barriers)
            int tn = (t + 1 < steps) ? t + 1 : t;
#pragma unroll
            for (int r = 0; r < 4; ++r) {
                preA[r] = g_Pre[((size_t)tn * NB + r0 + r) * NC + nc0 + lr];
                preB[r] = g_Pre[((size_t)tn * NB + r0 + 16 + r) * NC + nc0 + lr];
            }
        } else {
            const float* Wf = (const float*)shm;
            int col = tid & 15, rbase = (tid >> 4) * 8;
            for (int rr = 0; rr < 8; ++rr) {
                int row = rbase + rr;
                const double* hr = g_hx + (size_t)row * ND;
                double dot = 0.0;
                for (int k = 0; k < ND; ++k) dot += hr[k] * (double)Wf[col*ND + k];
                g_gbufF[(size_t)row * NC + nc0 + col] = (float)(dot
                    + (double)g_Pre[((size_t)t * NB + row) * NC + nc0 + col]);
            }
        }
        gbar(++nbar * nblk);
        // ---- phase B: row bid update on register state ----
        if (!probe && bid < NB) {
            const float* gb = g_gbufF + (size_t)bid * NC;
            double p0 = 0.0, p1 = 0.0;
            for (int j = tid; j < ND; j += 256) {
                double h = (double)gb[2048 + j];
                h = h > 0.0 ? h : 0.0;
                p0 += h * (double)W2l[j];
                p1 += h * (double)W2l[ND + j];
            }
            for (int off = 32; off > 0; off >>= 1) {
                p0 += __shfl_down(p0, off, 64);
                p1 += __shfl_down(p1, off, 64);
            }
            if (lane == 0) { red[wave*2] = p0; red[wave*2+1] = p1; }
            __syncthreads();
            if (tid == 0) {
                double l0 = red[0]+red[2]+red[4]+red[6] + (double)b2[0];
                double l1 = red[1]+red[3]+red[5]+red[7] + (double)b2[1];
                double mx = fmax(l0, l1);
                double sh0 = l0 - mx, sh1 = l1 - mx;
                double lsum = log(exp(sh0) + exp(sh1));
                double y0 = (sh0 - lsum) - g_gum[(size_t)t * (NB * 2) + bid * 2 + 0];
                double y1 = (sh1 - lsum) - g_gum[(size_t)t * (NB * 2) + bid * 2 + 1];
                double xx0 = y0 / 1e-5, xx1 = y1 / 1e-5;
                double mm = fmax(xx0, xx1);
                double e0 = exp(xx0 - mm), e1 = exp(xx1 - mm);
                double inv = 1.0 / (e0 + e1);
                skipsh[0] = e0 * inv; skipsh[1] = e1 * inv;
            }
            __syncthreads();
            double s0 = skipsh[0], s1 = skipsh[1];
            bool isFinal = (t == mylen - 1);
#define CELLUPD(J, CREG, HREG)                                                     \
            {                                                                      \
                int j = (J);                                                       \
                size_t ix = (size_t)bid * ND + j;                                  \
                double gi = (double)gb[j], gf = (double)gb[ND + j];                \
                double gg = (double)gb[2*ND + j], go = (double)gb[3*ND + j];       \
                double cn = sigd(gf) * CREG + sigd(gi) * tanh(gg);                 \
                double shx = sigd(go) * tanh(cn);                                  \
                double hn = HREG * s1 + shx * s0;                                  \
                CREG = cn; HREG = hn;                                              \
                g_hx[ix] = hn;                                                     \
                u16 w0, w1, w2x; decomp3((float)hn, w0, w1, w2x);                  \
                g_hxb[ix] = w0; g_hxb[PSH + ix] = w1; g_hxb[2 * PSH + ix] = w2x;   \
                if (isFinal) g_final[ix] = hn;                                     \
            }
            CELLUPD(tid,       c0, h0)
            CELLUPD(tid + 256, c1, h1)
#undef CELLUPD
        }
        gbar(++nbar * nblk);
    }
}

// ---------------- final projection ----------------
__global__ __launch_bounds__(256) void final_out(const float* __restrict__ Wo,
                                                 const float* __restrict__ bo,
                                                 float* __restrict__ out) {
    int tid = threadIdx.x;
    int b = tid >> 1, k = tid & 1;
    double acc = 0.0;
    const double* f = g_final + (size_t)b * ND;
    const float* w = Wo + (size_t)k * ND;
    for (int d = 0; d < ND; ++d) acc += f[d] * (double)w[d];
    out[b * 2 + k] = (float)(acc + (double)bo[k]);
}

// ---------------- host launcher ----------------
extern "C" void kernel_launch(void* const* d_in, const int* in_sizes, int n_in,
                              void* d_out, int out_size, void* d_ws, size_t ws_size,
                              hipStream_t stream) {
    (void)in_sizes; (void)n_in; (void)d_ws; (void)ws_size; (void)out_size;
    const int*   seqs    = (const int*)d_in[0];
    const int*   lengths = (const int*)d_in[2];
    const float* emb     = (const float*)d_in[5];
    const float* revWih  = (const float*)d_in[6];
    const float* revWhh  = (const float*)d_in[7];
    const float* convw   = (const float*)d_in[8];
    const float* W1      = (const float*)d_in[9];
    const float* b1      = (const float*)d_in[10];
    const float* W2      = (const float*)d_in[11];
    const float* b2      = (const float*)d_in[12];
    const float* cWih    = (const float*)d_in[13];
    const float* cWhh    = (const float*)d_in[14];
    const float* Wo      = (const float*)d_in[15];
    const float* bo      = (const float*)d_in[16];
    float* out = (float*)d_out;

    double *A_p = nullptr, *Ap_p = nullptr;
    hipGetSymbolAddress((void**)&A_p,  HIP_SYMBOL(g_A));
    hipGetSymbolAddress((void**)&Ap_p, HIP_SYMBOL(g_Aproj));

    probe_bf16<<<1, 64, 0, stream>>>();
    build_w<<<NC, 256, 0, stream>>>(cWih, cWhh, W1, b1);
    gumbel_init<<<256, 256, 0, stream>>>();
    embed_sum<<<NBS, 128, 0, stream>>>(seqs, emb);

    gemm_f64<<<dim3(NBS / 64, 1), 256, 0, stream>>>(A_p, KE, revWih, ND, Ap_p, 40,
                                                    NBS, 40, ND);
    rev_lstm<<<NB, 64, 0, stream>>>(revWhh);
    conv_relu<<<dim3(NB, NS / 8), 256, 0, stream>>>(convw);

    big_gemm<<<dim3(NC / 64, NBS / 64), 256, 0, stream>>>();
    verify_pre<<<32, 256, 0, stream>>>();
    big_fix<<<2048, 256, 0, stream>>>();

    // probes on synthetic state
    synth_hx<<<256, 256, 0, stream>>>();
    step_gemm<<<dim3(4, 40), 256, 0, stream>>>(0, 1);
    verify_step<<<8, 256, 0, stream>>>();
    {   // fused phase-A probe (1 step, no state writes)
        int steps1 = 1, probe1 = 1;
        void* pargs[] = { (void*)&W2, (void*)&b2, (void*)&lengths,
                          (void*)&steps1, (void*)&probe1 };
        hipError_t pe = hipLaunchCooperativeKernel((const void*)loop_fused,
                                                   dim3(160), dim3(256), pargs, 0, stream);
        if (pe == hipSuccess) verify_fused<<<8, 256, 0, stream>>>();
        else (void)hipGetLastError();
    }
    init_state<<<256, 256, 0, stream>>>();   // also resets g_barCnt

    int stepsN = NS, probe0 = 0;
    void* args[] = { (void*)&W2, (void*)&b2, (void*)&lengths,
                     (void*)&stepsN, (void*)&probe0 };
    hipError_t ce = hipLaunchCooperativeKernel((const void*)loop_fused,
                                               dim3(160), dim3(256), args, 0, stream);
    if (ce != hipSuccess) {
        (void)hipGetLastError();
        for (int t = 0; t < NS; ++t) {
            step_gemm<<<dim3(4, 40), 256, 0, stream>>>(t, 0);
            step_update<<<NB, 256, 0, stream>>>(W2, b2, lengths, t);
        }
    }
    final_out<<<1, 256, 0, stream>>>(Wo, bo, out);
}

// Round 11
// 12519.881 us; speedup vs baseline: 1.4907x; 1.0196x over previous
//
#include <hip/hip_runtime.h>
#include <math.h>

#define NB 128
#define NS 256
#define ND 512
#define NBS (NB*NS)   // 32768
#define KE 544        // 512 x | 10 back | 20 cnn | 1 bias | 1 pad
#define NC 2560       // 2048 cell gates + 512 leap hidden

typedef unsigned short u16;
typedef __attribute__((ext_vector_type(8))) short s8v;   // 8 bf16
typedef __attribute__((ext_vector_type(4))) float f4v;   // 4 f32 acc

static constexpr size_t PSA  = (size_t)NBS * KE;
static constexpr size_t PSWE = (size_t)NC  * KE;
static constexpr size_t PSWS = (size_t)NC  * ND;
static constexpr size_t PSH  = (size_t)NB  * ND;

// ---------------- device-global scratch ----------------
__device__ double g_A[(size_t)NBS * KE];
__device__ u16    g_Ab[3 * PSA];
__device__ float  g_Pre[(size_t)NBS * NC];    // layout [t][b][n]
__device__ double g_Aproj[(size_t)NBS * 40];
__device__ double g_gum[NS * NB * 2];
__device__ double g_hx[NB * ND];
__device__ u16    g_hxb[3 * NB * ND];
__device__ double g_c[NB * ND];
__device__ float  g_gbufF[NB * NC];           // fused path uses [128][2048] gates region
__device__ double g_final[NB * ND];
__device__ float  g_Wext[PSWE];
__device__ u16    g_Wextb[3 * PSWE];
__device__ float  g_Wstep[PSWS];
__device__ u16    g_Wstepb[3 * PSWS];
__device__ double g_lpart[32][NB][2];         // leap partial logits
__device__ int    g_aflag[160 * 32];          // per-block A-completion (128B apart)
__device__ int    g_hxf[NB * 32];             // per-row B-completion
__device__ int    g_ok, g_bad, g_badstep, g_badfused;

__device__ __forceinline__ double sigd(double x) { return 1.0 / (1.0 + exp(-x)); }
__device__ __forceinline__ u16 f2bf(float f) {
    unsigned u = __float_as_uint(f);
    return (u16)((u + 0x7FFFu + ((u >> 16) & 1u)) >> 16);   // RNE
}
__device__ __forceinline__ float bf2f(u16 b) { return __uint_as_float(((unsigned)b) << 16); }
__device__ __forceinline__ void decomp3(float f, u16& b0, u16& b1, u16& b2) {
    b0 = f2bf(f); float r1 = f - bf2f(b0);
    b1 = f2bf(r1); float r2 = r1 - bf2f(b1);
    b2 = f2bf(r2);
}
__device__ __forceinline__ size_t pre_ix(int m /*b*NS+s*/, int n) {
    return ((size_t)(m & 255) * NB + (m >> 8)) * NC + n;    // -> [s][b][n]
}
__device__ __forceinline__ void put_Ab(size_t ix, float f) {
    u16 b0, b1, b2; decomp3(f, b0, b1, b2);
    g_Ab[ix] = b0; g_Ab[PSA + ix] = b1; g_Ab[2 * PSA + ix] = b2;
}

#define MFMA_BF16 __builtin_amdgcn_mfma_f32_16x16x32_bf16
#define STEP6(AP,AC,A0,A1,A2,B0,B1,B2) \
    AP = MFMA_BF16(A0, B0, AP, 0, 0, 0); \
    AC = MFMA_BF16(A0, B1, AC, 0, 0, 0); \
    AC = MFMA_BF16(A1, B0, AC, 0, 0, 0); \
    AC = MFMA_BF16(A0, B2, AC, 0, 0, 0); \
    AC = MFMA_BF16(A1, B1, AC, 0, 0, 0); \
    AC = MFMA_BF16(A2, B0, AC, 0, 0, 0);

// ---------------- bf16 MFMA layout probe ----------------
__global__ void probe_bf16() {
    int l = threadIdx.x, lr = l & 15, lk = l >> 4;
    s8v a, b;
#pragma unroll
    for (int e = 0; e < 8; ++e) {
        int k = 8 * lk + e;
        a[e] = (short)f2bf((float)(((3 * lr + 7 * k) % 13) + 1));
        b[e] = (short)f2bf((float)(((5 * k + 11 * lr) % 17) + 1));
    }
    f4v d = {0.f, 0.f, 0.f, 0.f};
    d = MFMA_BF16(a, b, d, 0, 0, 0);
    bool okl = true;
#pragma unroll
    for (int r = 0; r < 4; ++r) {
        int row = 4 * lk + r, col = lr;
        int e = 0;
        for (int k = 0; k < 32; ++k)
            e += (((3 * row + 7 * k) % 13) + 1) * (((5 * k + 11 * col) % 17) + 1);
        if (d[r] != (float)e) okl = false;
    }
    unsigned long long vote = __ballot(okl);
    if (l == 0) {
        g_ok = (vote == 0xFFFFFFFFFFFFFFFFull) ? 1 : 0;
        g_bad = 0; g_badstep = 0; g_badfused = 0;
    }
}

// ---------------- init (state + sync flags) ----------------
__global__ void init_state() {
    int i = blockIdx.x * 256 + threadIdx.x;
    if (i < 160 * 32) g_aflag[i] = 0;
    if (i < NB * 32)  g_hxf[i]  = 0;
    if (i < NB * ND) {
        g_hx[i] = 0.0; g_c[i] = 0.0;
        g_hxb[i] = 0; g_hxb[PSH + i] = 0; g_hxb[2 * PSH + i] = 0;
    }
}

// ---------------- weight repack + bf16x3 ----------------
__global__ __launch_bounds__(256) void build_w(const float* __restrict__ cWih,
                                               const float* __restrict__ cWhh,
                                               const float* __restrict__ W1,
                                               const float* __restrict__ b1) {
    int n = blockIdx.x;
    for (int c = threadIdx.x; c < KE; c += 256) {
        float we;
        if (n < 2048) we = (c < 512) ? cWih[(size_t)n * 512 + c] : 0.f;
        else {
            int n2 = n - 2048;
            if      (c < 512)  we = W1[(size_t)n2 * 1054 + 512 + c];
            else if (c < 522)  we = W1[(size_t)n2 * 1054 + 1024 + (c - 512)];
            else if (c < 542)  we = W1[(size_t)n2 * 1054 + 1034 + (c - 522)];
            else if (c == 542) we = b1[n2];
            else               we = 0.f;
        }
        size_t ix = (size_t)n * KE + c;
        g_Wext[ix] = we;
        u16 b0, b1_, b2; decomp3(we, b0, b1_, b2);
        g_Wextb[ix] = b0; g_Wextb[PSWE + ix] = b1_; g_Wextb[2 * PSWE + ix] = b2;
        if (c < 512) {
            float ws = (n < 2048) ? cWhh[(size_t)n * 512 + c]
                                  : W1[(size_t)(n - 2048) * 1054 + c];
            size_t ix2 = (size_t)n * ND + c;
            g_Wstep[ix2] = ws;
            decomp3(ws, b0, b1_, b2);
            g_Wstepb[ix2] = b0; g_Wstepb[PSWS + ix2] = b1_; g_Wstepb[2 * PSWS + ix2] = b2;
        }
    }
}

// ---------------- gumbel: JAX partitionable threefry2x32, key (0,42) ----------------
__device__ __forceinline__ unsigned rotl32(unsigned x, int r) { return (x << r) | (x >> (32 - r)); }

__global__ void gumbel_init() {
    unsigned p = blockIdx.x * 256 + threadIdx.x;
    if (p >= 65536u) return;
    unsigned k0 = 0u, k1 = 42u;
    unsigned ks2 = k0 ^ k1 ^ 0x1BD11BDAu;
    unsigned x0 = 0u, x1 = p;
    x0 += k0; x1 += k1;
#define RND(r) { x0 += x1; x1 = rotl32(x1, (r)); x1 ^= x0; }
    RND(13) RND(15) RND(26) RND(6)
    x0 += k1;  x1 += ks2 + 1u;
    RND(17) RND(29) RND(16) RND(24)
    x0 += ks2; x1 += k0 + 2u;
    RND(13) RND(15) RND(26) RND(6)
    x0 += k0;  x1 += k1 + 3u;
    RND(17) RND(29) RND(16) RND(24)
    x0 += k1;  x1 += ks2 + 4u;
    RND(13) RND(15) RND(26) RND(6)
    x0 += ks2; x1 += k0 + 5u;
#undef RND
    unsigned bits = x0 ^ x1;
    float u = __uint_as_float((bits >> 9) | 0x3f800000u) - 1.0f;
    g_gum[p] = log(-log((double)u + 1e-20) + 1e-20);
}

// ---------------- embedding gather+sum (writes f64 + bf16x3 planes) ----------------
__global__ __launch_bounds__(128) void embed_sum(const int* __restrict__ seqs,
                                                 const float* __restrict__ emb) {
    int bs = blockIdx.x;
    int tid = threadIdx.x;
    __shared__ int idxs[16];
    if (tid < 16) idxs[tid] = seqs[(size_t)bs * 16 + tid];
    __syncthreads();
    double a0 = 0, a1 = 0, a2 = 0, a3 = 0;
    for (int v = 0; v < 16; ++v) {
        const float4* row = (const float4*)(emb + (size_t)idxs[v] * ND);
        float4 e = row[tid];
        a0 += (double)e.x; a1 += (double)e.y; a2 += (double)e.z; a3 += (double)e.w;
    }
    size_t base = (size_t)bs * KE + tid * 4;
    double* o = g_A + base;
    o[0] = a0; o[1] = a1; o[2] = a2; o[3] = a3;
    put_Ab(base + 0, (float)a0); put_Ab(base + 1, (float)a1);
    put_Ab(base + 2, (float)a2); put_Ab(base + 3, (float)a3);
    if (tid == 0) {
        g_A[(size_t)bs * KE + 542] = 1.0; g_A[(size_t)bs * KE + 543] = 0.0;
        put_Ab((size_t)bs * KE + 542, 1.0f); put_Ab((size_t)bs * KE + 543, 0.0f);
    }
}

// ---------------- f64 vector GEMM (Aproj only) ----------------
__global__ __launch_bounds__(256) void gemm_f64(
    const double* __restrict__ A, int lda,
    const float* __restrict__ W, int ldw,
    double* __restrict__ C, int ldc,
    int M, int N, int K) {
    __shared__ double As[16][66];
    __shared__ double Ws[16][66];
    int m0 = blockIdx.x * 64, n0 = blockIdx.y * 64;
    int tid = threadIdx.x, tx = tid & 15, ty = tid >> 4;
    double acc[4][4] = {};
    for (int k0 = 0; k0 < K; k0 += 16) {
        for (int i = tid; i < 1024; i += 256) {
            int r = i >> 4, c = i & 15;
            As[c][r] = (m0 + r < M && k0 + c < K) ? A[(size_t)(m0 + r) * lda + k0 + c] : 0.0;
            Ws[c][r] = (n0 + r < N && k0 + c < K) ? (double)W[(size_t)(n0 + r) * ldw + k0 + c] : 0.0;
        }
        __syncthreads();
#pragma unroll
        for (int kk = 0; kk < 16; ++kk) {
            double a0 = As[kk][ty*4], a1 = As[kk][ty*4+1], a2 = As[kk][ty*4+2], a3 = As[kk][ty*4+3];
            double w0 = Ws[kk][tx*4], w1 = Ws[kk][tx*4+1], w2 = Ws[kk][tx*4+2], w3 = Ws[kk][tx*4+3];
            acc[0][0] += a0*w0; acc[0][1] += a0*w1; acc[0][2] += a0*w2; acc[0][3] += a0*w3;
            acc[1][0] += a1*w0; acc[1][1] += a1*w1; acc[1][2] += a1*w2; acc[1][3] += a1*w3;
            acc[2][0] += a2*w0; acc[2][1] += a2*w1; acc[2][2] += a2*w2; acc[2][3] += a2*w3;
            acc[3][0] += a3*w0; acc[3][1] += a3*w1; acc[3][2] += a3*w2; acc[3][3] += a3*w3;
        }
        __syncthreads();
    }
#pragma unroll
    for (int i = 0; i < 4; ++i)
#pragma unroll
        for (int j = 0; j < 4; ++j) {
            int m = m0 + ty*4 + i, n = n0 + tx*4 + j;
            if (m < M && n < N) C[(size_t)m * ldc + n] = acc[i][j];
        }
}

// ---------------- reverse LSTM (writes f64 + planes) ----------------
__global__ __launch_bounds__(64) void rev_lstm(const float* __restrict__ Whh) {
    int b = blockIdx.x;
    int tid = threadIdx.x;
    __shared__ double h[10], cc[10], g[40], wsh[400];
    for (int i = tid; i < 400; i += 64) wsh[i] = (double)Whh[i];
    if (tid < 10) { h[tid] = 0.0; cc[tid] = 0.0; }
    __syncthreads();
    for (int s = NS - 1; s >= 0; --s) {
        if (tid < 40) {
            double acc = g_Aproj[((size_t)b * NS + s) * 40 + tid];
#pragma unroll
            for (int k = 0; k < 10; ++k) acc += h[k] * wsh[tid * 10 + k];
            g[tid] = acc;
        }
        __syncthreads();
        if (tid < 10) {
            double gi = g[tid], gf = g[10 + tid], gg = g[20 + tid], go = g[30 + tid];
            double cn = sigd(gf) * cc[tid] + sigd(gi) * tanh(gg);
            cc[tid] = cn;
            double hn = sigd(go) * tanh(cn);
            h[tid] = hn;
            size_t ix = ((size_t)b * NS + s) * KE + 512 + tid;
            g_A[ix] = hn;
            put_Ab(ix, (float)hn);
        }
        __syncthreads();
    }
}

// ---------------- conv1d + relu (writes f64 + planes) ----------------
__global__ __launch_bounds__(256) void conv_relu(const float* __restrict__ w) {
    int b = blockIdx.x, s0 = blockIdx.y * 8;
    int tid = threadIdx.x, grp = tid >> 5, lane = tid & 31;
    __shared__ double xs[10][ND];
    for (int i = tid; i < 10 * ND; i += 256) {
        int r = i >> 9, d = i & (ND - 1);
        int s = s0 - 1 + r;
        xs[r][d] = (s >= 0 && s < NS) ? g_A[((size_t)b * NS + s) * KE + d] : 0.0;
    }
    __syncthreads();
    int s = s0 + grp;
    for (int o = 0; o < 20; ++o) {
        const float* wo = w + (size_t)o * 1536;
        double acc = 0.0;
        for (int d = lane; d < ND; d += 32) {
            acc += xs[grp][d]     * (double)wo[d*3]
                 + xs[grp + 1][d] * (double)wo[d*3 + 1]
                 + xs[grp + 2][d] * (double)wo[d*3 + 2];
        }
        for (int m = 16; m > 0; m >>= 1) acc += __shfl_xor(acc, m, 32);
        if (lane == 0) {
            double v = acc > 0.0 ? acc : 0.0;
            size_t ix = ((size_t)b * NS + s) * KE + 522 + o;
            g_A[ix] = v;
            put_Ab(ix, (float)v);
        }
    }
}

// ---------------- big GEMM: g_Pre[t][b][n] = g_A @ g_Wext^T ----------------
__global__ __launch_bounds__(256) void big_gemm() {
    __shared__ __align__(16) unsigned char shm[36864];
    int tid = threadIdx.x;
    int n0 = blockIdx.x * 64, m0 = blockIdx.y * 64;
    if (g_ok) {
        u16* usA = (u16*)shm;
        u16* usB = usA + 9216;
        int lane = tid & 63, wave = tid >> 6;
        int wm = (wave & 1) * 32, wn = (wave >> 1) * 32;
        int lr = lane & 15, lk = lane >> 4;
        f4v z = {0.f,0.f,0.f,0.f};
        f4v aP00=z,aP01=z,aP10=z,aP11=z, aC00=z,aC01=z,aC10=z,aC11=z;
        for (int k0 = 0; k0 < KE; k0 += 32) {
            for (int i = tid; i < 1536; i += 256) {
                if (i < 768) {
                    int p = i >> 8, rem = i & 255, r = rem >> 2, sg = rem & 3;
                    *(uint4*)(void*)(usA + p*3072 + r*48 + sg*8) =
                        *(const uint4*)(const void*)(g_Ab + (size_t)p*PSA + (size_t)(m0+r)*KE + k0 + sg*8);
                } else {
                    int j = i - 768;
                    int p = j >> 8, rem = j & 255, r = rem >> 2, sg = rem & 3;
                    *(uint4*)(void*)(usB + p*3072 + r*48 + sg*8) =
                        *(const uint4*)(const void*)(g_Wextb + (size_t)p*PSWE + (size_t)(n0+r)*KE + k0 + sg*8);
                }
            }
            __syncthreads();
            const u16* pa = usA + (wm + lr) * 48 + 8 * lk;
            const u16* pb = usB + (wn + lr) * 48 + 8 * lk;
            s8v a0_0 = *(const s8v*)(const void*)(pa);
            s8v a0_1 = *(const s8v*)(const void*)(pa + 768);
            s8v a1_0 = *(const s8v*)(const void*)(pa + 3072);
            s8v a1_1 = *(const s8v*)(const void*)(pa + 3840);
            s8v a2_0 = *(const s8v*)(const void*)(pa + 6144);
            s8v a2_1 = *(const s8v*)(const void*)(pa + 6912);
            s8v b0_0 = *(const s8v*)(const void*)(pb);
            s8v b0_1 = *(const s8v*)(const void*)(pb + 768);
            s8v b1_0 = *(const s8v*)(const void*)(pb + 3072);
            s8v b1_1 = *(const s8v*)(const void*)(pb + 3840);
            s8v b2_0 = *(const s8v*)(const void*)(pb + 6144);
            s8v b2_1 = *(const s8v*)(const void*)(pb + 6912);
            STEP6(aP00, aC00, a0_0, a1_0, a2_0, b0_0, b1_0, b2_0)
            STEP6(aP01, aC01, a0_0, a1_0, a2_0, b0_1, b1_1, b2_1)
            STEP6(aP10, aC10, a0_1, a1_1, a2_1, b0_0, b1_0, b2_0)
            STEP6(aP11, aC11, a0_1, a1_1, a2_1, b0_1, b1_1, b2_1)
            __syncthreads();
        }
        int rb = m0 + wm + 4 * lk, cb0 = n0 + wn + lr, cb1 = cb0 + 16;
#pragma unroll
        for (int r = 0; r < 4; ++r) {
            g_Pre[pre_ix(rb + r, cb0)]      = aP00[r] + aC00[r];
            g_Pre[pre_ix(rb + r, cb1)]      = aP01[r] + aC01[r];
            g_Pre[pre_ix(rb + 16 + r, cb0)] = aP10[r] + aC10[r];
            g_Pre[pre_ix(rb + 16 + r, cb1)] = aP11[r] + aC11[r];
        }
    } else {
        double* Asd = (double*)shm;
        double* Wsd = Asd + 64 * 33;
        int tx = tid & 15, ty = tid >> 4;
        double acc[4][4] = {};
        for (int k0 = 0; k0 < KE; k0 += 32) {
            for (int i = tid; i < 2048; i += 256) {
                int r = i >> 5, c = i & 31;
                Asd[r * 33 + c] = g_A[(size_t)(m0 + r) * KE + k0 + c];
                Wsd[r * 33 + c] = (double)g_Wext[(size_t)(n0 + r) * KE + k0 + c];
            }
            __syncthreads();
            for (int kk = 0; kk < 32; ++kk) {
                double a0 = Asd[(ty*4)*33+kk], a1 = Asd[(ty*4+1)*33+kk], a2 = Asd[(ty*4+2)*33+kk], a3 = Asd[(ty*4+3)*33+kk];
                double w0 = Wsd[(tx*4)*33+kk], w1 = Wsd[(tx*4+1)*33+kk], w2 = Wsd[(tx*4+2)*33+kk], w3 = Wsd[(tx*4+3)*33+kk];
                acc[0][0] += a0*w0; acc[0][1] += a0*w1; acc[0][2] += a0*w2; acc[0][3] += a0*w3;
                acc[1][0] += a1*w0; acc[1][1] += a1*w1; acc[1][2] += a1*w2; acc[1][3] += a1*w3;
                acc[2][0] += a2*w0; acc[2][1] += a2*w1; acc[2][2] += a2*w2; acc[2][3] += a2*w3;
                acc[3][0] += a3*w0; acc[3][1] += a3*w1; acc[3][2] += a3*w2; acc[3][3] += a3*w3;
            }
            __syncthreads();
        }
#pragma unroll
        for (int i = 0; i < 4; ++i)
#pragma unroll
            for (int j = 0; j < 4; ++j)
                g_Pre[pre_ix(m0 + ty*4 + i, n0 + tx*4 + j)] = (float)acc[i][j];
    }
}

// ---------------- sample-verify g_Pre ----------------
__global__ void verify_pre() {
    int s = blockIdx.x * 256 + threadIdx.x;
    unsigned m = ((unsigned)s * 2654435761u) & 32767u;
    unsigned n = ((unsigned)s * 40503u + 7u) % 2560u;
    double dot = 0.0;
    const double* ar = g_A + (size_t)m * KE;
    const float*  wr = g_Wext + (size_t)n * KE;
    for (int c = 0; c < KE; ++c) dot += ar[c] * (double)wr[c];
    double got = (double)g_Pre[pre_ix((int)m, (int)n)];
    if (fabs(got - dot) > 1e-4 * (1.0 + fabs(dot))) atomicOr(&g_bad, 1);
}

// ---------------- full vector recompute of g_Pre (only if ok && bad) ----------------
__global__ __launch_bounds__(256) void big_fix() {
    if (!(g_ok && g_bad)) return;
    __shared__ double As[64][33];
    __shared__ double Ws[64][33];
    int tid = threadIdx.x, tx = tid & 15, ty = tid >> 4;
    for (int tile = blockIdx.x; tile < (NC/64) * (NBS/64); tile += gridDim.x) {
        int n0 = (tile % (NC/64)) * 64, m0 = (tile / (NC/64)) * 64;
        double acc[4][4] = {};
        for (int k0 = 0; k0 < KE; k0 += 32) {
            for (int i = tid; i < 2048; i += 256) {
                int r = i >> 5, c = i & 31;
                As[r][c] = g_A[(size_t)(m0 + r) * KE + k0 + c];
                Ws[r][c] = (double)g_Wext[(size_t)(n0 + r) * KE + k0 + c];
            }
            __syncthreads();
            for (int kk = 0; kk < 32; ++kk) {
                double a0 = As[ty*4][kk], a1 = As[ty*4+1][kk], a2 = As[ty*4+2][kk], a3 = As[ty*4+3][kk];
                double w0 = Ws[tx*4][kk], w1 = Ws[tx*4+1][kk], w2 = Ws[tx*4+2][kk], w3 = Ws[tx*4+3][kk];
                acc[0][0] += a0*w0; acc[0][1] += a0*w1; acc[0][2] += a0*w2; acc[0][3] += a0*w3;
                acc[1][0] += a1*w0; acc[1][1] += a1*w1; acc[1][2] += a1*w2; acc[1][3] += a1*w3;
                acc[2][0] += a2*w0; acc[2][1] += a2*w1; acc[2][2] += a2*w2; acc[2][3] += a2*w3;
                acc[3][0] += a3*w0; acc[3][1] += a3*w1; acc[3][2] += a3*w2; acc[3][3] += a3*w3;
            }
            __syncthreads();
        }
#pragma unroll
        for (int i = 0; i < 4; ++i)
#pragma unroll
            for (int j = 0; j < 4; ++j)
                g_Pre[pre_ix(m0 + ty*4 + i, n0 + tx*4 + j)] = (float)acc[i][j];
        __syncthreads();
    }
}

// ---------------- synthetic hx for step probes ----------------
__global__ void synth_hx() {
    int i = blockIdx.x * 256 + threadIdx.x;
    if (i >= NB * ND) return;
    unsigned h = (unsigned)i * 2654435761u;
    float v = (float)((h >> 8) & 0xFFFFu) / 65536.0f - 0.5f;
    g_hx[i] = (double)v;
    u16 b0, b1, b2; decomp3(v, b0, b1, b2);
    g_hxb[i] = b0; g_hxb[PSH + i] = b1; g_hxb[2 * PSH + i] = b2;
}

// ---------------- standalone step GEMM (probe + host-fallback path, NC stride) ----------------
__global__ __launch_bounds__(256) void step_gemm(int t, int probe) {
    __shared__ double shd[3168];
    int tid = threadIdx.x;
    int m0 = blockIdx.x * 32, n0 = blockIdx.y * 64;
    int use_mfma = g_ok && (probe || !g_badstep);
    if (use_mfma) {
        int lane = tid & 63, wave = tid >> 6;
        int wm = (wave & 1) * 16, wn = (wave >> 1) * 32;
        int lr = lane & 15, lk = lane >> 4;
        size_t ha  = (size_t)(m0 + wm + lr) * ND;
        size_t wb0 = (size_t)(n0 + wn + lr) * ND;
        size_t wb1 = (size_t)(n0 + wn + 16 + lr) * ND;
        f4v z = {0.f,0.f,0.f,0.f};
        f4v aP0=z, aP1=z, aC0=z, aC1=z;
        for (int k0 = 0; k0 < ND; k0 += 32) {
            int kk = k0 + 8 * lk;
            s8v a0  = *(const s8v*)(const void*)(g_hxb + ha + kk);
            s8v a1  = *(const s8v*)(const void*)(g_hxb + PSH + ha + kk);
            s8v a2  = *(const s8v*)(const void*)(g_hxb + 2*PSH + ha + kk);
            s8v b00 = *(const s8v*)(const void*)(g_Wstepb + wb0 + kk);
            s8v b01 = *(const s8v*)(const void*)(g_Wstepb + wb1 + kk);
            s8v b10 = *(const s8v*)(const void*)(g_Wstepb + PSWS + wb0 + kk);
            s8v b11 = *(const s8v*)(const void*)(g_Wstepb + PSWS + wb1 + kk);
            s8v b20 = *(const s8v*)(const void*)(g_Wstepb + 2*PSWS + wb0 + kk);
            s8v b21 = *(const s8v*)(const void*)(g_Wstepb + 2*PSWS + wb1 + kk);
            STEP6(aP0, aC0, a0, a1, a2, b00, b10, b20)
            STEP6(aP1, aC1, a0, a1, a2, b01, b11, b21)
        }
        int rb = m0 + wm + 4 * lk, cb0 = n0 + wn + lr, cb1 = cb0 + 16;
#pragma unroll
        for (int r = 0; r < 4; ++r) {
            g_gbufF[(size_t)(rb + r) * NC + cb0] = aP0[r] + aC0[r]
                + g_Pre[((size_t)t * NB + rb + r) * NC + cb0];
            g_gbufF[(size_t)(rb + r) * NC + cb1] = aP1[r] + aC1[r]
                + g_Pre[((size_t)t * NB + rb + r) * NC + cb1];
        }
    } else {
        double* Asd = shd;
        double* Wsd = shd + 1056;
        int tx = tid & 15, ty = tid >> 4;
        double acc[2][4] = {};
        for (int k0 = 0; k0 < ND; k0 += 32) {
            for (int i = tid; i < 1024; i += 256) {
                int r = i >> 5, c = i & 31;
                Asd[r * 33 + c] = g_hx[(size_t)(m0 + r) * ND + k0 + c];
            }
            for (int i = tid; i < 2048; i += 256) {
                int r = i >> 5, c = i & 31;
                Wsd[r * 33 + c] = (double)g_Wstep[(size_t)(n0 + r) * ND + k0 + c];
            }
            __syncthreads();
            for (int kk = 0; kk < 32; ++kk) {
                double a0 = Asd[(ty*2)*33+kk], a1 = Asd[(ty*2+1)*33+kk];
                double w0 = Wsd[(tx*4)*33+kk], w1 = Wsd[(tx*4+1)*33+kk], w2 = Wsd[(tx*4+2)*33+kk], w3 = Wsd[(tx*4+3)*33+kk];
                acc[0][0] += a0*w0; acc[0][1] += a0*w1; acc[0][2] += a0*w2; acc[0][3] += a0*w3;
                acc[1][0] += a1*w0; acc[1][1] += a1*w1; acc[1][2] += a1*w2; acc[1][3] += a1*w3;
            }
            __syncthreads();
        }
#pragma unroll
        for (int i = 0; i < 2; ++i)
#pragma unroll
            for (int j = 0; j < 4; ++j) {
                int m = m0 + ty*2 + i, n = n0 + tx*4 + j;
                g_gbufF[(size_t)m * NC + n] = (float)(acc[i][j]
                    + (double)g_Pre[((size_t)t * NB + m) * NC + n]);
            }
    }
}

// ---------------- verify standalone step (t=0, synthetic hx, NC stride) ----------------
__global__ void verify_step() {
    int s = blockIdx.x * 256 + threadIdx.x;
    unsigned m = ((unsigned)s * 2654435761u) & 127u;
    unsigned n = ((unsigned)s * 40503u + 7u) % 2560u;
    double dot = 0.0;
    const double* hr = g_hx + (size_t)m * ND;
    const float*  wr = g_Wstep + (size_t)n * ND;
    for (int c = 0; c < ND; ++c) dot += hr[c] * (double)wr[c];
    dot += (double)g_Pre[(size_t)m * NC + n];
    double got = (double)g_gbufF[(size_t)m * NC + n];
    if (fabs(got - dot) > 1e-4 * (1.0 + fabs(dot))) atomicOr(&g_badstep, 1);
}

// ---------------- verify fused probe output (gates 2048-stride + leap partials) ----------------
__global__ void verify_fused(const float* __restrict__ W2) {
    int s = blockIdx.x * 256 + threadIdx.x;    // 4096 samples
    unsigned m = ((unsigned)s * 2654435761u) & 127u;
    unsigned h2 = (unsigned)s * 40503u + 7u;
    const double* hr = g_hx + (size_t)m * ND;
    if (s & 1) {
        unsigned q = h2 & 31u;
        double p0 = 0.0, p1 = 0.0;
        for (int c = 0; c < 16; ++c) {
            int col = q * 16 + c;
            const float* wr = g_Wstep + (size_t)(2048 + col) * ND;
            double dot = 0.0;
            for (int k = 0; k < ND; ++k) dot += hr[k] * (double)wr[k];
            dot += (double)g_Pre[(size_t)m * NC + 2048 + col];
            double hh = dot > 0.0 ? dot : 0.0;
            p0 += hh * (double)W2[col];
            p1 += hh * (double)W2[512 + col];
        }
        if (fabs(g_lpart[q][m][0] - p0) > 1e-4 * (1.0 + fabs(p0)) ||
            fabs(g_lpart[q][m][1] - p1) > 1e-4 * (1.0 + fabs(p1)))
            atomicOr(&g_badfused, 1);
    } else {
        unsigned n = h2 % 2048u;
        double dot = 0.0;
        const float* wr = g_Wstep + (size_t)n * ND;
        for (int k = 0; k < ND; ++k) dot += hr[k] * (double)wr[k];
        dot += (double)g_Pre[(size_t)m * NC + n];
        double got = (double)g_gbufF[(size_t)m * 2048 + n];
        if (fabs(got - dot) > 1e-4 * (1.0 + fabs(dot))) atomicOr(&g_badfused, 1);
    }
}

// ---------------- standalone per-step update (host fallback, NC stride) ----------------
__global__ __launch_bounds__(256) void step_update(
    const float* __restrict__ W2, const float* __restrict__ b2,
    const int* __restrict__ lengths, int t) {
    __shared__ double red[8];
    __shared__ double skipsh[2];
    int b = blockIdx.x, tid = threadIdx.x, lane = tid & 63, wave = tid >> 6;
    const float* gb = g_gbufF + (size_t)b * NC;
    double p0 = 0.0, p1 = 0.0;
    for (int j = tid; j < ND; j += 256) {
        double h = (double)gb[2048 + j];
        h = h > 0.0 ? h : 0.0;
        p0 += h * (double)W2[j];
        p1 += h * (double)W2[ND + j];
    }
    for (int off = 32; off > 0; off >>= 1) {
        p0 += __shfl_down(p0, off, 64);
        p1 += __shfl_down(p1, off, 64);
    }
    if (lane == 0) { red[wave*2] = p0; red[wave*2+1] = p1; }
    __syncthreads();
    if (tid == 0) {
        double l0 = red[0]+red[2]+red[4]+red[6] + (double)b2[0];
        double l1 = red[1]+red[3]+red[5]+red[7] + (double)b2[1];
        double mx = fmax(l0, l1);
        double sh0 = l0 - mx, sh1 = l1 - mx;
        double lsum = log(exp(sh0) + exp(sh1));
        double y0 = (sh0 - lsum) - g_gum[(size_t)t * (NB * 2) + b * 2 + 0];
        double y1 = (sh1 - lsum) - g_gum[(size_t)t * (NB * 2) + b * 2 + 1];
        double xx0 = y0 / 1e-5, xx1 = y1 / 1e-5;
        double mm = fmax(xx0, xx1);
        double e0 = exp(xx0 - mm), e1 = exp(xx1 - mm);
        double inv = 1.0 / (e0 + e1);
        skipsh[0] = e0 * inv; skipsh[1] = e1 * inv;
    }
    __syncthreads();
    double s0 = skipsh[0], s1 = skipsh[1];
    bool isFinal = (t == lengths[b] - 1);
#pragma unroll
    for (int e = 0; e < 2; ++e) {
        int j = tid + 256 * e;
        size_t ix = (size_t)b * ND + j;
        double gi = (double)gb[j], gf = (double)gb[ND + j];
        double gg = (double)gb[2*ND + j], go = (double)gb[3*ND + j];
        double cn = sigd(gf) * g_c[ix] + sigd(gi) * tanh(gg);
        double shx = sigd(go) * tanh(cn);
        double hn = g_hx[ix] * s1 + shx * s0;
        g_c[ix] = cn; g_hx[ix] = hn;
        u16 w0, w1, w2x; decomp3((float)hn, w0, w1, w2x);
        g_hxb[ix] = w0; g_hxb[PSH + ix] = w1; g_hxb[2 * PSH + ix] = w2x;
        if (isFinal) g_final[ix] = hn;
    }
}

// ---------------- persistent flag-synced cooperative loop ----------------
// 160 blocks x 512 threads. Block owns 16 cols of Wstep (LDS). Blocks >=128 are
// leap-col blocks and deposit per-row partial logits. Block b<128 owns row b's
// register state and the per-step update. Sync: per-block aflag (A done),
// per-row hxf (B done); per-wave 16-row panel waits pipeline B->A.
__global__ __launch_bounds__(512, 1) void loop_fused(const float* __restrict__ W2,
                                                     const float* __restrict__ b2,
                                                     const int* __restrict__ lengths,
                                                     int steps, int probe) {
    __shared__ __align__(16) unsigned char shm[53504];
    int bid = blockIdx.x, tid = threadIdx.x;
    int nc0 = bid * 16;
    int w = tid >> 6, lane = tid & 63;
    int lr = lane & 15, lk = lane >> 4;
    int path = g_ok && !g_badfused;
    double c0 = 0.0, h0 = 0.0;                 // register state elem (row=bid, j=tid)
    int mylen = (bid < NB) ? lengths[bid] : -1;
    u16*    Wl     = (u16*)shm;                // 48KB bf16x3 weights (path)
    float*  Wfb    = (float*)shm;              // 32KB f32 weights (fallback overlay)
    float*  W2l    = (float*)(shm + 49152);    // 4KB
    double* skipsh = (double*)(shm + 53248);
    if (path) {
        for (int i = tid; i < 3072; i += 512) {
            int p = i >> 10, rem = i & 1023, kk = rem >> 6, l = rem & 63;
            int col = l & 15, k8 = l >> 4;
            *(uint4*)(void*)(Wl + (size_t)p*8192 + kk*512 + l*8) =
                *(const uint4*)(const void*)(g_Wstepb + (size_t)p*PSWS
                      + (size_t)(nc0 + col)*ND + kk*32 + k8*8);
        }
    } else {
        for (int i = tid; i < 16*512; i += 512)
            Wfb[i] = g_Wstep[(size_t)(nc0 + (i >> 9))*ND + (i & 511)];
    }
    for (int i = tid; i < 1024; i += 512) W2l[i] = W2[i];
    __syncthreads();
    int r0 = 16*w + 4*lk;
    float preA[4];
    if (path) {
#pragma unroll
        for (int r = 0; r < 4; ++r)
            preA[r] = g_Pre[((size_t)0 * NB + r0 + r) * NC + nc0 + lr];
    }
    for (int t = 0; t < steps; ++t) {
        // ---- phase A ----
        if (path) {
            if (t > 0) {   // per-wave wait on its 16-row panel's hx
                for (;;) {
                    bool ok = true;
                    if (lane < 16)
                        ok = (__hip_atomic_load(&g_hxf[(16*w + lane)*32],
                               __ATOMIC_RELAXED, __HIP_MEMORY_SCOPE_AGENT) >= t);
                    if (__all(ok)) break;
                    __builtin_amdgcn_s_sleep(1);
                }
                __builtin_amdgcn_fence(__ATOMIC_ACQUIRE, "agent");
            }
            f4v z = {0.f,0.f,0.f,0.f};
            f4v aP = z, aC = z;
            size_t ha = (size_t)(16*w + lr) * ND;
#pragma unroll 2
            for (int kk = 0; kk < 16; ++kk) {
                int kb = kk*32 + 8*lk;
                s8v A0 = *(const s8v*)(const void*)(g_hxb + ha + kb);
                s8v A1 = *(const s8v*)(const void*)(g_hxb + PSH + ha + kb);
                s8v A2 = *(const s8v*)(const void*)(g_hxb + 2*PSH + ha + kb);
                const u16* wp = Wl + kk*512 + lane*8;
                s8v B0 = *(const s8v*)(const void*)(wp);
                s8v B1 = *(const s8v*)(const void*)(wp + 8192);
                s8v B2 = *(const s8v*)(const void*)(wp + 16384);
                STEP6(aP, aC, A0, A1, A2, B0, B1, B2)
            }
            if (bid < NB) {
#pragma unroll
                for (int r = 0; r < 4; ++r)
                    g_gbufF[(size_t)(r0 + r) * 2048 + nc0 + lr] = aP[r] + aC[r] + preA[r];
            } else {
                int colg = nc0 - 2048 + lr;
                double q0[4], q1[4];
#pragma unroll
                for (int r = 0; r < 4; ++r) {
                    float v = aP[r] + aC[r] + preA[r];
                    double hh = v > 0.f ? (double)v : 0.0;
                    q0[r] = hh * (double)W2l[colg];
                    q1[r] = hh * (double)W2l[512 + colg];
                }
#pragma unroll
                for (int m = 8; m > 0; m >>= 1)
#pragma unroll
                    for (int r = 0; r < 4; ++r) {
                        q0[r] += __shfl_xor(q0[r], m, 16);
                        q1[r] += __shfl_xor(q1[r], m, 16);
                    }
                if (lr == 0)
#pragma unroll
                    for (int r = 0; r < 4; ++r) {
                        g_lpart[bid - NB][r0 + r][0] = q0[r];
                        g_lpart[bid - NB][r0 + r][1] = q1[r];
                    }
            }
            int tn = (t + 1 < steps) ? t + 1 : t;   // prefetch next Pre slice
#pragma unroll
            for (int r = 0; r < 4; ++r)
                preA[r] = g_Pre[((size_t)tn * NB + r0 + r) * NC + nc0 + lr];
        } else {
            // ---- f64 vector fallback phase A (block-level wait) ----
            if (t > 0) {
                if (tid < NB) {
                    while (__hip_atomic_load(&g_hxf[tid*32], __ATOMIC_RELAXED,
                             __HIP_MEMORY_SCOPE_AGENT) < t)
                        __builtin_amdgcn_s_sleep(1);
                }
                __syncthreads();
                if (tid == 0) __builtin_amdgcn_fence(__ATOMIC_ACQUIRE, "agent");
                __syncthreads();
            }
            int col = tid & 15, rgrp = tid >> 4;
            double q0[4] = {}, q1[4] = {};
#pragma unroll
            for (int rr = 0; rr < 4; ++rr) {
                int row = rgrp*4 + rr;
                const double* hr = g_hx + (size_t)row * ND;
                double dot = 0.0;
                for (int k = 0; k < ND; ++k) dot += hr[k] * (double)Wfb[col*512 + k];
                float v = (float)(dot + (double)g_Pre[((size_t)t * NB + row) * NC + nc0 + col]);
                if (bid < NB) {
                    g_gbufF[(size_t)row * 2048 + nc0 + col] = v;
                } else {
                    double hh = v > 0.f ? (double)v : 0.0;
                    q0[rr] = hh * (double)W2l[nc0 - 2048 + col];
                    q1[rr] = hh * (double)W2l[512 + nc0 - 2048 + col];
                }
            }
            if (bid >= NB) {
#pragma unroll
                for (int m = 8; m > 0; m >>= 1)
#pragma unroll
                    for (int rr = 0; rr < 4; ++rr) {
                        q0[rr] += __shfl_xor(q0[rr], m, 16);
                        q1[rr] += __shfl_xor(q1[rr], m, 16);
                    }
                if (col == 0)
#pragma unroll
                    for (int rr = 0; rr < 4; ++rr) {
                        g_lpart[bid - NB][rgrp*4 + rr][0] = q0[rr];
                        g_lpart[bid - NB][rgrp*4 + rr][1] = q1[rr];
                    }
            }
        }
        __syncthreads();
        if (tid == 0) {
            __builtin_amdgcn_fence(__ATOMIC_RELEASE, "agent");
            __hip_atomic_store(&g_aflag[bid*32], t + 1, __ATOMIC_RELAXED,
                               __HIP_MEMORY_SCOPE_AGENT);
        }
        __syncthreads();
        // ---- phase B (row owner) ----
        if (!probe && bid < NB) {
            if (tid < 160) {
                while (__hip_atomic_load(&g_aflag[tid*32], __ATOMIC_RELAXED,
                         __HIP_MEMORY_SCOPE_AGENT) < t + 1)
                    __builtin_amdgcn_s_sleep(1);
            }
            __syncthreads();
            if (tid == 0) __builtin_amdgcn_fence(__ATOMIC_ACQUIRE, "agent");
            __syncthreads();
            double p0 = 0.0, p1 = 0.0;
            if (tid < 32) { p0 = g_lpart[tid][bid][0]; p1 = g_lpart[tid][bid][1]; }
            if (tid < 64) {
#pragma unroll
                for (int m = 16; m > 0; m >>= 1) {
                    p0 += __shfl_xor(p0, m, 32);
                    p1 += __shfl_xor(p1, m, 32);
                }
            }
            if (tid == 0) {
                double l0 = p0 + (double)b2[0], l1 = p1 + (double)b2[1];
                double mx = fmax(l0, l1);
                double sh0 = l0 - mx, sh1 = l1 - mx;
                double lsum = log(exp(sh0) + exp(sh1));
                double y0 = (sh0 - lsum) - g_gum[(size_t)t * (NB*2) + bid*2 + 0];
                double y1 = (sh1 - lsum) - g_gum[(size_t)t * (NB*2) + bid*2 + 1];
                double xx0 = y0 / 1e-5, xx1 = y1 / 1e-5;
                double mm = fmax(xx0, xx1);
                double e0 = exp(xx0 - mm), e1 = exp(xx1 - mm);
                double inv = 1.0 / (e0 + e1);
                skipsh[0] = e0 * inv; skipsh[1] = e1 * inv;
            }
            __syncthreads();
            double s0 = skipsh[0], s1 = skipsh[1];
            bool isFinal = (t == mylen - 1);
            {
                int j = tid;
                size_t ix = (size_t)bid * ND + j;
                const float* gb = g_gbufF + (size_t)bid * 2048;
                double gi = (double)gb[j], gf = (double)gb[512 + j];
                double gg = (double)gb[1024 + j], go = (double)gb[1536 + j];
                double cn = sigd(gf) * c0 + sigd(gi) * tanh(gg);
                double shx = sigd(go) * tanh(cn);
                double hn = h0 * s1 + shx * s0;
                c0 = cn; h0 = hn;
                u16 w0_, w1_, w2_; decomp3((float)hn, w0_, w1_, w2_);
                g_hxb[ix] = w0_; g_hxb[PSH + ix] = w1_; g_hxb[2*PSH + ix] = w2_;
                if (!path) g_hx[ix] = hn;
                if (isFinal) g_final[ix] = hn;
            }
            __syncthreads();
            if (tid == 0) {
                __builtin_amdgcn_fence(__ATOMIC_RELEASE, "agent");
                __hip_atomic_store(&g_hxf[bid*32], t + 1, __ATOMIC_RELAXED,
                                   __HIP_MEMORY_SCOPE_AGENT);
            }
        }
    }
}

// ---------------- final projection ----------------
__global__ __launch_bounds__(256) void final_out(const float* __restrict__ Wo,
                                                 const float* __restrict__ bo,
                                                 float* __restrict__ out) {
    int tid = threadIdx.x;
    int b = tid >> 1, k = tid & 1;
    double acc = 0.0;
    const double* f = g_final + (size_t)b * ND;
    const float* w = Wo + (size_t)k * ND;
    for (int d = 0; d < ND; ++d) acc += f[d] * (double)w[d];
    out[b * 2 + k] = (float)(acc + (double)bo[k]);
}

// ---------------- host launcher ----------------
extern "C" void kernel_launch(void* const* d_in, const int* in_sizes, int n_in,
                              void* d_out, int out_size, void* d_ws, size_t ws_size,
                              hipStream_t stream) {
    (void)in_sizes; (void)n_in; (void)d_ws; (void)ws_size; (void)out_size;
    const int*   seqs    = (const int*)d_in[0];
    const int*   lengths = (const int*)d_in[2];
    const float* emb     = (const float*)d_in[5];
    const float* revWih  = (const float*)d_in[6];
    const float* revWhh  = (const float*)d_in[7];
    const float* convw   = (const float*)d_in[8];
    const float* W1      = (const float*)d_in[9];
    const float* b1      = (const float*)d_in[10];
    const float* W2      = (const float*)d_in[11];
    const float* b2      = (const float*)d_in[12];
    const float* cWih    = (const float*)d_in[13];
    const float* cWhh    = (const float*)d_in[14];
    const float* Wo      = (const float*)d_in[15];
    const float* bo      = (const float*)d_in[16];
    float* out = (float*)d_out;

    double *A_p = nullptr, *Ap_p = nullptr;
    hipGetSymbolAddress((void**)&A_p,  HIP_SYMBOL(g_A));
    hipGetSymbolAddress((void**)&Ap_p, HIP_SYMBOL(g_Aproj));

    probe_bf16<<<1, 64, 0, stream>>>();
    build_w<<<NC, 256, 0, stream>>>(cWih, cWhh, W1, b1);
    gumbel_init<<<256, 256, 0, stream>>>();
    embed_sum<<<NBS, 128, 0, stream>>>(seqs, emb);

    gemm_f64<<<dim3(NBS / 64, 1), 256, 0, stream>>>(A_p, KE, revWih, ND, Ap_p, 40,
                                                    NBS, 40, ND);
    rev_lstm<<<NB, 64, 0, stream>>>(revWhh);
    conv_relu<<<dim3(NB, NS / 8), 256, 0, stream>>>(convw);

    big_gemm<<<dim3(NC / 64, NBS / 64), 256, 0, stream>>>();
    verify_pre<<<32, 256, 0, stream>>>();
    big_fix<<<2048, 256, 0, stream>>>();

    // probes on synthetic state
    synth_hx<<<256, 256, 0, stream>>>();
    step_gemm<<<dim3(4, 40), 256, 0, stream>>>(0, 1);
    verify_step<<<8, 256, 0, stream>>>();
    {   // fused phase-A probe (1 step, B skipped)
        int steps1 = 1, probe1 = 1;
        void* pargs[] = { (void*)&W2, (void*)&b2, (void*)&lengths,
                          (void*)&steps1, (void*)&probe1 };
        hipError_t pe = hipLaunchCooperativeKernel((const void*)loop_fused,
                                                   dim3(160), dim3(512), pargs, 0, stream);
        if (pe == hipSuccess) verify_fused<<<16, 256, 0, stream>>>(W2);
        else (void)hipGetLastError();
    }
    init_state<<<256, 256, 0, stream>>>();   // resets state + aflag/hxf

    int stepsN = NS, probe0 = 0;
    void* args[] = { (void*)&W2, (void*)&b2, (void*)&lengths,
                     (void*)&stepsN, (void*)&probe0 };
    hipError_t ce = hipLaunchCooperativeKernel((const void*)loop_fused,
                                               dim3(160), dim3(512), args, 0, stream);
    if (ce != hipSuccess) {
        (void)hipGetLastError();
        for (int t = 0; t < NS; ++t) {
            step_gemm<<<dim3(4, 40), 256, 0, stream>>>(t, 0);
            step_update<<<NB, 256, 0, stream>>>(W2, b2, lengths, t);
        }
    }
    final_out<<<1, 256, 0, stream>>>(Wo, bo, out);
}

// Round 12
// 12397.549 us; speedup vs baseline: 1.5054x; 1.0099x over previous
//
#include <hip/hip_runtime.h>
#include <math.h>

#define NB 128
#define NS 256
#define ND 512
#define NBS (NB*NS)   // 32768
#define KE 544        // 512 x | 10 back | 20 cnn | 1 bias | 1 pad
#define NC 2560       // 2048 cell gates + 512 leap hidden

typedef unsigned short u16;
typedef __attribute__((ext_vector_type(8))) short s8v;   // 8 bf16
typedef __attribute__((ext_vector_type(4))) float f4v;   // 4 f32 acc

static constexpr size_t PSA  = (size_t)NBS * KE;
static constexpr size_t PSWE = (size_t)NC  * KE;
static constexpr size_t PSWS = (size_t)NC  * ND;
static constexpr size_t PSH  = (size_t)NB  * ND;

// ---------------- device-global scratch ----------------
__device__ double g_A[(size_t)NBS * KE];
__device__ u16    g_Ab[3 * PSA];
__device__ float  g_Pre[(size_t)NBS * NC];    // layout [t][b][n]
__device__ double g_Aproj[(size_t)NBS * 40];
__device__ double g_gum[NS * NB * 2];
__device__ double g_hx[NB * ND];
__device__ u16    g_hxb[3 * NB * ND];
__device__ double g_c[NB * ND];
__device__ float  g_gbufF[NB * NC];           // fused path uses [128][2048] gates region
__device__ double g_final[NB * ND];
__device__ float  g_Wext[PSWE];
__device__ u16    g_Wextb[3 * PSWE];
__device__ float  g_Wstep[PSWS];
__device__ u16    g_Wstepb[3 * PSWS];
__device__ double g_lpart[32][NB][2];         // leap partial logits
__device__ int    g_aflag[160 * 32];          // per-block A-completion (128B apart)
__device__ int    g_hxf[NB * 32];             // per-row B-completion
__device__ int    g_ok, g_bad, g_badstep, g_badfused;

__device__ __forceinline__ double sigd(double x) { return 1.0 / (1.0 + exp(-x)); }
__device__ __forceinline__ u16 f2bf(float f) {
    unsigned u = __float_as_uint(f);
    return (u16)((u + 0x7FFFu + ((u >> 16) & 1u)) >> 16);   // RNE
}
__device__ __forceinline__ float bf2f(u16 b) { return __uint_as_float(((unsigned)b) << 16); }
__device__ __forceinline__ void decomp3(float f, u16& b0, u16& b1, u16& b2) {
    b0 = f2bf(f); float r1 = f - bf2f(b0);
    b1 = f2bf(r1); float r2 = r1 - bf2f(b1);
    b2 = f2bf(r2);
}
__device__ __forceinline__ size_t pre_ix(int m /*b*NS+s*/, int n) {
    return ((size_t)(m & 255) * NB + (m >> 8)) * NC + n;    // -> [s][b][n]
}
__device__ __forceinline__ void put_Ab(size_t ix, float f) {
    u16 b0, b1, b2; decomp3(f, b0, b1, b2);
    g_Ab[ix] = b0; g_Ab[PSA + ix] = b1; g_Ab[2 * PSA + ix] = b2;
}

#define MFMA_BF16 __builtin_amdgcn_mfma_f32_16x16x32_bf16
#define STEP6(AP,AC,A0,A1,A2,B0,B1,B2) \
    AP = MFMA_BF16(A0, B0, AP, 0, 0, 0); \
    AC = MFMA_BF16(A0, B1, AC, 0, 0, 0); \
    AC = MFMA_BF16(A1, B0, AC, 0, 0, 0); \
    AC = MFMA_BF16(A0, B2, AC, 0, 0, 0); \
    AC = MFMA_BF16(A1, B1, AC, 0, 0, 0); \
    AC = MFMA_BF16(A2, B0, AC, 0, 0, 0);

// ---------------- bf16 MFMA layout probe ----------------
__global__ void probe_bf16() {
    int l = threadIdx.x, lr = l & 15, lk = l >> 4;
    s8v a, b;
#pragma unroll
    for (int e = 0; e < 8; ++e) {
        int k = 8 * lk + e;
        a[e] = (short)f2bf((float)(((3 * lr + 7 * k) % 13) + 1));
        b[e] = (short)f2bf((float)(((5 * k + 11 * lr) % 17) + 1));
    }
    f4v d = {0.f, 0.f, 0.f, 0.f};
    d = MFMA_BF16(a, b, d, 0, 0, 0);
    bool okl = true;
#pragma unroll
    for (int r = 0; r < 4; ++r) {
        int row = 4 * lk + r, col = lr;
        int e = 0;
        for (int k = 0; k < 32; ++k)
            e += (((3 * row + 7 * k) % 13) + 1) * (((5 * k + 11 * col) % 17) + 1);
        if (d[r] != (float)e) okl = false;
    }
    unsigned long long vote = __ballot(okl);
    if (l == 0) {
        g_ok = (vote == 0xFFFFFFFFFFFFFFFFull) ? 1 : 0;
        g_bad = 0; g_badstep = 0; g_badfused = 0;
    }
}

// ---------------- init (state + sync flags) ----------------
__global__ void init_state() {
    int i = blockIdx.x * 256 + threadIdx.x;
    if (i < 160 * 32) g_aflag[i] = 0;
    if (i < NB * 32)  g_hxf[i]  = 0;
    if (i < NB * ND) {
        g_hx[i] = 0.0; g_c[i] = 0.0;
        g_hxb[i] = 0; g_hxb[PSH + i] = 0; g_hxb[2 * PSH + i] = 0;
    }
}

// ---------------- weight repack + bf16x3 ----------------
__global__ __launch_bounds__(256) void build_w(const float* __restrict__ cWih,
                                               const float* __restrict__ cWhh,
                                               const float* __restrict__ W1,
                                               const float* __restrict__ b1) {
    int n = blockIdx.x;
    for (int c = threadIdx.x; c < KE; c += 256) {
        float we;
        if (n < 2048) we = (c < 512) ? cWih[(size_t)n * 512 + c] : 0.f;
        else {
            int n2 = n - 2048;
            if      (c < 512)  we = W1[(size_t)n2 * 1054 + 512 + c];
            else if (c < 522)  we = W1[(size_t)n2 * 1054 + 1024 + (c - 512)];
            else if (c < 542)  we = W1[(size_t)n2 * 1054 + 1034 + (c - 522)];
            else if (c == 542) we = b1[n2];
            else               we = 0.f;
        }
        size_t ix = (size_t)n * KE + c;
        g_Wext[ix] = we;
        u16 b0, b1_, b2; decomp3(we, b0, b1_, b2);
        g_Wextb[ix] = b0; g_Wextb[PSWE + ix] = b1_; g_Wextb[2 * PSWE + ix] = b2;
        if (c < 512) {
            float ws = (n < 2048) ? cWhh[(size_t)n * 512 + c]
                                  : W1[(size_t)(n - 2048) * 1054 + c];
            size_t ix2 = (size_t)n * ND + c;
            g_Wstep[ix2] = ws;
            decomp3(ws, b0, b1_, b2);
            g_Wstepb[ix2] = b0; g_Wstepb[PSWS + ix2] = b1_; g_Wstepb[2 * PSWS + ix2] = b2;
        }
    }
}

// ---------------- gumbel: JAX partitionable threefry2x32, key (0,42) ----------------
__device__ __forceinline__ unsigned rotl32(unsigned x, int r) { return (x << r) | (x >> (32 - r)); }

__global__ void gumbel_init() {
    unsigned p = blockIdx.x * 256 + threadIdx.x;
    if (p >= 65536u) return;
    unsigned k0 = 0u, k1 = 42u;
    unsigned ks2 = k0 ^ k1 ^ 0x1BD11BDAu;
    unsigned x0 = 0u, x1 = p;
    x0 += k0; x1 += k1;
#define RND(r) { x0 += x1; x1 = rotl32(x1, (r)); x1 ^= x0; }
    RND(13) RND(15) RND(26) RND(6)
    x0 += k1;  x1 += ks2 + 1u;
    RND(17) RND(29) RND(16) RND(24)
    x0 += ks2; x1 += k0 + 2u;
    RND(13) RND(15) RND(26) RND(6)
    x0 += k0;  x1 += k1 + 3u;
    RND(17) RND(29) RND(16) RND(24)
    x0 += k1;  x1 += ks2 + 4u;
    RND(13) RND(15) RND(26) RND(6)
    x0 += ks2; x1 += k0 + 5u;
#undef RND
    unsigned bits = x0 ^ x1;
    float u = __uint_as_float((bits >> 9) | 0x3f800000u) - 1.0f;
    g_gum[p] = log(-log((double)u + 1e-20) + 1e-20);
}

// ---------------- embedding gather+sum (writes f64 + bf16x3 planes) ----------------
__global__ __launch_bounds__(128) void embed_sum(const int* __restrict__ seqs,
                                                 const float* __restrict__ emb) {
    int bs = blockIdx.x;
    int tid = threadIdx.x;
    __shared__ int idxs[16];
    if (tid < 16) idxs[tid] = seqs[(size_t)bs * 16 + tid];
    __syncthreads();
    double a0 = 0, a1 = 0, a2 = 0, a3 = 0;
    for (int v = 0; v < 16; ++v) {
        const float4* row = (const float4*)(emb + (size_t)idxs[v] * ND);
        float4 e = row[tid];
        a0 += (double)e.x; a1 += (double)e.y; a2 += (double)e.z; a3 += (double)e.w;
    }
    size_t base = (size_t)bs * KE + tid * 4;
    double* o = g_A + base;
    o[0] = a0; o[1] = a1; o[2] = a2; o[3] = a3;
    put_Ab(base + 0, (float)a0); put_Ab(base + 1, (float)a1);
    put_Ab(base + 2, (float)a2); put_Ab(base + 3, (float)a3);
    if (tid == 0) {
        g_A[(size_t)bs * KE + 542] = 1.0; g_A[(size_t)bs * KE + 543] = 0.0;
        put_Ab((size_t)bs * KE + 542, 1.0f); put_Ab((size_t)bs * KE + 543, 0.0f);
    }
}

// ---------------- f64 vector GEMM (Aproj only) ----------------
__global__ __launch_bounds__(256) void gemm_f64(
    const double* __restrict__ A, int lda,
    const float* __restrict__ W, int ldw,
    double* __restrict__ C, int ldc,
    int M, int N, int K) {
    __shared__ double As[16][66];
    __shared__ double Ws[16][66];
    int m0 = blockIdx.x * 64, n0 = blockIdx.y * 64;
    int tid = threadIdx.x, tx = tid & 15, ty = tid >> 4;
    double acc[4][4] = {};
    for (int k0 = 0; k0 < K; k0 += 16) {
        for (int i = tid; i < 1024; i += 256) {
            int r = i >> 4, c = i & 15;
            As[c][r] = (m0 + r < M && k0 + c < K) ? A[(size_t)(m0 + r) * lda + k0 + c] : 0.0;
            Ws[c][r] = (n0 + r < N && k0 + c < K) ? (double)W[(size_t)(n0 + r) * ldw + k0 + c] : 0.0;
        }
        __syncthreads();
#pragma unroll
        for (int kk = 0; kk < 16; ++kk) {
            double a0 = As[kk][ty*4], a1 = As[kk][ty*4+1], a2 = As[kk][ty*4+2], a3 = As[kk][ty*4+3];
            double w0 = Ws[kk][tx*4], w1 = Ws[kk][tx*4+1], w2 = Ws[kk][tx*4+2], w3 = Ws[kk][tx*4+3];
            acc[0][0] += a0*w0; acc[0][1] += a0*w1; acc[0][2] += a0*w2; acc[0][3] += a0*w3;
            acc[1][0] += a1*w0; acc[1][1] += a1*w1; acc[1][2] += a1*w2; acc[1][3] += a1*w3;
            acc[2][0] += a2*w0; acc[2][1] += a2*w1; acc[2][2] += a2*w2; acc[2][3] += a2*w3;
            acc[3][0] += a3*w0; acc[3][1] += a3*w1; acc[3][2] += a3*w2; acc[3][3] += a3*w3;
        }
        __syncthreads();
    }
#pragma unroll
    for (int i = 0; i < 4; ++i)
#pragma unroll
        for (int j = 0; j < 4; ++j) {
            int m = m0 + ty*4 + i, n = n0 + tx*4 + j;
            if (m < M && n < N) C[(size_t)m * ldc + n] = acc[i][j];
        }
}

// ---------------- reverse LSTM (writes f64 + planes) ----------------
__global__ __launch_bounds__(64) void rev_lstm(const float* __restrict__ Whh) {
    int b = blockIdx.x;
    int tid = threadIdx.x;
    __shared__ double h[10], cc[10], g[40], wsh[400];
    for (int i = tid; i < 400; i += 64) wsh[i] = (double)Whh[i];
    if (tid < 10) { h[tid] = 0.0; cc[tid] = 0.0; }
    __syncthreads();
    for (int s = NS - 1; s >= 0; --s) {
        if (tid < 40) {
            double acc = g_Aproj[((size_t)b * NS + s) * 40 + tid];
#pragma unroll
            for (int k = 0; k < 10; ++k) acc += h[k] * wsh[tid * 10 + k];
            g[tid] = acc;
        }
        __syncthreads();
        if (tid < 10) {
            double gi = g[tid], gf = g[10 + tid], gg = g[20 + tid], go = g[30 + tid];
            double cn = sigd(gf) * cc[tid] + sigd(gi) * tanh(gg);
            cc[tid] = cn;
            double hn = sigd(go) * tanh(cn);
            h[tid] = hn;
            size_t ix = ((size_t)b * NS + s) * KE + 512 + tid;
            g_A[ix] = hn;
            put_Ab(ix, (float)hn);
        }
        __syncthreads();
    }
}

// ---------------- conv1d + relu (writes f64 + planes) ----------------
__global__ __launch_bounds__(256) void conv_relu(const float* __restrict__ w) {
    int b = blockIdx.x, s0 = blockIdx.y * 8;
    int tid = threadIdx.x, grp = tid >> 5, lane = tid & 31;
    __shared__ double xs[10][ND];
    for (int i = tid; i < 10 * ND; i += 256) {
        int r = i >> 9, d = i & (ND - 1);
        int s = s0 - 1 + r;
        xs[r][d] = (s >= 0 && s < NS) ? g_A[((size_t)b * NS + s) * KE + d] : 0.0;
    }
    __syncthreads();
    int s = s0 + grp;
    for (int o = 0; o < 20; ++o) {
        const float* wo = w + (size_t)o * 1536;
        double acc = 0.0;
        for (int d = lane; d < ND; d += 32) {
            acc += xs[grp][d]     * (double)wo[d*3]
                 + xs[grp + 1][d] * (double)wo[d*3 + 1]
                 + xs[grp + 2][d] * (double)wo[d*3 + 2];
        }
        for (int m = 16; m > 0; m >>= 1) acc += __shfl_xor(acc, m, 32);
        if (lane == 0) {
            double v = acc > 0.0 ? acc : 0.0;
            size_t ix = ((size_t)b * NS + s) * KE + 522 + o;
            g_A[ix] = v;
            put_Ab(ix, (float)v);
        }
    }
}

// ---------------- big GEMM: g_Pre[t][b][n] = g_A @ g_Wext^T ----------------
__global__ __launch_bounds__(256) void big_gemm() {
    __shared__ __align__(16) unsigned char shm[36864];
    int tid = threadIdx.x;
    int n0 = blockIdx.x * 64, m0 = blockIdx.y * 64;
    if (g_ok) {
        u16* usA = (u16*)shm;
        u16* usB = usA + 9216;
        int lane = tid & 63, wave = tid >> 6;
        int wm = (wave & 1) * 32, wn = (wave >> 1) * 32;
        int lr = lane & 15, lk = lane >> 4;
        f4v z = {0.f,0.f,0.f,0.f};
        f4v aP00=z,aP01=z,aP10=z,aP11=z, aC00=z,aC01=z,aC10=z,aC11=z;
        for (int k0 = 0; k0 < KE; k0 += 32) {
            for (int i = tid; i < 1536; i += 256) {
                if (i < 768) {
                    int p = i >> 8, rem = i & 255, r = rem >> 2, sg = rem & 3;
                    *(uint4*)(void*)(usA + p*3072 + r*48 + sg*8) =
                        *(const uint4*)(const void*)(g_Ab + (size_t)p*PSA + (size_t)(m0+r)*KE + k0 + sg*8);
                } else {
                    int j = i - 768;
                    int p = j >> 8, rem = j & 255, r = rem >> 2, sg = rem & 3;
                    *(uint4*)(void*)(usB + p*3072 + r*48 + sg*8) =
                        *(const uint4*)(const void*)(g_Wextb + (size_t)p*PSWE + (size_t)(n0+r)*KE + k0 + sg*8);
                }
            }
            __syncthreads();
            const u16* pa = usA + (wm + lr) * 48 + 8 * lk;
            const u16* pb = usB + (wn + lr) * 48 + 8 * lk;
            s8v a0_0 = *(const s8v*)(const void*)(pa);
            s8v a0_1 = *(const s8v*)(const void*)(pa + 768);
            s8v a1_0 = *(const s8v*)(const void*)(pa + 3072);
            s8v a1_1 = *(const s8v*)(const void*)(pa + 3840);
            s8v a2_0 = *(const s8v*)(const void*)(pa + 6144);
            s8v a2_1 = *(const s8v*)(const void*)(pa + 6912);
            s8v b0_0 = *(const s8v*)(const void*)(pb);
            s8v b0_1 = *(const s8v*)(const void*)(pb + 768);
            s8v b1_0 = *(const s8v*)(const void*)(pb + 3072);
            s8v b1_1 = *(const s8v*)(const void*)(pb + 3840);
            s8v b2_0 = *(const s8v*)(const void*)(pb + 6144);
            s8v b2_1 = *(const s8v*)(const void*)(pb + 6912);
            STEP6(aP00, aC00, a0_0, a1_0, a2_0, b0_0, b1_0, b2_0)
            STEP6(aP01, aC01, a0_0, a1_0, a2_0, b0_1, b1_1, b2_1)
            STEP6(aP10, aC10, a0_1, a1_1, a2_1, b0_0, b1_0, b2_0)
            STEP6(aP11, aC11, a0_1, a1_1, a2_1, b0_1, b1_1, b2_1)
            __syncthreads();
        }
        int rb = m0 + wm + 4 * lk, cb0 = n0 + wn + lr, cb1 = cb0 + 16;
#pragma unroll
        for (int r = 0; r < 4; ++r) {
            g_Pre[pre_ix(rb + r, cb0)]      = aP00[r] + aC00[r];
            g_Pre[pre_ix(rb + r, cb1)]      = aP01[r] + aC01[r];
            g_Pre[pre_ix(rb + 16 + r, cb0)] = aP10[r] + aC10[r];
            g_Pre[pre_ix(rb + 16 + r, cb1)] = aP11[r] + aC11[r];
        }
    } else {
        double* Asd = (double*)shm;
        double* Wsd = Asd + 64 * 33;
        int tx = tid & 15, ty = tid >> 4;
        double acc[4][4] = {};
        for (int k0 = 0; k0 < KE; k0 += 32) {
            for (int i = tid; i < 2048; i += 256) {
                int r = i >> 5, c = i & 31;
                Asd[r * 33 + c] = g_A[(size_t)(m0 + r) * KE + k0 + c];
                Wsd[r * 33 + c] = (double)g_Wext[(size_t)(n0 + r) * KE + k0 + c];
            }
            __syncthreads();
            for (int kk = 0; kk < 32; ++kk) {
                double a0 = Asd[(ty*4)*33+kk], a1 = Asd[(ty*4+1)*33+kk], a2 = Asd[(ty*4+2)*33+kk], a3 = Asd[(ty*4+3)*33+kk];
                double w0 = Wsd[(tx*4)*33+kk], w1 = Wsd[(tx*4+1)*33+kk], w2 = Wsd[(tx*4+2)*33+kk], w3 = Wsd[(tx*4+3)*33+kk];
                acc[0][0] += a0*w0; acc[0][1] += a0*w1; acc[0][2] += a0*w2; acc[0][3] += a0*w3;
                acc[1][0] += a1*w0; acc[1][1] += a1*w1; acc[1][2] += a1*w2; acc[1][3] += a1*w3;
                acc[2][0] += a2*w0; acc[2][1] += a2*w1; acc[2][2] += a2*w2; acc[2][3] += a2*w3;
                acc[3][0] += a3*w0; acc[3][1] += a3*w1; acc[3][2] += a3*w2; acc[3][3] += a3*w3;
            }
            __syncthreads();
        }
#pragma unroll
        for (int i = 0; i < 4; ++i)
#pragma unroll
            for (int j = 0; j < 4; ++j)
                g_Pre[pre_ix(m0 + ty*4 + i, n0 + tx*4 + j)] = (float)acc[i][j];
    }
}

// ---------------- sample-verify g_Pre ----------------
__global__ void verify_pre() {
    int s = blockIdx.x * 256 + threadIdx.x;
    unsigned m = ((unsigned)s * 2654435761u) & 32767u;
    unsigned n = ((unsigned)s * 40503u + 7u) % 2560u;
    double dot = 0.0;
    const double* ar = g_A + (size_t)m * KE;
    const float*  wr = g_Wext + (size_t)n * KE;
    for (int c = 0; c < KE; ++c) dot += ar[c] * (double)wr[c];
    double got = (double)g_Pre[pre_ix((int)m, (int)n)];
    if (fabs(got - dot) > 1e-4 * (1.0 + fabs(dot))) atomicOr(&g_bad, 1);
}

// ---------------- full vector recompute of g_Pre (only if ok && bad) ----------------
__global__ __launch_bounds__(256) void big_fix() {
    if (!(g_ok && g_bad)) return;
    __shared__ double As[64][33];
    __shared__ double Ws[64][33];
    int tid = threadIdx.x, tx = tid & 15, ty = tid >> 4;
    for (int tile = blockIdx.x; tile < (NC/64) * (NBS/64); tile += gridDim.x) {
        int n0 = (tile % (NC/64)) * 64, m0 = (tile / (NC/64)) * 64;
        double acc[4][4] = {};
        for (int k0 = 0; k0 < KE; k0 += 32) {
            for (int i = tid; i < 2048; i += 256) {
                int r = i >> 5, c = i & 31;
                As[r][c] = g_A[(size_t)(m0 + r) * KE + k0 + c];
                Ws[r][c] = (double)g_Wext[(size_t)(n0 + r) * KE + k0 + c];
            }
            __syncthreads();
            for (int kk = 0; kk < 32; ++kk) {
                double a0 = As[ty*4][kk], a1 = As[ty*4+1][kk], a2 = As[ty*4+2][kk], a3 = As[ty*4+3][kk];
                double w0 = Ws[tx*4][kk], w1 = Ws[tx*4+1][kk], w2 = Ws[tx*4+2][kk], w3 = Ws[tx*4+3][kk];
                acc[0][0] += a0*w0; acc[0][1] += a0*w1; acc[0][2] += a0*w2; acc[0][3] += a0*w3;
                acc[1][0] += a1*w0; acc[1][1] += a1*w1; acc[1][2] += a1*w2; acc[1][3] += a1*w3;
                acc[2][0] += a2*w0; acc[2][1] += a2*w1; acc[2][2] += a2*w2; acc[2][3] += a2*w3;
                acc[3][0] += a3*w0; acc[3][1] += a3*w1; acc[3][2] += a3*w2; acc[3][3] += a3*w3;
            }
            __syncthreads();
        }
#pragma unroll
        for (int i = 0; i < 4; ++i)
#pragma unroll
            for (int j = 0; j < 4; ++j)
                g_Pre[pre_ix(m0 + ty*4 + i, n0 + tx*4 + j)] = (float)acc[i][j];
        __syncthreads();
    }
}

// ---------------- synthetic hx for step probes ----------------
__global__ void synth_hx() {
    int i = blockIdx.x * 256 + threadIdx.x;
    if (i >= NB * ND) return;
    unsigned h = (unsigned)i * 2654435761u;
    float v = (float)((h >> 8) & 0xFFFFu) / 65536.0f - 0.5f;
    g_hx[i] = (double)v;
    u16 b0, b1, b2; decomp3(v, b0, b1, b2);
    g_hxb[i] = b0; g_hxb[PSH + i] = b1; g_hxb[2 * PSH + i] = b2;
}

// ---------------- standalone step GEMM (probe + host-fallback path, NC stride) ----------------
__global__ __launch_bounds__(256) void step_gemm(int t, int probe) {
    __shared__ double shd[3168];
    int tid = threadIdx.x;
    int m0 = blockIdx.x * 32, n0 = blockIdx.y * 64;
    int use_mfma = g_ok && (probe || !g_badstep);
    if (use_mfma) {
        int lane = tid & 63, wave = tid >> 6;
        int wm = (wave & 1) * 16, wn = (wave >> 1) * 32;
        int lr = lane & 15, lk = lane >> 4;
        size_t ha  = (size_t)(m0 + wm + lr) * ND;
        size_t wb0 = (size_t)(n0 + wn + lr) * ND;
        size_t wb1 = (size_t)(n0 + wn + 16 + lr) * ND;
        f4v z = {0.f,0.f,0.f,0.f};
        f4v aP0=z, aP1=z, aC0=z, aC1=z;
        for (int k0 = 0; k0 < ND; k0 += 32) {
            int kk = k0 + 8 * lk;
            s8v a0  = *(const s8v*)(const void*)(g_hxb + ha + kk);
            s8v a1  = *(const s8v*)(const void*)(g_hxb + PSH + ha + kk);
            s8v a2  = *(const s8v*)(const void*)(g_hxb + 2*PSH + ha + kk);
            s8v b00 = *(const s8v*)(const void*)(g_Wstepb + wb0 + kk);
            s8v b01 = *(const s8v*)(const void*)(g_Wstepb + wb1 + kk);
            s8v b10 = *(const s8v*)(const void*)(g_Wstepb + PSWS + wb0 + kk);
            s8v b11 = *(const s8v*)(const void*)(g_Wstepb + PSWS + wb1 + kk);
            s8v b20 = *(const s8v*)(const void*)(g_Wstepb + 2*PSWS + wb0 + kk);
            s8v b21 = *(const s8v*)(const void*)(g_Wstepb + 2*PSWS + wb1 + kk);
            STEP6(aP0, aC0, a0, a1, a2, b00, b10, b20)
            STEP6(aP1, aC1, a0, a1, a2, b01, b11, b21)
        }
        int rb = m0 + wm + 4 * lk, cb0 = n0 + wn + lr, cb1 = cb0 + 16;
#pragma unroll
        for (int r = 0; r < 4; ++r) {
            g_gbufF[(size_t)(rb + r) * NC + cb0] = aP0[r] + aC0[r]
                + g_Pre[((size_t)t * NB + rb + r) * NC + cb0];
            g_gbufF[(size_t)(rb + r) * NC + cb1] = aP1[r] + aC1[r]
                + g_Pre[((size_t)t * NB + rb + r) * NC + cb1];
        }
    } else {
        double* Asd = shd;
        double* Wsd = shd + 1056;
        int tx = tid & 15, ty = tid >> 4;
        double acc[2][4] = {};
        for (int k0 = 0; k0 < ND; k0 += 32) {
            for (int i = tid; i < 1024; i += 256) {
                int r = i >> 5, c = i & 31;
                Asd[r * 33 + c] = g_hx[(size_t)(m0 + r) * ND + k0 + c];
            }
            for (int i = tid; i < 2048; i += 256) {
                int r = i >> 5, c = i & 31;
                Wsd[r * 33 + c] = (double)g_Wstep[(size_t)(n0 + r) * ND + k0 + c];
            }
            __syncthreads();
            for (int kk = 0; kk < 32; ++kk) {
                double a0 = Asd[(ty*2)*33+kk], a1 = Asd[(ty*2+1)*33+kk];
                double w0 = Wsd[(tx*4)*33+kk], w1 = Wsd[(tx*4+1)*33+kk], w2 = Wsd[(tx*4+2)*33+kk], w3 = Wsd[(tx*4+3)*33+kk];
                acc[0][0] += a0*w0; acc[0][1] += a0*w1; acc[0][2] += a0*w2; acc[0][3] += a0*w3;
                acc[1][0] += a1*w0; acc[1][1] += a1*w1; acc[1][2] += a1*w2; acc[1][3] += a1*w3;
            }
            __syncthreads();
        }
#pragma unroll
        for (int i = 0; i < 2; ++i)
#pragma unroll
            for (int j = 0; j < 4; ++j) {
                int m = m0 + ty*2 + i, n = n0 + tx*4 + j;
                g_gbufF[(size_t)m * NC + n] = (float)(acc[i][j]
                    + (double)g_Pre[((size_t)t * NB + m) * NC + n]);
            }
    }
}

// ---------------- verify standalone step (t=0, synthetic hx, NC stride) ----------------
__global__ void verify_step() {
    int s = blockIdx.x * 256 + threadIdx.x;
    unsigned m = ((unsigned)s * 2654435761u) & 127u;
    unsigned n = ((unsigned)s * 40503u + 7u) % 2560u;
    double dot = 0.0;
    const double* hr = g_hx + (size_t)m * ND;
    const float*  wr = g_Wstep + (size_t)n * ND;
    for (int c = 0; c < ND; ++c) dot += hr[c] * (double)wr[c];
    dot += (double)g_Pre[(size_t)m * NC + n];
    double got = (double)g_gbufF[(size_t)m * NC + n];
    if (fabs(got - dot) > 1e-4 * (1.0 + fabs(dot))) atomicOr(&g_badstep, 1);
}

// ---------------- verify fused probe output (gates 2048-stride + leap partials) ----------------
__global__ void verify_fused(const float* __restrict__ W2) {
    int s = blockIdx.x * 256 + threadIdx.x;    // 4096 samples
    unsigned m = ((unsigned)s * 2654435761u) & 127u;
    unsigned h2 = (unsigned)s * 40503u + 7u;
    const double* hr = g_hx + (size_t)m * ND;
    if (s & 1) {
        unsigned q = h2 & 31u;
        double p0 = 0.0, p1 = 0.0;
        for (int c = 0; c < 16; ++c) {
            int col = q * 16 + c;
            const float* wr = g_Wstep + (size_t)(2048 + col) * ND;
            double dot = 0.0;
            for (int k = 0; k < ND; ++k) dot += hr[k] * (double)wr[k];
            dot += (double)g_Pre[(size_t)m * NC + 2048 + col];
            double hh = dot > 0.0 ? dot : 0.0;
            p0 += hh * (double)W2[col];
            p1 += hh * (double)W2[512 + col];
        }
        if (fabs(g_lpart[q][m][0] - p0) > 1e-4 * (1.0 + fabs(p0)) ||
            fabs(g_lpart[q][m][1] - p1) > 1e-4 * (1.0 + fabs(p1)))
            atomicOr(&g_badfused, 1);
    } else {
        unsigned n = h2 % 2048u;
        double dot = 0.0;
        const float* wr = g_Wstep + (size_t)n * ND;
        for (int k = 0; k < ND; ++k) dot += hr[k] * (double)wr[k];
        dot += (double)g_Pre[(size_t)m * NC + n];
        double got = (double)g_gbufF[(size_t)m * 2048 + n];
        if (fabs(got - dot) > 1e-4 * (1.0 + fabs(dot))) atomicOr(&g_badfused, 1);
    }
}

// ---------------- standalone per-step update (host fallback, NC stride) ----------------
__global__ __launch_bounds__(256) void step_update(
    const float* __restrict__ W2, const float* __restrict__ b2,
    const int* __restrict__ lengths, int t) {
    __shared__ double red[8];
    __shared__ double skipsh[2];
    int b = blockIdx.x, tid = threadIdx.x, lane = tid & 63, wave = tid >> 6;
    const float* gb = g_gbufF + (size_t)b * NC;
    double p0 = 0.0, p1 = 0.0;
    for (int j = tid; j < ND; j += 256) {
        double h = (double)gb[2048 + j];
        h = h > 0.0 ? h : 0.0;
        p0 += h * (double)W2[j];
        p1 += h * (double)W2[ND + j];
    }
    for (int off = 32; off > 0; off >>= 1) {
        p0 += __shfl_down(p0, off, 64);
        p1 += __shfl_down(p1, off, 64);
    }
    if (lane == 0) { red[wave*2] = p0; red[wave*2+1] = p1; }
    __syncthreads();
    if (tid == 0) {
        double l0 = red[0]+red[2]+red[4]+red[6] + (double)b2[0];
        double l1 = red[1]+red[3]+red[5]+red[7] + (double)b2[1];
        double mx = fmax(l0, l1);
        double sh0 = l0 - mx, sh1 = l1 - mx;
        double lsum = log(exp(sh0) + exp(sh1));
        double y0 = (sh0 - lsum) - g_gum[(size_t)t * (NB * 2) + b * 2 + 0];
        double y1 = (sh1 - lsum) - g_gum[(size_t)t * (NB * 2) + b * 2 + 1];
        double xx0 = y0 / 1e-5, xx1 = y1 / 1e-5;
        double mm = fmax(xx0, xx1);
        double e0 = exp(xx0 - mm), e1 = exp(xx1 - mm);
        double inv = 1.0 / (e0 + e1);
        skipsh[0] = e0 * inv; skipsh[1] = e1 * inv;
    }
    __syncthreads();
    double s0 = skipsh[0], s1 = skipsh[1];
    bool isFinal = (t == lengths[b] - 1);
#pragma unroll
    for (int e = 0; e < 2; ++e) {
        int j = tid + 256 * e;
        size_t ix = (size_t)b * ND + j;
        double gi = (double)gb[j], gf = (double)gb[ND + j];
        double gg = (double)gb[2*ND + j], go = (double)gb[3*ND + j];
        double cn = sigd(gf) * g_c[ix] + sigd(gi) * tanh(gg);
        double shx = sigd(go) * tanh(cn);
        double hn = g_hx[ix] * s1 + shx * s0;
        g_c[ix] = cn; g_hx[ix] = hn;
        u16 w0, w1, w2x; decomp3((float)hn, w0, w1, w2x);
        g_hxb[ix] = w0; g_hxb[PSH + ix] = w1; g_hxb[2 * PSH + ix] = w2x;
        if (isFinal) g_final[ix] = hn;
    }
}

// ---------------- persistent flag-synced cooperative loop ----------------
// 160 blocks x 512 threads. Block owns 16 cols of Wstep (LDS). Blocks >=128 are
// leap-col blocks and deposit per-row partial logits. Block b<128 owns row b's
// register state and the per-step update. Sync: per-block aflag (A done),
// per-row hxf (B done); per-wave 16-row panel waits pipeline B->A.
// Phase A issues all 24 A-fragment loads per half-pass before consuming (miss
// concurrency ~24/wave); Pre(t+1) prefetch issued AFTER the aflag release so
// it doesn't extend the release fence's vmcnt(0) wait.
__global__ __launch_bounds__(512, 1) void loop_fused(const float* __restrict__ W2,
                                                     const float* __restrict__ b2,
                                                     const int* __restrict__ lengths,
                                                     int steps, int probe) {
    __shared__ __align__(16) unsigned char shm[53504];
    int bid = blockIdx.x, tid = threadIdx.x;
    int nc0 = bid * 16;
    int w = tid >> 6, lane = tid & 63;
    int lr = lane & 15, lk = lane >> 4;
    int path = g_ok && !g_badfused;
    double c0 = 0.0, h0 = 0.0;                 // register state elem (row=bid, j=tid)
    int mylen = (bid < NB) ? lengths[bid] : -1;
    u16*    Wl     = (u16*)shm;                // 48KB bf16x3 weights (path)
    float*  Wfb    = (float*)shm;              // 32KB f32 weights (fallback overlay)
    float*  W2l    = (float*)(shm + 49152);    // 4KB
    double* skipsh = (double*)(shm + 53248);
    if (path) {
        for (int i = tid; i < 3072; i += 512) {
            int p = i >> 10, rem = i & 1023, kk = rem >> 6, l = rem & 63;
            int col = l & 15, k8 = l >> 4;
            *(uint4*)(void*)(Wl + (size_t)p*8192 + kk*512 + l*8) =
                *(const uint4*)(const void*)(g_Wstepb + (size_t)p*PSWS
                      + (size_t)(nc0 + col)*ND + kk*32 + k8*8);
        }
    } else {
        for (int i = tid; i < 16*512; i += 512)
            Wfb[i] = g_Wstep[(size_t)(nc0 + (i >> 9))*ND + (i & 511)];
    }
    for (int i = tid; i < 1024; i += 512) W2l[i] = W2[i];
    __syncthreads();
    int r0 = 16*w + 4*lk;
    float preA[4];
    if (path) {
#pragma unroll
        for (int r = 0; r < 4; ++r)
            preA[r] = g_Pre[((size_t)0 * NB + r0 + r) * NC + nc0 + lr];
    }
    for (int t = 0; t < steps; ++t) {
        // ---- phase A ----
        if (path) {
            if (t > 0) {   // per-wave wait on its 16-row panel's hx
                for (;;) {
                    bool ok = true;
                    if (lane < 16)
                        ok = (__hip_atomic_load(&g_hxf[(16*w + lane)*32],
                               __ATOMIC_RELAXED, __HIP_MEMORY_SCOPE_AGENT) >= t);
                    if (__all(ok)) break;
                    __builtin_amdgcn_s_sleep(1);
                }
                __builtin_amdgcn_fence(__ATOMIC_ACQUIRE, "agent");
            }
            f4v z = {0.f,0.f,0.f,0.f};
            f4v aP = z, aC = z;
            size_t ha = (size_t)(16*w + lr) * ND;
#pragma unroll
            for (int h = 0; h < 2; ++h) {
                s8v A0[8], A1[8], A2[8];
#pragma unroll
                for (int kk = 0; kk < 8; ++kk) {     // issue all 24 loads first
                    int kb = (8*h + kk)*32 + 8*lk;
                    A0[kk] = *(const s8v*)(const void*)(g_hxb + ha + kb);
                    A1[kk] = *(const s8v*)(const void*)(g_hxb + PSH + ha + kb);
                    A2[kk] = *(const s8v*)(const void*)(g_hxb + 2*PSH + ha + kb);
                }
#pragma unroll
                for (int kk = 0; kk < 8; ++kk) {     // consume
                    const u16* wp = Wl + (8*h + kk)*512 + lane*8;
                    s8v B0 = *(const s8v*)(const void*)(wp);
                    s8v B1 = *(const s8v*)(const void*)(wp + 8192);
                    s8v B2 = *(const s8v*)(const void*)(wp + 16384);
                    STEP6(aP, aC, A0[kk], A1[kk], A2[kk], B0, B1, B2)
                }
            }
            if (bid < NB) {
#pragma unroll
                for (int r = 0; r < 4; ++r)
                    g_gbufF[(size_t)(r0 + r) * 2048 + nc0 + lr] = aP[r] + aC[r] + preA[r];
            } else {
                int colg = nc0 - 2048 + lr;
                double q0[4], q1[4];
#pragma unroll
                for (int r = 0; r < 4; ++r) {
                    float v = aP[r] + aC[r] + preA[r];
                    double hh = v > 0.f ? (double)v : 0.0;
                    q0[r] = hh * (double)W2l[colg];
                    q1[r] = hh * (double)W2l[512 + colg];
                }
#pragma unroll
                for (int m = 8; m > 0; m >>= 1)
#pragma unroll
                    for (int r = 0; r < 4; ++r) {
                        q0[r] += __shfl_xor(q0[r], m, 16);
                        q1[r] += __shfl_xor(q1[r], m, 16);
                    }
                if (lr == 0)
#pragma unroll
                    for (int r = 0; r < 4; ++r) {
                        g_lpart[bid - NB][r0 + r][0] = q0[r];
                        g_lpart[bid - NB][r0 + r][1] = q1[r];
                    }
            }
        } else {
            // ---- f64 vector fallback phase A (block-level wait) ----
            if (t > 0) {
                if (tid < NB) {
                    while (__hip_atomic_load(&g_hxf[tid*32], __ATOMIC_RELAXED,
                             __HIP_MEMORY_SCOPE_AGENT) < t)
                        __builtin_amdgcn_s_sleep(1);
                }
                __syncthreads();
                if (tid == 0) __builtin_amdgcn_fence(__ATOMIC_ACQUIRE, "agent");
                __syncthreads();
            }
            int col = tid & 15, rgrp = tid >> 4;
            double q0[4] = {}, q1[4] = {};
#pragma unroll
            for (int rr = 0; rr < 4; ++rr) {
                int row = rgrp*4 + rr;
                const double* hr = g_hx + (size_t)row * ND;
                double dot = 0.0;
                for (int k = 0; k < ND; ++k) dot += hr[k] * (double)Wfb[col*512 + k];
                float v = (float)(dot + (double)g_Pre[((size_t)t * NB + row) * NC + nc0 + col]);
                if (bid < NB) {
                    g_gbufF[(size_t)row * 2048 + nc0 + col] = v;
                } else {
                    double hh = v > 0.f ? (double)v : 0.0;
                    q0[rr] = hh * (double)W2l[nc0 - 2048 + col];
                    q1[rr] = hh * (double)W2l[512 + nc0 - 2048 + col];
                }
            }
            if (bid >= NB) {
#pragma unroll
                for (int m = 8; m > 0; m >>= 1)
#pragma unroll
                    for (int rr = 0; rr < 4; ++rr) {
                        q0[rr] += __shfl_xor(q0[rr], m, 16);
                        q1[rr] += __shfl_xor(q1[rr], m, 16);
                    }
                if (col == 0)
#pragma unroll
                    for (int rr = 0; rr < 4; ++rr) {
                        g_lpart[bid - NB][rgrp*4 + rr][0] = q0[rr];
                        g_lpart[bid - NB][rgrp*4 + rr][1] = q1[rr];
                    }
            }
        }
        __syncthreads();
        if (tid == 0) {
            __builtin_amdgcn_fence(__ATOMIC_RELEASE, "agent");
            __hip_atomic_store(&g_aflag[bid*32], t + 1, __ATOMIC_RELAXED,
                               __HIP_MEMORY_SCOPE_AGENT);
        }
        __syncthreads();
        // prefetch next step's Pre slice AFTER the release (overlaps phase B)
        if (path) {
            int tn = (t + 1 < steps) ? t + 1 : t;
#pragma unroll
            for (int r = 0; r < 4; ++r)
                preA[r] = g_Pre[((size_t)tn * NB + r0 + r) * NC + nc0 + lr];
        }
        // ---- phase B (row owner) ----
        if (!probe && bid < NB) {
            if (tid < 160) {
                while (__hip_atomic_load(&g_aflag[tid*32], __ATOMIC_RELAXED,
                         __HIP_MEMORY_SCOPE_AGENT) < t + 1)
                    __builtin_amdgcn_s_sleep(1);
            }
            __syncthreads();
            if (tid == 0) __builtin_amdgcn_fence(__ATOMIC_ACQUIRE, "agent");
            __syncthreads();
            double p0 = 0.0, p1 = 0.0;
            if (tid < 32) { p0 = g_lpart[tid][bid][0]; p1 = g_lpart[tid][bid][1]; }
            if (tid < 64) {
#pragma unroll
                for (int m = 16; m > 0; m >>= 1) {
                    p0 += __shfl_xor(p0, m, 32);
                    p1 += __shfl_xor(p1, m, 32);
                }
            }
            if (tid == 0) {
                double l0 = p0 + (double)b2[0], l1 = p1 + (double)b2[1];
                double mx = fmax(l0, l1);
                double sh0 = l0 - mx, sh1 = l1 - mx;
                double lsum = log(exp(sh0) + exp(sh1));
                double y0 = (sh0 - lsum) - g_gum[(size_t)t * (NB*2) + bid*2 + 0];
                double y1 = (sh1 - lsum) - g_gum[(size_t)t * (NB*2) + bid*2 + 1];
                double xx0 = y0 / 1e-5, xx1 = y1 / 1e-5;
                double mm = fmax(xx0, xx1);
                double e0 = exp(xx0 - mm), e1 = exp(xx1 - mm);
                double inv = 1.0 / (e0 + e1);
                skipsh[0] = e0 * inv; skipsh[1] = e1 * inv;
            }
            __syncthreads();
            double s0 = skipsh[0], s1 = skipsh[1];
            bool isFinal = (t == mylen - 1);
            {
                int j = tid;
                size_t ix = (size_t)bid * ND + j;
                const float* gb = g_gbufF + (size_t)bid * 2048;
                double gi = (double)gb[j], gf = (double)gb[512 + j];
                double gg = (double)gb[1024 + j], go = (double)gb[1536 + j];
                double cn = sigd(gf) * c0 + sigd(gi) * tanh(gg);
                double shx = sigd(go) * tanh(cn);
                double hn = h0 * s1 + shx * s0;
                c0 = cn; h0 = hn;
                u16 w0_, w1_, w2_; decomp3((float)hn, w0_, w1_, w2_);
                g_hxb[ix] = w0_; g_hxb[PSH + ix] = w1_; g_hxb[2*PSH + ix] = w2_;
                if (!path) g_hx[ix] = hn;
                if (isFinal) g_final[ix] = hn;
            }
            __syncthreads();
            if (tid == 0) {
                __builtin_amdgcn_fence(__ATOMIC_RELEASE, "agent");
                __hip_atomic_store(&g_hxf[bid*32], t + 1, __ATOMIC_RELAXED,
                                   __HIP_MEMORY_SCOPE_AGENT);
            }
        }
    }
}

// ---------------- final projection ----------------
__global__ __launch_bounds__(256) void final_out(const float* __restrict__ Wo,
                                                 const float* __restrict__ bo,
                                                 float* __restrict__ out) {
    int tid = threadIdx.x;
    int b = tid >> 1, k = tid & 1;
    double acc = 0.0;
    const double* f = g_final + (size_t)b * ND;
    const float* w = Wo + (size_t)k * ND;
    for (int d = 0; d < ND; ++d) acc += f[d] * (double)w[d];
    out[b * 2 + k] = (float)(acc + (double)bo[k]);
}

// ---------------- host launcher ----------------
extern "C" void kernel_launch(void* const* d_in, const int* in_sizes, int n_in,
                              void* d_out, int out_size, void* d_ws, size_t ws_size,
                              hipStream_t stream) {
    (void)in_sizes; (void)n_in; (void)d_ws; (void)ws_size; (void)out_size;
    const int*   seqs    = (const int*)d_in[0];
    const int*   lengths = (const int*)d_in[2];
    const float* emb     = (const float*)d_in[5];
    const float* revWih  = (const float*)d_in[6];
    const float* revWhh  = (const float*)d_in[7];
    const float* convw   = (const float*)d_in[8];
    const float* W1      = (const float*)d_in[9];
    const float* b1      = (const float*)d_in[10];
    const float* W2      = (const float*)d_in[11];
    const float* b2      = (const float*)d_in[12];
    const float* cWih    = (const float*)d_in[13];
    const float* cWhh    = (const float*)d_in[14];
    const float* Wo      = (const float*)d_in[15];
    const float* bo      = (const float*)d_in[16];
    float* out = (float*)d_out;

    double *A_p = nullptr, *Ap_p = nullptr;
    hipGetSymbolAddress((void**)&A_p,  HIP_SYMBOL(g_A));
    hipGetSymbolAddress((void**)&Ap_p, HIP_SYMBOL(g_Aproj));

    probe_bf16<<<1, 64, 0, stream>>>();
    build_w<<<NC, 256, 0, stream>>>(cWih, cWhh, W1, b1);
    gumbel_init<<<256, 256, 0, stream>>>();
    embed_sum<<<NBS, 128, 0, stream>>>(seqs, emb);

    gemm_f64<<<dim3(NBS / 64, 1), 256, 0, stream>>>(A_p, KE, revWih, ND, Ap_p, 40,
                                                    NBS, 40, ND);
    rev_lstm<<<NB, 64, 0, stream>>>(revWhh);
    conv_relu<<<dim3(NB, NS / 8), 256, 0, stream>>>(convw);

    big_gemm<<<dim3(NC / 64, NBS / 64), 256, 0, stream>>>();
    verify_pre<<<32, 256, 0, stream>>>();
    big_fix<<<2048, 256, 0, stream>>>();

    // probes on synthetic state
    synth_hx<<<256, 256, 0, stream>>>();
    step_gemm<<<dim3(4, 40), 256, 0, stream>>>(0, 1);
    verify_step<<<8, 256, 0, stream>>>();
    {   // fused phase-A probe (1 step, B skipped)
        int steps1 = 1, probe1 = 1;
        void* pargs[] = { (void*)&W2, (void*)&b2, (void*)&lengths,
                          (void*)&steps1, (void*)&probe1 };
        hipError_t pe = hipLaunchCooperativeKernel((const void*)loop_fused,
                                                   dim3(160), dim3(512), pargs, 0, stream);
        if (pe == hipSuccess) verify_fused<<<16, 256, 0, stream>>>(W2);
        else (void)hipGetLastError();
    }
    init_state<<<256, 256, 0, stream>>>();   // resets state + aflag/hxf

    int stepsN = NS, probe0 = 0;
    void* args[] = { (void*)&W2, (void*)&b2, (void*)&lengths,
                     (void*)&stepsN, (void*)&probe0 };
    hipError_t ce = hipLaunchCooperativeKernel((const void*)loop_fused,
                                               dim3(160), dim3(512), args, 0, stream);
    if (ce != hipSuccess) {
        (void)hipGetLastError();
        for (int t = 0; t < NS; ++t) {
            step_gemm<<<dim3(4, 40), 256, 0, stream>>>(t, 0);
            step_update<<<NB, 256, 0, stream>>>(W2, b2, lengths, t);
        }
    }
    final_out<<<1, 256, 0, stream>>>(Wo, bo, out);
}

// Round 13
// 9158.652 us; speedup vs baseline: 2.0377x; 1.3536x over previous
//
#include <hip/hip_runtime.h>
#include <math.h>

#define NB 128
#define NS 256
#define ND 512
#define NBS (NB*NS)   // 32768
#define KE 544        // 512 x | 10 back | 20 cnn | 1 bias | 1 pad
#define NC 2560       // 2048 cell gates + 512 leap hidden

typedef unsigned short u16;
typedef __attribute__((ext_vector_type(8))) short s8v;     // 8 bf16
typedef __attribute__((ext_vector_type(4))) float f4v;     // 4 f32 acc
typedef __attribute__((ext_vector_type(4))) unsigned uv4;  // 16B asm payload
typedef __attribute__((ext_vector_type(2))) double dv2;    // 16B asm payload

static constexpr size_t PSA  = (size_t)NBS * KE;
static constexpr size_t PSWE = (size_t)NC  * KE;
static constexpr size_t PSWS = (size_t)NC  * ND;
static constexpr size_t PSH  = (size_t)NB  * ND;

// ---------------- device-global scratch ----------------
__device__ double g_A[(size_t)NBS * KE];
__device__ u16    g_Ab[3 * PSA];
__device__ float  g_Pre[(size_t)NBS * NC];    // layout [t][b][n]
__device__ double g_Aproj[(size_t)NBS * 40];
__device__ double g_gum[NS * NB * 2];
__device__ double g_hx[NB * ND];
__device__ u16    g_hxb[3 * NB * ND];
__device__ double g_c[NB * ND];
__device__ float  g_gbufF[NB * NC];           // fused path uses [128][2048] gates region
__device__ double g_final[NB * ND];
__device__ float  g_Wext[PSWE];
__device__ u16    g_Wextb[3 * PSWE];
__device__ float  g_Wstep[PSWS];
__device__ u16    g_Wstepb[3 * PSWS];
__device__ double g_lpart[32][NB][2];         // leap partial logits
__device__ int    g_aflag[160 * 32];          // per-block A-completion (128B apart)
__device__ int    g_hxf[NB * 32];             // per-row B-completion
__device__ int    g_ok, g_bad, g_badstep, g_badfused;

__device__ __forceinline__ double sigd(double x) { return 1.0 / (1.0 + exp(-x)); }
__device__ __forceinline__ u16 f2bf(float f) {
    unsigned u = __float_as_uint(f);
    return (u16)((u + 0x7FFFu + ((u >> 16) & 1u)) >> 16);   // RNE
}
__device__ __forceinline__ float bf2f(u16 b) { return __uint_as_float(((unsigned)b) << 16); }
__device__ __forceinline__ void decomp3(float f, u16& b0, u16& b1, u16& b2) {
    b0 = f2bf(f); float r1 = f - bf2f(b0);
    b1 = f2bf(r1); float r2 = r1 - bf2f(b1);
    b2 = f2bf(r2);
}
__device__ __forceinline__ size_t pre_ix(int m /*b*NS+s*/, int n) {
    return ((size_t)(m & 255) * NB + (m >> 8)) * NC + n;    // -> [s][b][n]
}
__device__ __forceinline__ void put_Ab(size_t ix, float f) {
    u16 b0, b1, b2; decomp3(f, b0, b1, b2);
    g_Ab[ix] = b0; g_Ab[PSA + ix] = b1; g_Ab[2 * PSA + ix] = b2;
}

// ---- coherence-point (MALL) access helpers: bypass L1/L2, no fences needed ----
__device__ __forceinline__ void sc_store_f32(float* p, float v) {
    asm volatile("global_store_dword %0, %1, off sc0 sc1" :: "v"(p), "v"(v) : "memory");
}
__device__ __forceinline__ void sc_store_u16(u16* p, unsigned v) {
    asm volatile("global_store_short %0, %1, off sc0 sc1" :: "v"(p), "v"(v) : "memory");
}
__device__ __forceinline__ void sc_store_d2(double* p, dv2 v) {
    asm volatile("global_store_dwordx4 %0, %1, off sc0 sc1" :: "v"(p), "v"(v) : "memory");
}
#define SC_WAIT() do { asm volatile("s_waitcnt vmcnt(0)" ::: "memory"); \
                       __builtin_amdgcn_sched_barrier(0); } while (0)

#define MFMA_BF16 __builtin_amdgcn_mfma_f32_16x16x32_bf16
#define STEP6(AP,AC,A0,A1,A2,B0,B1,B2) \
    AP = MFMA_BF16(A0, B0, AP, 0, 0, 0); \
    AC = MFMA_BF16(A0, B1, AC, 0, 0, 0); \
    AC = MFMA_BF16(A1, B0, AC, 0, 0, 0); \
    AC = MFMA_BF16(A0, B2, AC, 0, 0, 0); \
    AC = MFMA_BF16(A1, B1, AC, 0, 0, 0); \
    AC = MFMA_BF16(A2, B0, AC, 0, 0, 0);

// ---------------- bf16 MFMA layout probe ----------------
__global__ void probe_bf16() {
    int l = threadIdx.x, lr = l & 15, lk = l >> 4;
    s8v a, b;
#pragma unroll
    for (int e = 0; e < 8; ++e) {
        int k = 8 * lk + e;
        a[e] = (short)f2bf((float)(((3 * lr + 7 * k) % 13) + 1));
        b[e] = (short)f2bf((float)(((5 * k + 11 * lr) % 17) + 1));
    }
    f4v d = {0.f, 0.f, 0.f, 0.f};
    d = MFMA_BF16(a, b, d, 0, 0, 0);
    bool okl = true;
#pragma unroll
    for (int r = 0; r < 4; ++r) {
        int row = 4 * lk + r, col = lr;
        int e = 0;
        for (int k = 0; k < 32; ++k)
            e += (((3 * row + 7 * k) % 13) + 1) * (((5 * k + 11 * col) % 17) + 1);
        if (d[r] != (float)e) okl = false;
    }
    unsigned long long vote = __ballot(okl);
    if (l == 0) {
        g_ok = (vote == 0xFFFFFFFFFFFFFFFFull) ? 1 : 0;
        g_bad = 0; g_badstep = 0; g_badfused = 0;
    }
}

// ---------------- init (state + sync flags) ----------------
__global__ void init_state() {
    int i = blockIdx.x * 256 + threadIdx.x;
    if (i < 160 * 32) g_aflag[i] = 0;
    if (i < NB * 32)  g_hxf[i]  = 0;
    if (i < NB * ND) {
        g_hx[i] = 0.0; g_c[i] = 0.0;
        g_hxb[i] = 0; g_hxb[PSH + i] = 0; g_hxb[2 * PSH + i] = 0;
    }
}

// ---------------- weight repack + bf16x3 ----------------
__global__ __launch_bounds__(256) void build_w(const float* __restrict__ cWih,
                                               const float* __restrict__ cWhh,
                                               const float* __restrict__ W1,
                                               const float* __restrict__ b1) {
    int n = blockIdx.x;
    for (int c = threadIdx.x; c < KE; c += 256) {
        float we;
        if (n < 2048) we = (c < 512) ? cWih[(size_t)n * 512 + c] : 0.f;
        else {
            int n2 = n - 2048;
            if      (c < 512)  we = W1[(size_t)n2 * 1054 + 512 + c];
            else if (c < 522)  we = W1[(size_t)n2 * 1054 + 1024 + (c - 512)];
            else if (c < 542)  we = W1[(size_t)n2 * 1054 + 1034 + (c - 522)];
            else if (c == 542) we = b1[n2];
            else               we = 0.f;
        }
        size_t ix = (size_t)n * KE + c;
        g_Wext[ix] = we;
        u16 b0, b1_, b2; decomp3(we, b0, b1_, b2);
        g_Wextb[ix] = b0; g_Wextb[PSWE + ix] = b1_; g_Wextb[2 * PSWE + ix] = b2;
        if (c < 512) {
            float ws = (n < 2048) ? cWhh[(size_t)n * 512 + c]
                                  : W1[(size_t)(n - 2048) * 1054 + c];
            size_t ix2 = (size_t)n * ND + c;
            g_Wstep[ix2] = ws;
            decomp3(ws, b0, b1_, b2);
            g_Wstepb[ix2] = b0; g_Wstepb[PSWS + ix2] = b1_; g_Wstepb[2 * PSWS + ix2] = b2;
        }
    }
}

// ---------------- gumbel: JAX partitionable threefry2x32, key (0,42) ----------------
__device__ __forceinline__ unsigned rotl32(unsigned x, int r) { return (x << r) | (x >> (32 - r)); }

__global__ void gumbel_init() {
    unsigned p = blockIdx.x * 256 + threadIdx.x;
    if (p >= 65536u) return;
    unsigned k0 = 0u, k1 = 42u;
    unsigned ks2 = k0 ^ k1 ^ 0x1BD11BDAu;
    unsigned x0 = 0u, x1 = p;
    x0 += k0; x1 += k1;
#define RND(r) { x0 += x1; x1 = rotl32(x1, (r)); x1 ^= x0; }
    RND(13) RND(15) RND(26) RND(6)
    x0 += k1;  x1 += ks2 + 1u;
    RND(17) RND(29) RND(16) RND(24)
    x0 += ks2; x1 += k0 + 2u;
    RND(13) RND(15) RND(26) RND(6)
    x0 += k0;  x1 += k1 + 3u;
    RND(17) RND(29) RND(16) RND(24)
    x0 += k1;  x1 += ks2 + 4u;
    RND(13) RND(15) RND(26) RND(6)
    x0 += ks2; x1 += k0 + 5u;
#undef RND
    unsigned bits = x0 ^ x1;
    float u = __uint_as_float((bits >> 9) | 0x3f800000u) - 1.0f;
    g_gum[p] = log(-log((double)u + 1e-20) + 1e-20);
}

// ---------------- embedding gather+sum (writes f64 + bf16x3 planes) ----------------
__global__ __launch_bounds__(128) void embed_sum(const int* __restrict__ seqs,
                                                 const float* __restrict__ emb) {
    int bs = blockIdx.x;
    int tid = threadIdx.x;
    __shared__ int idxs[16];
    if (tid < 16) idxs[tid] = seqs[(size_t)bs * 16 + tid];
    __syncthreads();
    double a0 = 0, a1 = 0, a2 = 0, a3 = 0;
    for (int v = 0; v < 16; ++v) {
        const float4* row = (const float4*)(emb + (size_t)idxs[v] * ND);
        float4 e = row[tid];
        a0 += (double)e.x; a1 += (double)e.y; a2 += (double)e.z; a3 += (double)e.w;
    }
    size_t base = (size_t)bs * KE + tid * 4;
    double* o = g_A + base;
    o[0] = a0; o[1] = a1; o[2] = a2; o[3] = a3;
    put_Ab(base + 0, (float)a0); put_Ab(base + 1, (float)a1);
    put_Ab(base + 2, (float)a2); put_Ab(base + 3, (float)a3);
    if (tid == 0) {
        g_A[(size_t)bs * KE + 542] = 1.0; g_A[(size_t)bs * KE + 543] = 0.0;
        put_Ab((size_t)bs * KE + 542, 1.0f); put_Ab((size_t)bs * KE + 543, 0.0f);
    }
}

// ---------------- f64 vector GEMM (Aproj only) ----------------
__global__ __launch_bounds__(256) void gemm_f64(
    const double* __restrict__ A, int lda,
    const float* __restrict__ W, int ldw,
    double* __restrict__ C, int ldc,
    int M, int N, int K) {
    __shared__ double As[16][66];
    __shared__ double Ws[16][66];
    int m0 = blockIdx.x * 64, n0 = blockIdx.y * 64;
    int tid = threadIdx.x, tx = tid & 15, ty = tid >> 4;
    double acc[4][4] = {};
    for (int k0 = 0; k0 < K; k0 += 16) {
        for (int i = tid; i < 1024; i += 256) {
            int r = i >> 4, c = i & 15;
            As[c][r] = (m0 + r < M && k0 + c < K) ? A[(size_t)(m0 + r) * lda + k0 + c] : 0.0;
            Ws[c][r] = (n0 + r < N && k0 + c < K) ? (double)W[(size_t)(n0 + r) * ldw + k0 + c] : 0.0;
        }
        __syncthreads();
#pragma unroll
        for (int kk = 0; kk < 16; ++kk) {
            double a0 = As[kk][ty*4], a1 = As[kk][ty*4+1], a2 = As[kk][ty*4+2], a3 = As[kk][ty*4+3];
            double w0 = Ws[kk][tx*4], w1 = Ws[kk][tx*4+1], w2 = Ws[kk][tx*4+2], w3 = Ws[kk][tx*4+3];
            acc[0][0] += a0*w0; acc[0][1] += a0*w1; acc[0][2] += a0*w2; acc[0][3] += a0*w3;
            acc[1][0] += a1*w0; acc[1][1] += a1*w1; acc[1][2] += a1*w2; acc[1][3] += a1*w3;
            acc[2][0] += a2*w0; acc[2][1] += a2*w1; acc[2][2] += a2*w2; acc[2][3] += a2*w3;
            acc[3][0] += a3*w0; acc[3][1] += a3*w1; acc[3][2] += a3*w2; acc[3][3] += a3*w3;
        }
        __syncthreads();
    }
#pragma unroll
    for (int i = 0; i < 4; ++i)
#pragma unroll
        for (int j = 0; j < 4; ++j) {
            int m = m0 + ty*4 + i, n = n0 + tx*4 + j;
            if (m < M && n < N) C[(size_t)m * ldc + n] = acc[i][j];
        }
}

// ---------------- reverse LSTM (writes f64 + planes) ----------------
__global__ __launch_bounds__(64) void rev_lstm(const float* __restrict__ Whh) {
    int b = blockIdx.x;
    int tid = threadIdx.x;
    __shared__ double h[10], cc[10], g[40], wsh[400];
    for (int i = tid; i < 400; i += 64) wsh[i] = (double)Whh[i];
    if (tid < 10) { h[tid] = 0.0; cc[tid] = 0.0; }
    __syncthreads();
    for (int s = NS - 1; s >= 0; --s) {
        if (tid < 40) {
            double acc = g_Aproj[((size_t)b * NS + s) * 40 + tid];
#pragma unroll
            for (int k = 0; k < 10; ++k) acc += h[k] * wsh[tid * 10 + k];
            g[tid] = acc;
        }
        __syncthreads();
        if (tid < 10) {
            double gi = g[tid], gf = g[10 + tid], gg = g[20 + tid], go = g[30 + tid];
            double cn = sigd(gf) * cc[tid] + sigd(gi) * tanh(gg);
            cc[tid] = cn;
            double hn = sigd(go) * tanh(cn);
            h[tid] = hn;
            size_t ix = ((size_t)b * NS + s) * KE + 512 + tid;
            g_A[ix] = hn;
            put_Ab(ix, (float)hn);
        }
        __syncthreads();
    }
}

// ---------------- conv1d + relu (writes f64 + planes) ----------------
__global__ __launch_bounds__(256) void conv_relu(const float* __restrict__ w) {
    int b = blockIdx.x, s0 = blockIdx.y * 8;
    int tid = threadIdx.x, grp = tid >> 5, lane = tid & 31;
    __shared__ double xs[10][ND];
    for (int i = tid; i < 10 * ND; i += 256) {
        int r = i >> 9, d = i & (ND - 1);
        int s = s0 - 1 + r;
        xs[r][d] = (s >= 0 && s < NS) ? g_A[((size_t)b * NS + s) * KE + d] : 0.0;
    }
    __syncthreads();
    int s = s0 + grp;
    for (int o = 0; o < 20; ++o) {
        const float* wo = w + (size_t)o * 1536;
        double acc = 0.0;
        for (int d = lane; d < ND; d += 32) {
            acc += xs[grp][d]     * (double)wo[d*3]
                 + xs[grp + 1][d] * (double)wo[d*3 + 1]
                 + xs[grp + 2][d] * (double)wo[d*3 + 2];
        }
        for (int m = 16; m > 0; m >>= 1) acc += __shfl_xor(acc, m, 32);
        if (lane == 0) {
            double v = acc > 0.0 ? acc : 0.0;
            size_t ix = ((size_t)b * NS + s) * KE + 522 + o;
            g_A[ix] = v;
            put_Ab(ix, (float)v);
        }
    }
}

// ---------------- big GEMM: g_Pre[t][b][n] = g_A @ g_Wext^T ----------------
__global__ __launch_bounds__(256) void big_gemm() {
    __shared__ __align__(16) unsigned char shm[36864];
    int tid = threadIdx.x;
    int n0 = blockIdx.x * 64, m0 = blockIdx.y * 64;
    if (g_ok) {
        u16* usA = (u16*)shm;
        u16* usB = usA + 9216;
        int lane = tid & 63, wave = tid >> 6;
        int wm = (wave & 1) * 32, wn = (wave >> 1) * 32;
        int lr = lane & 15, lk = lane >> 4;
        f4v z = {0.f,0.f,0.f,0.f};
        f4v aP00=z,aP01=z,aP10=z,aP11=z, aC00=z,aC01=z,aC10=z,aC11=z;
        for (int k0 = 0; k0 < KE; k0 += 32) {
            for (int i = tid; i < 1536; i += 256) {
                if (i < 768) {
                    int p = i >> 8, rem = i & 255, r = rem >> 2, sg = rem & 3;
                    *(uint4*)(void*)(usA + p*3072 + r*48 + sg*8) =
                        *(const uint4*)(const void*)(g_Ab + (size_t)p*PSA + (size_t)(m0+r)*KE + k0 + sg*8);
                } else {
                    int j = i - 768;
                    int p = j >> 8, rem = j & 255, r = rem >> 2, sg = rem & 3;
                    *(uint4*)(void*)(usB + p*3072 + r*48 + sg*8) =
                        *(const uint4*)(const void*)(g_Wextb + (size_t)p*PSWE + (size_t)(n0+r)*KE + k0 + sg*8);
                }
            }
            __syncthreads();
            const u16* pa = usA + (wm + lr) * 48 + 8 * lk;
            const u16* pb = usB + (wn + lr) * 48 + 8 * lk;
            s8v a0_0 = *(const s8v*)(const void*)(pa);
            s8v a0_1 = *(const s8v*)(const void*)(pa + 768);
            s8v a1_0 = *(const s8v*)(const void*)(pa + 3072);
            s8v a1_1 = *(const s8v*)(const void*)(pa + 3840);
            s8v a2_0 = *(const s8v*)(const void*)(pa + 6144);
            s8v a2_1 = *(const s8v*)(const void*)(pa + 6912);
            s8v b0_0 = *(const s8v*)(const void*)(pb);
            s8v b0_1 = *(const s8v*)(const void*)(pb + 768);
            s8v b1_0 = *(const s8v*)(const void*)(pb + 3072);
            s8v b1_1 = *(const s8v*)(const void*)(pb + 3840);
            s8v b2_0 = *(const s8v*)(const void*)(pb + 6144);
            s8v b2_1 = *(const s8v*)(const void*)(pb + 6912);
            STEP6(aP00, aC00, a0_0, a1_0, a2_0, b0_0, b1_0, b2_0)
            STEP6(aP01, aC01, a0_0, a1_0, a2_0, b0_1, b1_1, b2_1)
            STEP6(aP10, aC10, a0_1, a1_1, a2_1, b0_0, b1_0, b2_0)
            STEP6(aP11, aC11, a0_1, a1_1, a2_1, b0_1, b1_1, b2_1)
            __syncthreads();
        }
        int rb = m0 + wm + 4 * lk, cb0 = n0 + wn + lr, cb1 = cb0 + 16;
#pragma unroll
        for (int r = 0; r < 4; ++r) {
            g_Pre[pre_ix(rb + r, cb0)]      = aP00[r] + aC00[r];
            g_Pre[pre_ix(rb + r, cb1)]      = aP01[r] + aC01[r];
            g_Pre[pre_ix(rb + 16 + r, cb0)] = aP10[r] + aC10[r];
            g_Pre[pre_ix(rb + 16 + r, cb1)] = aP11[r] + aC11[r];
        }
    } else {
        double* Asd = (double*)shm;
        double* Wsd = Asd + 64 * 33;
        int tx = tid & 15, ty = tid >> 4;
        double acc[4][4] = {};
        for (int k0 = 0; k0 < KE; k0 += 32) {
            for (int i = tid; i < 2048; i += 256) {
                int r = i >> 5, c = i & 31;
                Asd[r * 33 + c] = g_A[(size_t)(m0 + r) * KE + k0 + c];
                Wsd[r * 33 + c] = (double)g_Wext[(size_t)(n0 + r) * KE + k0 + c];
            }
            __syncthreads();
            for (int kk = 0; kk < 32; ++kk) {
                double a0 = Asd[(ty*4)*33+kk], a1 = Asd[(ty*4+1)*33+kk], a2 = Asd[(ty*4+2)*33+kk], a3 = Asd[(ty*4+3)*33+kk];
                double w0 = Wsd[(tx*4)*33+kk], w1 = Wsd[(tx*4+1)*33+kk], w2 = Wsd[(tx*4+2)*33+kk], w3 = Wsd[(tx*4+3)*33+kk];
                acc[0][0] += a0*w0; acc[0][1] += a0*w1; acc[0][2] += a0*w2; acc[0][3] += a0*w3;
                acc[1][0] += a1*w0; acc[1][1] += a1*w1; acc[1][2] += a1*w2; acc[1][3] += a1*w3;
                acc[2][0] += a2*w0; acc[2][1] += a2*w1; acc[2][2] += a2*w2; acc[2][3] += a2*w3;
                acc[3][0] += a3*w0; acc[3][1] += a3*w1; acc[3][2] += a3*w2; acc[3][3] += a3*w3;
            }
            __syncthreads();
        }
#pragma unroll
        for (int i = 0; i < 4; ++i)
#pragma unroll
            for (int j = 0; j < 4; ++j)
                g_Pre[pre_ix(m0 + ty*4 + i, n0 + tx*4 + j)] = (float)acc[i][j];
    }
}

// ---------------- sample-verify g_Pre ----------------
__global__ void verify_pre() {
    int s = blockIdx.x * 256 + threadIdx.x;
    unsigned m = ((unsigned)s * 2654435761u) & 32767u;
    unsigned n = ((unsigned)s * 40503u + 7u) % 2560u;
    double dot = 0.0;
    const double* ar = g_A + (size_t)m * KE;
    const float*  wr = g_Wext + (size_t)n * KE;
    for (int c = 0; c < KE; ++c) dot += ar[c] * (double)wr[c];
    double got = (double)g_Pre[pre_ix((int)m, (int)n)];
    if (fabs(got - dot) > 1e-4 * (1.0 + fabs(dot))) atomicOr(&g_bad, 1);
}

// ---------------- full vector recompute of g_Pre (only if ok && bad) ----------------
__global__ __launch_bounds__(256) void big_fix() {
    if (!(g_ok && g_bad)) return;
    __shared__ double As[64][33];
    __shared__ double Ws[64][33];
    int tid = threadIdx.x, tx = tid & 15, ty = tid >> 4;
    for (int tile = blockIdx.x; tile < (NC/64) * (NBS/64); tile += gridDim.x) {
        int n0 = (tile % (NC/64)) * 64, m0 = (tile / (NC/64)) * 64;
        double acc[4][4] = {};
        for (int k0 = 0; k0 < KE; k0 += 32) {
            for (int i = tid; i < 2048; i += 256) {
                int r = i >> 5, c = i & 31;
                As[r][c] = g_A[(size_t)(m0 + r) * KE + k0 + c];
                Ws[r][c] = (double)g_Wext[(size_t)(n0 + r) * KE + k0 + c];
            }
            __syncthreads();
            for (int kk = 0; kk < 32; ++kk) {
                double a0 = As[ty*4][kk], a1 = As[ty*4+1][kk], a2 = As[ty*4+2][kk], a3 = As[ty*4+3][kk];
                double w0 = Ws[tx*4][kk], w1 = Ws[tx*4+1][kk], w2 = Ws[tx*4+2][kk], w3 = Ws[tx*4+3][kk];
                acc[0][0] += a0*w0; acc[0][1] += a0*w1; acc[0][2] += a0*w2; acc[0][3] += a0*w3;
                acc[1][0] += a1*w0; acc[1][1] += a1*w1; acc[1][2] += a1*w2; acc[1][3] += a1*w3;
                acc[2][0] += a2*w0; acc[2][1] += a2*w1; acc[2][2] += a2*w2; acc[2][3] += a2*w3;
                acc[3][0] += a3*w0; acc[3][1] += a3*w1; acc[3][2] += a3*w2; acc[3][3] += a3*w3;
            }
            __syncthreads();
        }
#pragma unroll
        for (int i = 0; i < 4; ++i)
#pragma unroll
            for (int j = 0; j < 4; ++j)
                g_Pre[pre_ix(m0 + ty*4 + i, n0 + tx*4 + j)] = (float)acc[i][j];
        __syncthreads();
    }
}

// ---------------- synthetic hx for step probes ----------------
__global__ void synth_hx() {
    int i = blockIdx.x * 256 + threadIdx.x;
    if (i >= NB * ND) return;
    unsigned h = (unsigned)i * 2654435761u;
    float v = (float)((h >> 8) & 0xFFFFu) / 65536.0f - 0.5f;
    g_hx[i] = (double)v;
    u16 b0, b1, b2; decomp3(v, b0, b1, b2);
    g_hxb[i] = b0; g_hxb[PSH + i] = b1; g_hxb[2 * PSH + i] = b2;
}

// ---------------- standalone step GEMM (probe + host-fallback path, NC stride) ----------------
__global__ __launch_bounds__(256) void step_gemm(int t, int probe) {
    __shared__ double shd[3168];
    int tid = threadIdx.x;
    int m0 = blockIdx.x * 32, n0 = blockIdx.y * 64;
    int use_mfma = g_ok && (probe || !g_badstep);
    if (use_mfma) {
        int lane = tid & 63, wave = tid >> 6;
        int wm = (wave & 1) * 16, wn = (wave >> 1) * 32;
        int lr = lane & 15, lk = lane >> 4;
        size_t ha  = (size_t)(m0 + wm + lr) * ND;
        size_t wb0 = (size_t)(n0 + wn + lr) * ND;
        size_t wb1 = (size_t)(n0 + wn + 16 + lr) * ND;
        f4v z = {0.f,0.f,0.f,0.f};
        f4v aP0=z, aP1=z, aC0=z, aC1=z;
        for (int k0 = 0; k0 < ND; k0 += 32) {
            int kk = k0 + 8 * lk;
            s8v a0  = *(const s8v*)(const void*)(g_hxb + ha + kk);
            s8v a1  = *(const s8v*)(const void*)(g_hxb + PSH + ha + kk);
            s8v a2  = *(const s8v*)(const void*)(g_hxb + 2*PSH + ha + kk);
            s8v b00 = *(const s8v*)(const void*)(g_Wstepb + wb0 + kk);
            s8v b01 = *(const s8v*)(const void*)(g_Wstepb + wb1 + kk);
            s8v b10 = *(const s8v*)(const void*)(g_Wstepb + PSWS + wb0 + kk);
            s8v b11 = *(const s8v*)(const void*)(g_Wstepb + PSWS + wb1 + kk);
            s8v b20 = *(const s8v*)(const void*)(g_Wstepb + 2*PSWS + wb0 + kk);
            s8v b21 = *(const s8v*)(const void*)(g_Wstepb + 2*PSWS + wb1 + kk);
            STEP6(aP0, aC0, a0, a1, a2, b00, b10, b20)
            STEP6(aP1, aC1, a0, a1, a2, b01, b11, b21)
        }
        int rb = m0 + wm + 4 * lk, cb0 = n0 + wn + lr, cb1 = cb0 + 16;
#pragma unroll
        for (int r = 0; r < 4; ++r) {
            g_gbufF[(size_t)(rb + r) * NC + cb0] = aP0[r] + aC0[r]
                + g_Pre[((size_t)t * NB + rb + r) * NC + cb0];
            g_gbufF[(size_t)(rb + r) * NC + cb1] = aP1[r] + aC1[r]
                + g_Pre[((size_t)t * NB + rb + r) * NC + cb1];
        }
    } else {
        double* Asd = shd;
        double* Wsd = shd + 1056;
        int tx = tid & 15, ty = tid >> 4;
        double acc[2][4] = {};
        for (int k0 = 0; k0 < ND; k0 += 32) {
            for (int i = tid; i < 1024; i += 256) {
                int r = i >> 5, c = i & 31;
                Asd[r * 33 + c] = g_hx[(size_t)(m0 + r) * ND + k0 + c];
            }
            for (int i = tid; i < 2048; i += 256) {
                int r = i >> 5, c = i & 31;
                Wsd[r * 33 + c] = (double)g_Wstep[(size_t)(n0 + r) * ND + k0 + c];
            }
            __syncthreads();
            for (int kk = 0; kk < 32; ++kk) {
                double a0 = Asd[(ty*2)*33+kk], a1 = Asd[(ty*2+1)*33+kk];
                double w0 = Wsd[(tx*4)*33+kk], w1 = Wsd[(tx*4+1)*33+kk], w2 = Wsd[(tx*4+2)*33+kk], w3 = Wsd[(tx*4+3)*33+kk];
                acc[0][0] += a0*w0; acc[0][1] += a0*w1; acc[0][2] += a0*w2; acc[0][3] += a0*w3;
                acc[1][0] += a1*w0; acc[1][1] += a1*w1; acc[1][2] += a1*w2; acc[1][3] += a1*w3;
            }
            __syncthreads();
        }
#pragma unroll
        for (int i = 0; i < 2; ++i)
#pragma unroll
            for (int j = 0; j < 4; ++j) {
                int m = m0 + ty*2 + i, n = n0 + tx*4 + j;
                g_gbufF[(size_t)m * NC + n] = (float)(acc[i][j]
                    + (double)g_Pre[((size_t)t * NB + m) * NC + n]);
            }
    }
}

// ---------------- verify standalone step (t=0, synthetic hx, NC stride) ----------------
__global__ void verify_step() {
    int s = blockIdx.x * 256 + threadIdx.x;
    unsigned m = ((unsigned)s * 2654435761u) & 127u;
    unsigned n = ((unsigned)s * 40503u + 7u) % 2560u;
    double dot = 0.0;
    const double* hr = g_hx + (size_t)m * ND;
    const float*  wr = g_Wstep + (size_t)n * ND;
    for (int c = 0; c < ND; ++c) dot += hr[c] * (double)wr[c];
    dot += (double)g_Pre[(size_t)m * NC + n];
    double got = (double)g_gbufF[(size_t)m * NC + n];
    if (fabs(got - dot) > 1e-4 * (1.0 + fabs(dot))) atomicOr(&g_badstep, 1);
}

// ---------------- verify fused probe output (gates 2048-stride + leap partials) ----------------
__global__ void verify_fused(const float* __restrict__ W2) {
    int s = blockIdx.x * 256 + threadIdx.x;    // 4096 samples
    unsigned m = ((unsigned)s * 2654435761u) & 127u;
    unsigned h2 = (unsigned)s * 40503u + 7u;
    const double* hr = g_hx + (size_t)m * ND;
    if (s & 1) {
        unsigned q = h2 & 31u;
        double p0 = 0.0, p1 = 0.0;
        for (int c = 0; c < 16; ++c) {
            int col = q * 16 + c;
            const float* wr = g_Wstep + (size_t)(2048 + col) * ND;
            double dot = 0.0;
            for (int k = 0; k < ND; ++k) dot += hr[k] * (double)wr[k];
            dot += (double)g_Pre[(size_t)m * NC + 2048 + col];
            double hh = dot > 0.0 ? dot : 0.0;
            p0 += hh * (double)W2[col];
            p1 += hh * (double)W2[512 + col];
        }
        if (fabs(g_lpart[q][m][0] - p0) > 1e-4 * (1.0 + fabs(p0)) ||
            fabs(g_lpart[q][m][1] - p1) > 1e-4 * (1.0 + fabs(p1)))
            atomicOr(&g_badfused, 1);
    } else {
        unsigned n = h2 % 2048u;
        double dot = 0.0;
        const float* wr = g_Wstep + (size_t)n * ND;
        for (int k = 0; k < ND; ++k) dot += hr[k] * (double)wr[k];
        dot += (double)g_Pre[(size_t)m * NC + n];
        double got = (double)g_gbufF[(size_t)m * 2048 + n];
        if (fabs(got - dot) > 1e-4 * (1.0 + fabs(dot))) atomicOr(&g_badfused, 1);
    }
}

// ---------------- standalone per-step update (host fallback, NC stride) ----------------
__global__ __launch_bounds__(256) void step_update(
    const float* __restrict__ W2, const float* __restrict__ b2,
    const int* __restrict__ lengths, int t) {
    __shared__ double red[8];
    __shared__ double skipsh[2];
    int b = blockIdx.x, tid = threadIdx.x, lane = tid & 63, wave = tid >> 6;
    const float* gb = g_gbufF + (size_t)b * NC;
    double p0 = 0.0, p1 = 0.0;
    for (int j = tid; j < ND; j += 256) {
        double h = (double)gb[2048 + j];
        h = h > 0.0 ? h : 0.0;
        p0 += h * (double)W2[j];
        p1 += h * (double)W2[ND + j];
    }
    for (int off = 32; off > 0; off >>= 1) {
        p0 += __shfl_down(p0, off, 64);
        p1 += __shfl_down(p1, off, 64);
    }
    if (lane == 0) { red[wave*2] = p0; red[wave*2+1] = p1; }
    __syncthreads();
    if (tid == 0) {
        double l0 = red[0]+red[2]+red[4]+red[6] + (double)b2[0];
        double l1 = red[1]+red[3]+red[5]+red[7] + (double)b2[1];
        double mx = fmax(l0, l1);
        double sh0 = l0 - mx, sh1 = l1 - mx;
        double lsum = log(exp(sh0) + exp(sh1));
        double y0 = (sh0 - lsum) - g_gum[(size_t)t * (NB * 2) + b * 2 + 0];
        double y1 = (sh1 - lsum) - g_gum[(size_t)t * (NB * 2) + b * 2 + 1];
        double xx0 = y0 / 1e-5, xx1 = y1 / 1e-5;
        double mm = fmax(xx0, xx1);
        double e0 = exp(xx0 - mm), e1 = exp(xx1 - mm);
        double inv = 1.0 / (e0 + e1);
        skipsh[0] = e0 * inv; skipsh[1] = e1 * inv;
    }
    __syncthreads();
    double s0 = skipsh[0], s1 = skipsh[1];
    bool isFinal = (t == lengths[b] - 1);
#pragma unroll
    for (int e = 0; e < 2; ++e) {
        int j = tid + 256 * e;
        size_t ix = (size_t)b * ND + j;
        double gi = (double)gb[j], gf = (double)gb[ND + j];
        double gg = (double)gb[2*ND + j], go = (double)gb[3*ND + j];
        double cn = sigd(gf) * g_c[ix] + sigd(gi) * tanh(gg);
        double shx = sigd(go) * tanh(cn);
        double hn = g_hx[ix] * s1 + shx * s0;
        g_c[ix] = cn; g_hx[ix] = hn;
        u16 w0, w1, w2x; decomp3((float)hn, w0, w1, w2x);
        g_hxb[ix] = w0; g_hxb[PSH + ix] = w1; g_hxb[2 * PSH + ix] = w2x;
        if (isFinal) g_final[ix] = hn;
    }
}

// ---------------- persistent flag-synced loop: sc0sc1 (MALL) data path, no fences ----------------
__global__ __launch_bounds__(512, 1) void loop_fused(const float* __restrict__ W2,
                                                     const float* __restrict__ b2,
                                                     const int* __restrict__ lengths,
                                                     int steps, int probe) {
    __shared__ __align__(16) unsigned char shm[53504];
    int bid = blockIdx.x, tid = threadIdx.x;
    int nc0 = bid * 16;
    int w = tid >> 6, lane = tid & 63;
    int lr = lane & 15, lk = lane >> 4;
    int path = g_ok && !g_badfused;
    double c0 = 0.0, h0 = 0.0;                 // register state elem (row=bid, j=tid)
    int mylen = (bid < NB) ? lengths[bid] : -1;
    u16*    Wl     = (u16*)shm;                // 48KB bf16x3 weights (path)
    float*  Wfb    = (float*)shm;              // 32KB f32 weights (fallback overlay)
    float*  W2l    = (float*)(shm + 49152);    // 4KB
    double* skipsh = (double*)(shm + 53248);
    if (path) {
        for (int i = tid; i < 3072; i += 512) {
            int p = i >> 10, rem = i & 1023, kk = rem >> 6, l = rem & 63;
            int col = l & 15, k8 = l >> 4;
            *(uint4*)(void*)(Wl + (size_t)p*8192 + kk*512 + l*8) =
                *(const uint4*)(const void*)(g_Wstepb + (size_t)p*PSWS
                      + (size_t)(nc0 + col)*ND + kk*32 + k8*8);
        }
    } else {
        for (int i = tid; i < 16*512; i += 512)
            Wfb[i] = g_Wstep[(size_t)(nc0 + (i >> 9))*ND + (i & 511)];
    }
    for (int i = tid; i < 1024; i += 512) W2l[i] = W2[i];
    __syncthreads();
    int r0 = 16*w + 4*lk;
    float preA[4];
    if (path) {
#pragma unroll
        for (int r = 0; r < 4; ++r)
            preA[r] = g_Pre[((size_t)0 * NB + r0 + r) * NC + nc0 + lr];
    }
    for (int t = 0; t < steps; ++t) {
        if (path) {
            // ================= SC PATH (no fences) =================
            // ---- phase A: wait own 16-row panel's hx, MALL-load hxb, MFMA ----
            if (t > 0) {
                for (;;) {
                    bool ok = true;
                    if (lane < 16)
                        ok = (__hip_atomic_load(&g_hxf[(16*w + lane)*32],
                               __ATOMIC_RELAXED, __HIP_MEMORY_SCOPE_AGENT) >= t);
                    if (__all(ok)) break;
                    __builtin_amdgcn_s_sleep(1);
                }
            }
            f4v z = {0.f,0.f,0.f,0.f};
            f4v aP = z, aC = z;
            size_t ha = (size_t)(16*w + lr) * ND;
#pragma unroll
            for (int h = 0; h < 2; ++h) {
                uv4 U0[8], U1[8], U2[8];
#pragma unroll
                for (int kk = 0; kk < 8; ++kk) {     // issue 24 MALL loads
                    int kb = (8*h + kk)*32 + 8*lk;
                    const u16* p0 = g_hxb + ha + kb;
                    const u16* p1 = g_hxb + PSH + ha + kb;
                    const u16* p2 = g_hxb + 2*PSH + ha + kb;
                    asm volatile("global_load_dwordx4 %0, %3, off sc0 sc1\n\t"
                                 "global_load_dwordx4 %1, %4, off sc0 sc1\n\t"
                                 "global_load_dwordx4 %2, %5, off sc0 sc1"
                                 : "=v"(U0[kk]), "=v"(U1[kk]), "=v"(U2[kk])
                                 : "v"(p0), "v"(p1), "v"(p2));
                }
                SC_WAIT();
#pragma unroll
                for (int kk = 0; kk < 8; ++kk) {     // consume
                    const u16* wp = Wl + (8*h + kk)*512 + lane*8;
                    s8v B0 = *(const s8v*)(const void*)(wp);
                    s8v B1 = *(const s8v*)(const void*)(wp + 8192);
                    s8v B2 = *(const s8v*)(const void*)(wp + 16384);
                    s8v A0 = __builtin_bit_cast(s8v, U0[kk]);
                    s8v A1 = __builtin_bit_cast(s8v, U1[kk]);
                    s8v A2 = __builtin_bit_cast(s8v, U2[kk]);
                    STEP6(aP, aC, A0, A1, A2, B0, B1, B2)
                }
            }
            if (bid < NB) {
#pragma unroll
                for (int r = 0; r < 4; ++r) {
                    float v = aP[r] + aC[r] + preA[r];
                    sc_store_f32(g_gbufF + (size_t)(r0 + r) * 2048 + nc0 + lr, v);
                }
            } else {
                int colg = nc0 - 2048 + lr;
                double q0[4], q1[4];
#pragma unroll
                for (int r = 0; r < 4; ++r) {
                    float v = aP[r] + aC[r] + preA[r];
                    double hh = v > 0.f ? (double)v : 0.0;
                    q0[r] = hh * (double)W2l[colg];
                    q1[r] = hh * (double)W2l[512 + colg];
                }
#pragma unroll
                for (int m = 8; m > 0; m >>= 1)
#pragma unroll
                    for (int r = 0; r < 4; ++r) {
                        q0[r] += __shfl_xor(q0[r], m, 16);
                        q1[r] += __shfl_xor(q1[r], m, 16);
                    }
                if (lr == 0) {
#pragma unroll
                    for (int r = 0; r < 4; ++r) {
                        dv2 q; q[0] = q0[r]; q[1] = q1[r];
                        sc_store_d2(&g_lpart[bid - NB][r0 + r][0], q);
                    }
                }
            }
            asm volatile("s_waitcnt vmcnt(0)" ::: "memory");
            __syncthreads();
            if (tid == 0)
                __hip_atomic_store(&g_aflag[bid*32], t + 1, __ATOMIC_RELAXED,
                                   __HIP_MEMORY_SCOPE_AGENT);
            __syncthreads();
            // prefetch next Pre slice (cached; Pre is read-only and L2 stays warm)
            {
                int tn = (t + 1 < steps) ? t + 1 : t;
#pragma unroll
                for (int r = 0; r < 4; ++r)
                    preA[r] = g_Pre[((size_t)tn * NB + r0 + r) * NC + nc0 + lr];
            }
            // ---- phase B (row owner) ----
            if (!probe && bid < NB) {
                if (tid < 160) {
                    while (__hip_atomic_load(&g_aflag[tid*32], __ATOMIC_RELAXED,
                             __HIP_MEMORY_SCOPE_AGENT) < t + 1)
                        __builtin_amdgcn_s_sleep(1);
                }
                __syncthreads();
                // issue gbuf MALL loads (drain later, overlaps skip computation)
                float gi_f, gf_f, gg_f, go_f;
                {
                    const float* gp = g_gbufF + (size_t)bid * 2048 + tid;
                    asm volatile("global_load_dword %0, %4, off sc0 sc1\n\t"
                                 "global_load_dword %1, %5, off sc0 sc1\n\t"
                                 "global_load_dword %2, %6, off sc0 sc1\n\t"
                                 "global_load_dword %3, %7, off sc0 sc1"
                                 : "=v"(gi_f), "=v"(gf_f), "=v"(gg_f), "=v"(go_f)
                                 : "v"(gp), "v"(gp + 512), "v"(gp + 1024), "v"(gp + 1536));
                }
                double p0 = 0.0, p1 = 0.0;
                if (tid < 32) {
                    dv2 lp;
                    const double* lpp = &g_lpart[tid][bid][0];
                    asm volatile("global_load_dwordx4 %0, %1, off sc0 sc1"
                                 : "=v"(lp) : "v"(lpp));
                    asm volatile("s_waitcnt vmcnt(0)" ::: "memory");
                    p0 = lp[0]; p1 = lp[1];
                }
                __builtin_amdgcn_sched_barrier(0);
                if (tid < 64) {
#pragma unroll
                    for (int m = 16; m > 0; m >>= 1) {
                        p0 += __shfl_xor(p0, m, 32);
                        p1 += __shfl_xor(p1, m, 32);
                    }
                }
                if (tid == 0) {
                    double l0 = p0 + (double)b2[0], l1 = p1 + (double)b2[1];
                    double mx = fmax(l0, l1);
                    double sh0 = l0 - mx, sh1 = l1 - mx;
                    double lsum = log(exp(sh0) + exp(sh1));
                    double y0 = (sh0 - lsum) - g_gum[(size_t)t * (NB*2) + bid*2 + 0];
                    double y1 = (sh1 - lsum) - g_gum[(size_t)t * (NB*2) + bid*2 + 1];
                    double xx0 = y0 / 1e-5, xx1 = y1 / 1e-5;
                    double mm = fmax(xx0, xx1);
                    double e0 = exp(xx0 - mm), e1 = exp(xx1 - mm);
                    double inv = 1.0 / (e0 + e1);
                    skipsh[0] = e0 * inv; skipsh[1] = e1 * inv;
                }
                __syncthreads();
                SC_WAIT();                           // gbuf loads ready
                double s0 = skipsh[0], s1 = skipsh[1];
                bool isFinal = (t == mylen - 1);
                size_t ix = (size_t)bid * ND + tid;
                double gi = (double)gi_f, gf = (double)gf_f;
                double gg = (double)gg_f, go = (double)go_f;
                double cn = sigd(gf) * c0 + sigd(gi) * tanh(gg);
                double shx = sigd(go) * tanh(cn);
                double hn = h0 * s1 + shx * s0;
                c0 = cn; h0 = hn;
                u16 w0_, w1_, w2_; decomp3((float)hn, w0_, w1_, w2_);
                sc_store_u16(g_hxb + ix, w0_);
                sc_store_u16(g_hxb + PSH + ix, w1_);
                sc_store_u16(g_hxb + 2*PSH + ix, w2_);
                if (isFinal) g_final[ix] = hn;
                asm volatile("s_waitcnt vmcnt(0)" ::: "memory");
                __syncthreads();
                if (tid == 0)
                    __hip_atomic_store(&g_hxf[bid*32], t + 1, __ATOMIC_RELAXED,
                                       __HIP_MEMORY_SCOPE_AGENT);
            }
        } else {
            // ================= FENCED FALLBACK (f64 vector, r12 semantics) =================
            if (t > 0) {
                if (tid < NB) {
                    while (__hip_atomic_load(&g_hxf[tid*32], __ATOMIC_RELAXED,
                             __HIP_MEMORY_SCOPE_AGENT) < t)
                        __builtin_amdgcn_s_sleep(1);
                }
                __syncthreads();
                if (tid == 0) __builtin_amdgcn_fence(__ATOMIC_ACQUIRE, "agent");
                __syncthreads();
            }
            int col = tid & 15, rgrp = tid >> 4;
            double q0[4] = {}, q1[4] = {};
#pragma unroll
            for (int rr = 0; rr < 4; ++rr) {
                int row = rgrp*4 + rr;
                const double* hr = g_hx + (size_t)row * ND;
                double dot = 0.0;
                for (int k = 0; k < ND; ++k) dot += hr[k] * (double)Wfb[col*512 + k];
                float v = (float)(dot + (double)g_Pre[((size_t)t * NB + row) * NC + nc0 + col]);
                if (bid < NB) {
                    g_gbufF[(size_t)row * 2048 + nc0 + col] = v;
                } else {
                    double hh = v > 0.f ? (double)v : 0.0;
                    q0[rr] = hh * (double)W2l[nc0 - 2048 + col];
                    q1[rr] = hh * (double)W2l[512 + nc0 - 2048 + col];
                }
            }
            if (bid >= NB) {
#pragma unroll
                for (int m = 8; m > 0; m >>= 1)
#pragma unroll
                    for (int rr = 0; rr < 4; ++rr) {
                        q0[rr] += __shfl_xor(q0[rr], m, 16);
                        q1[rr] += __shfl_xor(q1[rr], m, 16);
                    }
                if (col == 0)
#pragma unroll
                    for (int rr = 0; rr < 4; ++rr) {
                        g_lpart[bid - NB][rgrp*4 + rr][0] = q0[rr];
                        g_lpart[bid - NB][rgrp*4 + rr][1] = q1[rr];
                    }
            }
            __syncthreads();
            if (tid == 0) {
                __builtin_amdgcn_fence(__ATOMIC_RELEASE, "agent");
                __hip_atomic_store(&g_aflag[bid*32], t + 1, __ATOMIC_RELAXED,
                                   __HIP_MEMORY_SCOPE_AGENT);
            }
            __syncthreads();
            if (!probe && bid < NB) {
                if (tid < 160) {
                    while (__hip_atomic_load(&g_aflag[tid*32], __ATOMIC_RELAXED,
                             __HIP_MEMORY_SCOPE_AGENT) < t + 1)
                        __builtin_amdgcn_s_sleep(1);
                }
                __syncthreads();
                if (tid == 0) __builtin_amdgcn_fence(__ATOMIC_ACQUIRE, "agent");
                __syncthreads();
                double p0 = 0.0, p1 = 0.0;
                if (tid < 32) { p0 = g_lpart[tid][bid][0]; p1 = g_lpart[tid][bid][1]; }
                if (tid < 64) {
#pragma unroll
                    for (int m = 16; m > 0; m >>= 1) {
                        p0 += __shfl_xor(p0, m, 32);
                        p1 += __shfl_xor(p1, m, 32);
                    }
                }
                if (tid == 0) {
                    double l0 = p0 + (double)b2[0], l1 = p1 + (double)b2[1];
                    double mx = fmax(l0, l1);
                    double sh0 = l0 - mx, sh1 = l1 - mx;
                    double lsum = log(exp(sh0) + exp(sh1));
                    double y0 = (sh0 - lsum) - g_gum[(size_t)t * (NB*2) + bid*2 + 0];
                    double y1 = (sh1 - lsum) - g_gum[(size_t)t * (NB*2) + bid*2 + 1];
                    double xx0 = y0 / 1e-5, xx1 = y1 / 1e-5;
                    double mm = fmax(xx0, xx1);
                    double e0 = exp(xx0 - mm), e1 = exp(xx1 - mm);
                    double inv = 1.0 / (e0 + e1);
                    skipsh[0] = e0 * inv; skipsh[1] = e1 * inv;
                }
                __syncthreads();
                double s0 = skipsh[0], s1 = skipsh[1];
                bool isFinal = (t == mylen - 1);
                int j = tid;
                size_t ix = (size_t)bid * ND + j;
                const float* gb = g_gbufF + (size_t)bid * 2048;
                double gi = (double)gb[j], gf = (double)gb[512 + j];
                double gg = (double)gb[1024 + j], go = (double)gb[1536 + j];
                double cn = sigd(gf) * c0 + sigd(gi) * tanh(gg);
                double shx = sigd(go) * tanh(cn);
                double hn = h0 * s1 + shx * s0;
                c0 = cn; h0 = hn;
                u16 w0_, w1_, w2_; decomp3((float)hn, w0_, w1_, w2_);
                g_hxb[ix] = w0_; g_hxb[PSH + ix] = w1_; g_hxb[2*PSH + ix] = w2_;
                g_hx[ix] = hn;
                if (isFinal) g_final[ix] = hn;
                __syncthreads();
                if (tid == 0) {
                    __builtin_amdgcn_fence(__ATOMIC_RELEASE, "agent");
                    __hip_atomic_store(&g_hxf[bid*32], t + 1, __ATOMIC_RELAXED,
                                       __HIP_MEMORY_SCOPE_AGENT);
                }
            }
        }
    }
}

// ---------------- final projection ----------------
__global__ __launch_bounds__(256) void final_out(const float* __restrict__ Wo,
                                                 const float* __restrict__ bo,
                                                 float* __restrict__ out) {
    int tid = threadIdx.x;
    int b = tid >> 1, k = tid & 1;
    double acc = 0.0;
    const double* f = g_final + (size_t)b * ND;
    const float* w = Wo + (size_t)k * ND;
    for (int d = 0; d < ND; ++d) acc += f[d] * (double)w[d];
    out[b * 2 + k] = (float)(acc + (double)bo[k]);
}

// ---------------- host launcher ----------------
extern "C" void kernel_launch(void* const* d_in, const int* in_sizes, int n_in,
                              void* d_out, int out_size, void* d_ws, size_t ws_size,
                              hipStream_t stream) {
    (void)in_sizes; (void)n_in; (void)d_ws; (void)ws_size; (void)out_size;
    const int*   seqs    = (const int*)d_in[0];
    const int*   lengths = (const int*)d_in[2];
    const float* emb     = (const float*)d_in[5];
    const float* revWih  = (const float*)d_in[6];
    const float* revWhh  = (const float*)d_in[7];
    const float* convw   = (const float*)d_in[8];
    const float* W1      = (const float*)d_in[9];
    const float* b1      = (const float*)d_in[10];
    const float* W2      = (const float*)d_in[11];
    const float* b2      = (const float*)d_in[12];
    const float* cWih    = (const float*)d_in[13];
    const float* cWhh    = (const float*)d_in[14];
    const float* Wo      = (const float*)d_in[15];
    const float* bo      = (const float*)d_in[16];
    float* out = (float*)d_out;

    double *A_p = nullptr, *Ap_p = nullptr;
    hipGetSymbolAddress((void**)&A_p,  HIP_SYMBOL(g_A));
    hipGetSymbolAddress((void**)&Ap_p, HIP_SYMBOL(g_Aproj));

    probe_bf16<<<1, 64, 0, stream>>>();
    build_w<<<NC, 256, 0, stream>>>(cWih, cWhh, W1, b1);
    gumbel_init<<<256, 256, 0, stream>>>();
    embed_sum<<<NBS, 128, 0, stream>>>(seqs, emb);

    gemm_f64<<<dim3(NBS / 64, 1), 256, 0, stream>>>(A_p, KE, revWih, ND, Ap_p, 40,
                                                    NBS, 40, ND);
    rev_lstm<<<NB, 64, 0, stream>>>(revWhh);
    conv_relu<<<dim3(NB, NS / 8), 256, 0, stream>>>(convw);

    big_gemm<<<dim3(NC / 64, NBS / 64), 256, 0, stream>>>();
    verify_pre<<<32, 256, 0, stream>>>();
    big_fix<<<2048, 256, 0, stream>>>();

    // probes on synthetic state
    synth_hx<<<256, 256, 0, stream>>>();
    step_gemm<<<dim3(4, 40), 256, 0, stream>>>(0, 1);
    verify_step<<<8, 256, 0, stream>>>();
    {   // fused sc-path phase-A probe (1 step, B skipped)
        int steps1 = 1, probe1 = 1;
        void* pargs[] = { (void*)&W2, (void*)&b2, (void*)&lengths,
                          (void*)&steps1, (void*)&probe1 };
        hipError_t pe = hipLaunchCooperativeKernel((const void*)loop_fused,
                                                   dim3(160), dim3(512), pargs, 0, stream);
        if (pe == hipSuccess) verify_fused<<<16, 256, 0, stream>>>(W2);
        else (void)hipGetLastError();
    }
    init_state<<<256, 256, 0, stream>>>();   // resets state + aflag/hxf

    int stepsN = NS, probe0 = 0;
    void* args[] = { (void*)&W2, (void*)&b2, (void*)&lengths,
                     (void*)&stepsN, (void*)&probe0 };
    hipError_t ce = hipLaunchCooperativeKernel((const void*)loop_fused,
                                               dim3(160), dim3(512), args, 0, stream);
    if (ce != hipSuccess) {
        (void)hipGetLastError();
        for (int t = 0; t < NS; ++t) {
            step_gemm<<<dim3(4, 40), 256, 0, stream>>>(t, 0);
            step_update<<<NB, 256, 0, stream>>>(W2, b2, lengths, t);
        }
    }
    final_out<<<1, 256, 0, stream>>>(Wo, bo, out);
}